// Round 3
// baseline (615.106 us; speedup 1.0000x reference)
//
#include <hip/hip_runtime.h>

#define B_ 2048
#define LC_ 20
#define LX_ 20
#define LH_ 200
#define D_ 128
#define H_ 512
#define DENSE_ 256

__device__ __forceinline__ float siluf(float x) { return x / (1.f + __expf(-x)); }

__device__ __forceinline__ float wredsum(float v) {
#pragma unroll
  for (int off = 32; off > 0; off >>= 1) v += __shfl_xor(v, off, 64);
  return v;
}
__device__ __forceinline__ float wredmax(float v) {
#pragma unroll
  for (int off = 32; off > 0; off >>= 1) v = fmaxf(v, __shfl_xor(v, off, 64));
  return v;
}

// ---------------------------------------------------------------------------
// K0 (1 block, 128 threads): degree-4 poly of u(t)=silu(t*w1+b1) per channel;
// E_p = c_p @ W2 (E_0 += time_b2); F_p = E_p @ comp_w[128:,:] (F_0 += comp_b);
// gvec[g] = grp_emb[g] @ comp_w[:128,:]
__global__ __launch_bounds__(128) void k0_poly(
    const float* __restrict__ w1, const float* __restrict__ b1,
    const float* __restrict__ W2, const float* __restrict__ b2,
    const float* __restrict__ comp_w, const float* __restrict__ comp_b,
    const float* __restrict__ grp_emb,
    float* __restrict__ E, float* __restrict__ F, float* __restrict__ gvec) {
  __shared__ float sc[5 * 128];
  __shared__ float sE[5 * 128];
  int k = threadIdx.x;
  {
    float w = w1[k], bb = b1[k];
    float y0 = siluf(bb);
    float y1 = siluf(0.25f * w + bb);
    float y2 = siluf(0.50f * w + bb);
    float y3 = siluf(0.75f * w + bb);
    float y4 = siluf(w + bb);
    float d1 = y1 - y0;
    float d2 = y2 - 2.f * y1 + y0;
    float d3 = y3 - 3.f * y2 + 3.f * y1 - y0;
    float d4 = y4 - 4.f * y3 + 6.f * y2 - 4.f * y1 + y0;
    float c0 = y0;
    float c1 = d1 - 0.5f * d2 + d3 * (1.f / 3.f) - 0.25f * d4;
    float c2 = 0.5f * d2 - 0.5f * d3 + (11.f / 24.f) * d4;
    float c3 = d3 * (1.f / 6.f) - 0.25f * d4;
    float c4 = d4 * (1.f / 24.f);
    sc[0 * 128 + k] = c0;
    sc[1 * 128 + k] = c1 * 4.f;
    sc[2 * 128 + k] = c2 * 16.f;
    sc[3 * 128 + k] = c3 * 64.f;
    sc[4 * 128 + k] = c4 * 256.f;
  }
  __syncthreads();
  int j = k;
  float e[5] = {0, 0, 0, 0, 0};
  for (int kk = 0; kk < 128; ++kk) {
    float wv = W2[kk * 128 + j];
#pragma unroll
    for (int p = 0; p < 5; ++p) e[p] += sc[p * 128 + kk] * wv;
  }
  e[0] += b2[j];
#pragma unroll
  for (int p = 0; p < 5; ++p) { sE[p * 128 + j] = e[p]; E[p * 128 + j] = e[p]; }
  __syncthreads();
  float f[5] = {0, 0, 0, 0, 0};
  for (int kk = 0; kk < 128; ++kk) {
    float wv = comp_w[(128 + kk) * 128 + j];
#pragma unroll
    for (int p = 0; p < 5; ++p) f[p] += sE[p * 128 + kk] * wv;
  }
  f[0] += comp_b[j];
#pragma unroll
  for (int p = 0; p < 5; ++p) F[p * 128 + j] = f[p];
  for (int g = 0; g < 4; ++g) {
    float acc = 0.f;
    for (int kk = 0; kk < 128; ++kk) acc += grp_emb[g * 128 + kk] * comp_w[kk * 128 + j];
    gvec[g * 128 + j] = acc;
  }
}

// ---------------------------------------------------------------------------
// cand_s / ctx_s masked means -> QIN[0:256), FUSED[0:256). grid B_, block 128
__global__ __launch_bounds__(128) void k_candctx(
    const int* __restrict__ ctok, const int* __restrict__ xtok,
    const int* __restrict__ cmask, const int* __restrict__ xmask,
    const float* __restrict__ tok_emb,
    float* __restrict__ QIN, float* __restrict__ FUSED) {
  int b = blockIdx.x, j = threadIdx.x;
  float acc = 0.f, cnt = 0.f;
  for (int l = 0; l < LC_; ++l) {
    if (cmask[b * LC_ + l]) { acc += tok_emb[(size_t)ctok[b * LC_ + l] * 128 + j]; cnt += 1.f; }
  }
  float cs = acc / fmaxf(cnt, 1.f);
  acc = 0.f; cnt = 0.f;
  for (int l = 0; l < LX_; ++l) {
    if (xmask[b * LX_ + l]) { acc += tok_emb[(size_t)xtok[b * LX_ + l] * 128 + j]; cnt += 1.f; }
  }
  float xs = acc / fmaxf(cnt, 1.f);
  QIN[(size_t)b * 896 + j] = cs;
  QIN[(size_t)b * 896 + 128 + j] = xs;
  FUSED[(size_t)b * 1408 + j] = cs;
  FUSED[(size_t)b * 1408 + 128 + j] = xs;
}

// ---------------------------------------------------------------------------
// comp summary via polynomial -> QIN[256:384), FUSED[384:512). grid B_, block 256
__global__ __launch_bounds__(256) void k_comp_poly(
    const float* __restrict__ times, const int* __restrict__ groups,
    const int* __restrict__ hmask,
    const float* __restrict__ F, const float* __restrict__ gvec,
    const float* __restrict__ comp_g, const float* __restrict__ comp_bt,
    float* __restrict__ QIN, float* __restrict__ FUSED) {
  __shared__ float sF[5 * 128];
  __shared__ float sG[4 * 128];
  __shared__ float sCs[4 * 128];
  int tid = threadIdx.x, b = blockIdx.x;
  int lane = tid & 63, w = tid >> 6;
  for (int idx = tid; idx < 5 * 128; idx += 256) sF[idx] = F[idx];
  for (int idx = tid; idx < 4 * 128; idx += 256) sG[idx] = gvec[idx];
  __syncthreads();
  const float* tptr = times + b * LH_;
  const int* gptr = groups + b * LH_;
  const int* mptr = hmask + b * LH_;
  int j0 = lane, j1 = lane + 64;
  float g0 = comp_g[j0], g1 = comp_g[j1], bt0 = comp_bt[j0], bt1 = comp_bt[j1];
  float cnt = 0.f;
  for (int l = lane; l < LH_; l += 64) cnt += (float)mptr[l];
  cnt = wredsum(cnt);
  float cs0 = 0.f, cs1 = 0.f;
  for (int l = w; l < LH_; l += 4) {
    float t = tptr[l];
    int g = gptr[l];
    int mk = mptr[l];
    float p0 = sG[g * 128 + j0] +
               (((sF[4 * 128 + j0] * t + sF[3 * 128 + j0]) * t + sF[2 * 128 + j0]) * t +
                sF[128 + j0]) * t + sF[j0];
    float p1 = sG[g * 128 + j1] +
               (((sF[4 * 128 + j1] * t + sF[3 * 128 + j1]) * t + sF[2 * 128 + j1]) * t +
                sF[128 + j1]) * t + sF[j1];
    float s1 = wredsum(p0 + p1);
    float s2 = wredsum(p0 * p0 + p1 * p1);
    float mean = s1 * (1.f / 128.f);
    float var = s2 * (1.f / 128.f) - mean * mean;
    float rstd = rsqrtf(var + 1e-5f);
    if (mk) {
      cs0 += siluf((p0 - mean) * rstd * g0 + bt0);
      cs1 += siluf((p1 - mean) * rstd * g1 + bt1);
    }
  }
  sCs[w * 128 + j0] = cs0;
  sCs[w * 128 + j1] = cs1;
  __syncthreads();
  if (tid < 128) {
    float v = sCs[tid] + sCs[128 + tid] + sCs[256 + tid] + sCs[384 + tid];
    float cm = v / fmaxf(cnt, 1.f);
    QIN[(size_t)b * 896 + 256 + tid] = cm;
    FUSED[(size_t)b * 1408 + 384 + tid] = cm;
  }
}

// ---------------------------------------------------------------------------
// dense: scalar-x GEMM [8 rows x 512 out], LN, silu -> QIN[384:896), FUSED[896:1408)
// grid B_/8, block 512
__global__ __launch_bounds__(512) void k_dense_g(
    const float* __restrict__ df, const float* __restrict__ dw,
    const float* __restrict__ dbias, const float* __restrict__ dg,
    const float* __restrict__ dbt,
    float* __restrict__ QIN, float* __restrict__ FUSED) {
  __shared__ float sr1[64], sr2[64];
  int tid = threadIdx.x;
  int b0 = blockIdx.x * 8;
  int j = tid;
  float acc[8] = {0, 0, 0, 0, 0, 0, 0, 0};
  const float* xb = df + (size_t)b0 * DENSE_;
#pragma unroll 4
  for (int k = 0; k < DENSE_; ++k) {
    float w = dw[k * H_ + j];
#pragma unroll
    for (int r = 0; r < 8; ++r) acc[r] += xb[r * DENSE_ + k] * w;
  }
  float bi = dbias[j];
  int wv = tid >> 6;
#pragma unroll
  for (int r = 0; r < 8; ++r) {
    float v = acc[r] + bi;
    acc[r] = v;
    float s1 = wredsum(v);
    float s2 = wredsum(v * v);
    if ((tid & 63) == 0) { sr1[r * 8 + wv] = s1; sr2[r * 8 + wv] = s2; }
  }
  __syncthreads();
  float g = dg[j], bt = dbt[j];
#pragma unroll
  for (int r = 0; r < 8; ++r) {
    float s1 = 0.f, s2 = 0.f;
#pragma unroll
    for (int w = 0; w < 8; ++w) { s1 += sr1[r * 8 + w]; s2 += sr2[r * 8 + w]; }
    float mean = s1 / (float)H_;
    float var = s2 / (float)H_ - mean * mean;
    float rstd = rsqrtf(var + 1e-5f);
    float y = siluf((acc[r] - mean) * rstd * g + bt);
    QIN[(size_t)(b0 + r) * 896 + 384 + j] = y;
    FUSED[(size_t)(b0 + r) * 1408 + 896 + j] = y;
  }
}

// ---------------------------------------------------------------------------
// query: scalar-x GEMM [8 rows x 128 out], LN, silu. grid B_/8, block 256
// waves 0,1 -> rows 0..3; waves 2,3 -> rows 4..7
__global__ __launch_bounds__(256) void k_query_g(
    const float* __restrict__ QIN, const float* __restrict__ qw,
    const float* __restrict__ qb, const float* __restrict__ qg,
    const float* __restrict__ qbt, float* __restrict__ query) {
  __shared__ float sr1[16], sr2[16];
  int tid = threadIdx.x;
  int j = tid & 127, rh = tid >> 7;
  int b0 = blockIdx.x * 8;
  float acc[4] = {0, 0, 0, 0};
  const float* xb = QIN + (size_t)(b0 + rh * 4) * 896;
#pragma unroll 4
  for (int k = 0; k < 896; ++k) {
    float w = qw[k * 128 + j];
#pragma unroll
    for (int r = 0; r < 4; ++r) acc[r] += xb[r * 896 + k] * w;
  }
  float bj = qb[j];
  int wh = (tid >> 6) & 1;
#pragma unroll
  for (int r = 0; r < 4; ++r) {
    float v = acc[r] + bj;
    acc[r] = v;
    float s1 = wredsum(v);
    float s2 = wredsum(v * v);
    if ((tid & 63) == 0) { sr1[(rh * 4 + r) * 2 + wh] = s1; sr2[(rh * 4 + r) * 2 + wh] = s2; }
  }
  __syncthreads();
  float g = qg[j], bt = qbt[j];
#pragma unroll
  for (int r = 0; r < 4; ++r) {
    int rr = rh * 4 + r;
    float s1 = sr1[rr * 2] + sr1[rr * 2 + 1];
    float s2 = sr2[rr * 2] + sr2[rr * 2 + 1];
    float mean = s1 / 128.f, var = s2 / 128.f - mean * mean;
    float rstd = rsqrtf(var + 1e-5f);
    query[(size_t)(b0 + rr) * 128 + j] = siluf((acc[r] - mean) * rstd * g + bt);
  }
}

// ---------------------------------------------------------------------------
// attention with polynomial time term; writes hist_s into FUSED[256:384).
// grid B_, block 256
__global__ __launch_bounds__(256) void k_attn2(
    const int* __restrict__ htok, const int* __restrict__ hpos,
    const int* __restrict__ hgrp, const int* __restrict__ hmask,
    const float* __restrict__ times,
    const float* __restrict__ tok_emb, const float* __restrict__ pos_emb,
    const float* __restrict__ grp_emb,
    const float* __restrict__ query, const float* __restrict__ E,
    float* __restrict__ FUSED) {
  __shared__ float sq[128];
  __shared__ float sE[5 * 128];
  __shared__ float st[LH_];
  __shared__ int smk[LH_];
  __shared__ float sa[LH_];
  __shared__ float sp[4 * 100];
  __shared__ float sred[4], sred2[4];
  __shared__ float seq[5 * 2];
  __shared__ float s_eq[5];
  __shared__ float smom[5 * 4];
  __shared__ float s_m[5];
  __shared__ float sA[2 * 128];
  int tid = threadIdx.x, b = blockIdx.x;
  int i = tid & 127, h = tid >> 7, wv = tid >> 6;
  if (tid < 128) sq[tid] = query[b * 128 + tid];
  for (int idx = tid; idx < 5 * 128; idx += 256) sE[idx] = E[idx];
  for (int l = tid; l < LH_; l += 256) { st[l] = times[b * LH_ + l]; smk[l] = hmask[b * LH_ + l]; }
  __syncthreads();
  if (tid < 128) {
#pragma unroll
    for (int p = 0; p < 5; ++p) {
      float v = sE[p * 128 + tid] * sq[tid];
      v = wredsum(v);
      if ((tid & 63) == 0) seq[p * 2 + wv] = v;
    }
  }
  const int* tokp = htok + b * LH_;
  const int* posp = hpos + b * LH_;
  const int* grpp = hgrp + b * LH_;
  for (int lp = 0; lp < 100; ++lp) {
    int l = 2 * lp + h;
    if (smk[l]) {
      int tok = tokp[l], pos = posp[l], g = grpp[l];
      float v = tok_emb[(size_t)tok * 128 + i] + pos_emb[pos * 128 + i] + grp_emb[g * 128 + i];
      float p = v * sq[i];
      p = wredsum(p);
      if ((tid & 63) == 0) sp[wv * 100 + lp] = p;
    }
  }
  __syncthreads();
  if (tid < 5) s_eq[tid] = seq[tid * 2] + seq[tid * 2 + 1];
  __syncthreads();
  const float scale = 0.08838834764831845f;
  if (tid < LH_) {
    float s;
    if (smk[tid]) {
      int hh = tid & 1, lp = tid >> 1;
      float t = st[tid];
      float poly = (((s_eq[4] * t + s_eq[3]) * t + s_eq[2]) * t + s_eq[1]) * t + s_eq[0];
      s = (sp[(2 * hh) * 100 + lp] + sp[(2 * hh + 1) * 100 + lp] + poly) * scale;
    } else s = -1e9f;
    sa[tid] = s;
  }
  __syncthreads();
  float m = (tid < LH_) ? sa[tid] : -3.0e38f;
  m = wredmax(m);
  if ((tid & 63) == 0) sred[wv] = m;
  __syncthreads();
  m = fmaxf(fmaxf(sred[0], sred[1]), fmaxf(sred[2], sred[3]));
  float e = 0.f;
  if (tid < LH_) { e = __expf(sa[tid] - m); sa[tid] = e; }
  float ssum = wredsum(e);
  if ((tid & 63) == 0) sred2[wv] = ssum;
  __syncthreads();
  float inv = 1.f / (sred2[0] + sred2[1] + sred2[2] + sred2[3]);
  {
    float a = (tid < LH_) ? sa[tid] * inv : 0.f;
    float t = (tid < LH_) ? st[tid] : 0.f;
    float tp = 1.f;
#pragma unroll
    for (int p = 0; p < 5; ++p) {
      float v = wredsum(a * tp);
      if ((tid & 63) == 0) smom[p * 4 + wv] = v;
      tp *= t;
    }
  }
  __syncthreads();
  if (tid < 5) s_m[tid] = smom[tid * 4] + smom[tid * 4 + 1] + smom[tid * 4 + 2] + smom[tid * 4 + 3];
  float hg = 0.f;
  for (int l = h * 100; l < h * 100 + 100; ++l) {
    float a = sa[l] * inv;
    if (a != 0.f) {
      int tok = tokp[l], pos = posp[l], g = grpp[l];
      float v = tok_emb[(size_t)tok * 128 + i] + pos_emb[pos * 128 + i] + grp_emb[g * 128 + i];
      hg += a * v;
    }
  }
  sA[h * 128 + i] = hg;
  __syncthreads();
  if (h == 0) {
    float v = sA[i] + sA[128 + i];
#pragma unroll
    for (int p = 0; p < 5; ++p) v += s_m[p] * sE[p * 128 + i];
    FUSED[(size_t)b * 1408 + 256 + i] = v;
  }
}

// ---------------------------------------------------------------------------
// interaction features: FUSED[512:896) from cand/hist/comp. grid B_, block 128
__global__ __launch_bounds__(128) void k_fuse_f(float* __restrict__ FUSED) {
  int b = blockIdx.x, i = threadIdx.x;
  float* row = FUSED + (size_t)b * 1408;
  float c = row[i], hs = row[256 + i], cm = row[384 + i];
  row[512 + i] = c * hs;
  row[640 + i] = c * cm;
  row[768 + i] = fabsf(hs - cm);
}

// ---------------------------------------------------------------------------
// final MLP: scalar-x GEMM1 [8 rows x 512], LN+silu -> LDS; GEMM2 [8 x 256]+silu;
// dot w3. grid B_/8, block 512
__global__ __launch_bounds__(512) void k_final_g(
    const float* __restrict__ FUSED,
    const float* __restrict__ ow1, const float* __restrict__ ob1,
    const float* __restrict__ og, const float* __restrict__ obt,
    const float* __restrict__ ow2, const float* __restrict__ ob2,
    const float* __restrict__ ow3, const float* __restrict__ ob3,
    float* __restrict__ out) {
  __shared__ float sh1[8 * 512];
  __shared__ float sr1[64], sr2[64];
  __shared__ float sdot[32];
  int tid = threadIdx.x;
  int b0 = blockIdx.x * 8;
  int j = tid;
  float acc[8] = {0, 0, 0, 0, 0, 0, 0, 0};
  const float* xb = FUSED + (size_t)b0 * 1408;
#pragma unroll 4
  for (int k = 0; k < 1408; ++k) {
    float w = ow1[k * 512 + j];
#pragma unroll
    for (int r = 0; r < 8; ++r) acc[r] += xb[r * 1408 + k] * w;
  }
  float bi = ob1[j];
  int wv = tid >> 6;
#pragma unroll
  for (int r = 0; r < 8; ++r) {
    float v = acc[r] + bi;
    acc[r] = v;
    float s1 = wredsum(v);
    float s2 = wredsum(v * v);
    if ((tid & 63) == 0) { sr1[r * 8 + wv] = s1; sr2[r * 8 + wv] = s2; }
  }
  __syncthreads();
  float g = og[j], bt = obt[j];
#pragma unroll
  for (int r = 0; r < 8; ++r) {
    float s1 = 0.f, s2 = 0.f;
#pragma unroll
    for (int w = 0; w < 8; ++w) { s1 += sr1[r * 8 + w]; s2 += sr2[r * 8 + w]; }
    float mean = s1 / 512.f, var = s2 / 512.f - mean * mean;
    float rstd = rsqrtf(var + 1e-5f);
    sh1[r * 512 + j] = siluf((acc[r] - mean) * rstd * g + bt);
  }
  __syncthreads();
  // GEMM2: half 0 -> rows 0..3, half 1 -> rows 4..7; j2 = output channel
  int j2 = tid & 255, half = tid >> 8;
  const float* h1b = &sh1[half * 4 * 512];
  float acc2[4] = {0, 0, 0, 0};
  for (int k = 0; k < 512; k += 4) {
    float w0 = ow2[(k + 0) * 256 + j2];
    float w1 = ow2[(k + 1) * 256 + j2];
    float w2v = ow2[(k + 2) * 256 + j2];
    float w3v = ow2[(k + 3) * 256 + j2];
#pragma unroll
    for (int rr = 0; rr < 4; ++rr) {
      const float4 x4 = *(const float4*)&h1b[rr * 512 + k];
      acc2[rr] += x4.x * w0 + x4.y * w1 + x4.z * w2v + x4.w * w3v;
    }
  }
  float b2v = ob2[j2], w3j = ow3[j2];
  int wq = (tid >> 6) & 3;
#pragma unroll
  for (int rr = 0; rr < 4; ++rr) {
    float h2 = siluf(acc2[rr] + b2v);
    float p = wredsum(h2 * w3j);
    if ((tid & 63) == 0) sdot[(half * 4 + rr) * 4 + wq] = p;
  }
  __syncthreads();
  if (tid < 8) {
    out[b0 + tid] = sdot[tid * 4] + sdot[tid * 4 + 1] + sdot[tid * 4 + 2] + sdot[tid * 4 + 3] +
                    ob3[0];
  }
}

// ---------------------------------------------------------------------------
extern "C" void kernel_launch(void* const* d_in, const int* in_sizes, int n_in,
                              void* d_out, int out_size, void* d_ws, size_t ws_size,
                              hipStream_t stream) {
  const int* cand_tok = (const int*)d_in[0];
  const int* ctx_tok = (const int*)d_in[1];
  const int* hist_tok = (const int*)d_in[2];
  const int* hist_pos = (const int*)d_in[3];
  const int* hist_grp = (const int*)d_in[4];
  const int* cand_mask = (const int*)d_in[5];
  const int* ctx_mask = (const int*)d_in[6];
  const int* hist_mask = (const int*)d_in[7];
  const float* hist_times = (const float*)d_in[8];
  const float* dense_feat = (const float*)d_in[9];
  const float* tok_emb = (const float*)d_in[10];
  const float* pos_emb = (const float*)d_in[11];
  const float* grp_emb = (const float*)d_in[12];
  const float* time_w1 = (const float*)d_in[13];
  const float* time_b1 = (const float*)d_in[14];
  const float* time_w2 = (const float*)d_in[15];
  const float* time_b2 = (const float*)d_in[16];
  const float* comp_w = (const float*)d_in[17];
  const float* comp_b = (const float*)d_in[18];
  const float* comp_g = (const float*)d_in[19];
  const float* comp_bt = (const float*)d_in[20];
  const float* dense_w = (const float*)d_in[21];
  const float* dense_b = (const float*)d_in[22];
  const float* dense_g = (const float*)d_in[23];
  const float* dense_bt = (const float*)d_in[24];
  const float* query_w = (const float*)d_in[25];
  const float* query_b = (const float*)d_in[26];
  const float* query_g = (const float*)d_in[27];
  const float* query_bt = (const float*)d_in[28];
  const float* out_w1 = (const float*)d_in[29];
  const float* out_b1 = (const float*)d_in[30];
  const float* out_g = (const float*)d_in[31];
  const float* out_bt = (const float*)d_in[32];
  const float* out_w2 = (const float*)d_in[33];
  const float* out_b2 = (const float*)d_in[34];
  const float* out_w3 = (const float*)d_in[35];
  const float* out_b3 = (const float*)d_in[36];
  float* out = (float*)d_out;

  float* ws = (float*)d_ws;
  float* E = ws;                   // 640
  float* F = ws + 640;             // 640
  float* gvec = ws + 1280;         // 512
  float* query = ws + 2048;        // 262144
  float* QIN = ws + 264192;        // 2048*896  = 1835008
  float* FUSED = ws + 2099200;     // 2048*1408 = 2883584  (end 4982784 floats)

  k0_poly<<<1, 128, 0, stream>>>(time_w1, time_b1, time_w2, time_b2,
                                 comp_w, comp_b, grp_emb, E, F, gvec);
  k_candctx<<<B_, 128, 0, stream>>>(cand_tok, ctx_tok, cand_mask, ctx_mask,
                                    tok_emb, QIN, FUSED);
  k_comp_poly<<<B_, 256, 0, stream>>>(hist_times, hist_grp, hist_mask,
                                      F, gvec, comp_g, comp_bt, QIN, FUSED);
  k_dense_g<<<B_ / 8, 512, 0, stream>>>(dense_feat, dense_w, dense_b, dense_g, dense_bt,
                                        QIN, FUSED);
  k_query_g<<<B_ / 8, 256, 0, stream>>>(QIN, query_w, query_b, query_g, query_bt, query);
  k_attn2<<<B_, 256, 0, stream>>>(hist_tok, hist_pos, hist_grp, hist_mask, hist_times,
                                  tok_emb, pos_emb, grp_emb, query, E, FUSED);
  k_fuse_f<<<B_, 128, 0, stream>>>(FUSED);
  k_final_g<<<B_ / 8, 512, 0, stream>>>(FUSED, out_w1, out_b1, out_g, out_bt,
                                        out_w2, out_b2, out_w3, out_b3, out);
}

// Round 4
// 519.230 us; speedup vs baseline: 1.1847x; 1.1847x over previous
//
#include <hip/hip_runtime.h>
#include <hip/hip_bf16.h>

#define B_ 2048
#define LC_ 20
#define LX_ 20
#define LH_ 200
#define D_ 128
#define H_ 512
#define DENSE_ 256

typedef __attribute__((ext_vector_type(8))) short short8v;
typedef __attribute__((ext_vector_type(4))) float floatx4;

__device__ __forceinline__ float siluf(float x) { return x / (1.f + __expf(-x)); }

__device__ __forceinline__ unsigned short f2bf(float f) {
  return __builtin_bit_cast(unsigned short, __float2bfloat16(f));
}
__device__ __forceinline__ float bf2f(unsigned short u) {
  return __bfloat162float(__builtin_bit_cast(__hip_bfloat16, u));
}

__device__ __forceinline__ float wredsum(float v) {
#pragma unroll
  for (int off = 32; off > 0; off >>= 1) v += __shfl_xor(v, off, 64);
  return v;
}
__device__ __forceinline__ float wredmax(float v) {
#pragma unroll
  for (int off = 32; off > 0; off >>= 1) v = fmaxf(v, __shfl_xor(v, off, 64));
  return v;
}

// ---------------------------------------------------------------------------
// K0 (1 block, 128 threads): degree-4 poly of u(t)=silu(t*w1+b1) per channel;
// E_p = c_p @ W2 (E_0 += time_b2); F_p = E_p @ comp_w[128:,:] (F_0 += comp_b);
// gvec[g] = grp_emb[g] @ comp_w[:128,:]
__global__ __launch_bounds__(128) void k0_poly(
    const float* __restrict__ w1, const float* __restrict__ b1,
    const float* __restrict__ W2, const float* __restrict__ b2,
    const float* __restrict__ comp_w, const float* __restrict__ comp_b,
    const float* __restrict__ grp_emb,
    float* __restrict__ E, float* __restrict__ F, float* __restrict__ gvec) {
  __shared__ float sc[5 * 128];
  __shared__ float sE[5 * 128];
  int k = threadIdx.x;
  {
    float w = w1[k], bb = b1[k];
    float y0 = siluf(bb);
    float y1 = siluf(0.25f * w + bb);
    float y2 = siluf(0.50f * w + bb);
    float y3 = siluf(0.75f * w + bb);
    float y4 = siluf(w + bb);
    float d1 = y1 - y0;
    float d2 = y2 - 2.f * y1 + y0;
    float d3 = y3 - 3.f * y2 + 3.f * y1 - y0;
    float d4 = y4 - 4.f * y3 + 6.f * y2 - 4.f * y1 + y0;
    float c0 = y0;
    float c1 = d1 - 0.5f * d2 + d3 * (1.f / 3.f) - 0.25f * d4;
    float c2 = 0.5f * d2 - 0.5f * d3 + (11.f / 24.f) * d4;
    float c3 = d3 * (1.f / 6.f) - 0.25f * d4;
    float c4 = d4 * (1.f / 24.f);
    sc[0 * 128 + k] = c0;
    sc[1 * 128 + k] = c1 * 4.f;
    sc[2 * 128 + k] = c2 * 16.f;
    sc[3 * 128 + k] = c3 * 64.f;
    sc[4 * 128 + k] = c4 * 256.f;
  }
  __syncthreads();
  int j = k;
  float e[5] = {0, 0, 0, 0, 0};
  for (int kk = 0; kk < 128; ++kk) {
    float wv = W2[kk * 128 + j];
#pragma unroll
    for (int p = 0; p < 5; ++p) e[p] += sc[p * 128 + kk] * wv;
  }
  e[0] += b2[j];
#pragma unroll
  for (int p = 0; p < 5; ++p) { sE[p * 128 + j] = e[p]; E[p * 128 + j] = e[p]; }
  __syncthreads();
  float f[5] = {0, 0, 0, 0, 0};
  for (int kk = 0; kk < 128; ++kk) {
    float wv = comp_w[(128 + kk) * 128 + j];
#pragma unroll
    for (int p = 0; p < 5; ++p) f[p] += sE[p * 128 + kk] * wv;
  }
  f[0] += comp_b[j];
#pragma unroll
  for (int p = 0; p < 5; ++p) F[p * 128 + j] = f[p];
  for (int g = 0; g < 4; ++g) {
    float acc = 0.f;
    for (int kk = 0; kk < 128; ++kk) acc += grp_emb[g * 128 + kk] * comp_w[kk * 128 + j];
    gvec[g * 128 + j] = acc;
  }
}

// ---------------------------------------------------------------------------
// transpose+convert out_w1 [1408x512] f32 -> BT [512x1408] bf16. grid 2816, 256
__global__ __launch_bounds__(256) void k_convw1(
    const float* __restrict__ ow1, unsigned short* __restrict__ BT) {
  int idx = blockIdx.x * 256 + threadIdx.x;
  if (idx < 512 * 1408) {
    int n = idx / 1408, k = idx - n * 1408;
    BT[(size_t)n * 1408 + k] = f2bf(ow1[(size_t)k * 512 + n]);
  }
}

// ---------------------------------------------------------------------------
// cand_s / ctx_s masked means -> QIN[0:256) fp32, FB[0:256) bf16. grid B_, 128
__global__ __launch_bounds__(128) void k_candctx(
    const int* __restrict__ ctok, const int* __restrict__ xtok,
    const int* __restrict__ cmask, const int* __restrict__ xmask,
    const float* __restrict__ tok_emb,
    float* __restrict__ QIN, unsigned short* __restrict__ FB) {
  int b = blockIdx.x, j = threadIdx.x;
  float acc = 0.f, cnt = 0.f;
#pragma unroll
  for (int l = 0; l < LC_; ++l) {
    float mv = (float)cmask[b * LC_ + l];
    acc += mv * tok_emb[(size_t)ctok[b * LC_ + l] * 128 + j];
    cnt += mv;
  }
  float cs = acc / fmaxf(cnt, 1.f);
  acc = 0.f; cnt = 0.f;
#pragma unroll
  for (int l = 0; l < LX_; ++l) {
    float mv = (float)xmask[b * LX_ + l];
    acc += mv * tok_emb[(size_t)xtok[b * LX_ + l] * 128 + j];
    cnt += mv;
  }
  float xs = acc / fmaxf(cnt, 1.f);
  QIN[(size_t)b * 896 + j] = cs;
  QIN[(size_t)b * 896 + 128 + j] = xs;
  FB[(size_t)b * 1408 + j] = f2bf(cs);
  FB[(size_t)b * 1408 + 128 + j] = f2bf(xs);
}

// ---------------------------------------------------------------------------
// comp summary via polynomial -> QIN[256:384) fp32, FB[384:512) bf16. grid B_, 256
__global__ __launch_bounds__(256) void k_comp_poly(
    const float* __restrict__ times, const int* __restrict__ groups,
    const int* __restrict__ hmask,
    const float* __restrict__ F, const float* __restrict__ gvec,
    const float* __restrict__ comp_g, const float* __restrict__ comp_bt,
    float* __restrict__ QIN, unsigned short* __restrict__ FB) {
  __shared__ float sF[5 * 128];
  __shared__ float sG[4 * 128];
  __shared__ float sCs[4 * 128];
  int tid = threadIdx.x, b = blockIdx.x;
  int lane = tid & 63, w = tid >> 6;
  for (int idx = tid; idx < 5 * 128; idx += 256) sF[idx] = F[idx];
  for (int idx = tid; idx < 4 * 128; idx += 256) sG[idx] = gvec[idx];
  __syncthreads();
  const float* tptr = times + b * LH_;
  const int* gptr = groups + b * LH_;
  const int* mptr = hmask + b * LH_;
  int j0 = lane, j1 = lane + 64;
  float g0 = comp_g[j0], g1 = comp_g[j1], bt0 = comp_bt[j0], bt1 = comp_bt[j1];
  float cnt = 0.f;
  for (int l = lane; l < LH_; l += 64) cnt += (float)mptr[l];
  cnt = wredsum(cnt);
  float cs0 = 0.f, cs1 = 0.f;
  for (int l = w; l < LH_; l += 4) {
    float t = tptr[l];
    int g = gptr[l];
    int mk = mptr[l];
    float p0 = sG[g * 128 + j0] +
               (((sF[4 * 128 + j0] * t + sF[3 * 128 + j0]) * t + sF[2 * 128 + j0]) * t +
                sF[128 + j0]) * t + sF[j0];
    float p1 = sG[g * 128 + j1] +
               (((sF[4 * 128 + j1] * t + sF[3 * 128 + j1]) * t + sF[2 * 128 + j1]) * t +
                sF[128 + j1]) * t + sF[j1];
    float s1 = wredsum(p0 + p1);
    float s2 = wredsum(p0 * p0 + p1 * p1);
    float mean = s1 * (1.f / 128.f);
    float var = s2 * (1.f / 128.f) - mean * mean;
    float rstd = rsqrtf(var + 1e-5f);
    if (mk) {
      cs0 += siluf((p0 - mean) * rstd * g0 + bt0);
      cs1 += siluf((p1 - mean) * rstd * g1 + bt1);
    }
  }
  sCs[w * 128 + j0] = cs0;
  sCs[w * 128 + j1] = cs1;
  __syncthreads();
  if (tid < 128) {
    float v = sCs[tid] + sCs[128 + tid] + sCs[256 + tid] + sCs[384 + tid];
    float cm = v / fmaxf(cnt, 1.f);
    QIN[(size_t)b * 896 + 256 + tid] = cm;
    FB[(size_t)b * 1408 + 384 + tid] = f2bf(cm);
  }
}

// ---------------------------------------------------------------------------
// dense: LDS-staged GEMM [4 rows x 512], LN, silu -> QIN[384:896), FB[896:1408)
// grid B_/4, block 256
__global__ __launch_bounds__(256) void k_dense(
    const float* __restrict__ df, const float* __restrict__ dw,
    const float* __restrict__ dbias, const float* __restrict__ dg,
    const float* __restrict__ dbt,
    float* __restrict__ QIN, unsigned short* __restrict__ FB) {
  __shared__ float sx[4 * DENSE_];
  __shared__ float sr1[16], sr2[16];
  int tid = threadIdx.x;
  int b0 = blockIdx.x * 4;
  for (int idx = tid; idx < 4 * DENSE_; idx += 256) sx[idx] = df[b0 * DENSE_ + idx];
  __syncthreads();
  float a0[4] = {0, 0, 0, 0}, a1[4] = {0, 0, 0, 0};
  for (int k = 0; k < DENSE_; ++k) {
    float w0 = dw[k * H_ + tid];
    float w1 = dw[k * H_ + tid + 256];
#pragma unroll
    for (int bb = 0; bb < 4; ++bb) {
      float x = sx[bb * DENSE_ + k];
      a0[bb] += x * w0;
      a1[bb] += x * w1;
    }
  }
  float bi0 = dbias[tid], bi1 = dbias[tid + 256];
  int wv = tid >> 6;
#pragma unroll
  for (int bb = 0; bb < 4; ++bb) {
    a0[bb] += bi0; a1[bb] += bi1;
    float s1 = wredsum(a0[bb] + a1[bb]);
    float s2 = wredsum(a0[bb] * a0[bb] + a1[bb] * a1[bb]);
    if ((tid & 63) == 0) { sr1[bb * 4 + wv] = s1; sr2[bb * 4 + wv] = s2; }
  }
  __syncthreads();
  float g0 = dg[tid], g1 = dg[tid + 256], t0 = dbt[tid], t1 = dbt[tid + 256];
#pragma unroll
  for (int bb = 0; bb < 4; ++bb) {
    float s1 = sr1[bb * 4] + sr1[bb * 4 + 1] + sr1[bb * 4 + 2] + sr1[bb * 4 + 3];
    float s2 = sr2[bb * 4] + sr2[bb * 4 + 1] + sr2[bb * 4 + 2] + sr2[bb * 4 + 3];
    float mean = s1 / (float)H_;
    float var = s2 / (float)H_ - mean * mean;
    float rstd = rsqrtf(var + 1e-5f);
    float y0 = siluf((a0[bb] - mean) * rstd * g0 + t0);
    float y1 = siluf((a1[bb] - mean) * rstd * g1 + t1);
    QIN[(size_t)(b0 + bb) * 896 + 384 + tid] = y0;
    QIN[(size_t)(b0 + bb) * 896 + 384 + tid + 256] = y1;
    FB[(size_t)(b0 + bb) * 1408 + 896 + tid] = f2bf(y0);
    FB[(size_t)(b0 + bb) * 1408 + 896 + tid + 256] = f2bf(y1);
  }
}

// ---------------------------------------------------------------------------
// query = silu(ln(QIN @ query_w + b)). grid B_/4, block 128
__global__ __launch_bounds__(128) void k_query(
    const float* __restrict__ QIN, const float* __restrict__ qw,
    const float* __restrict__ qb, const float* __restrict__ qg,
    const float* __restrict__ qbt, float* __restrict__ query) {
  __shared__ float sx[4 * 896];
  __shared__ float sr1[8], sr2[8];
  int tid = threadIdx.x;
  int b0 = blockIdx.x * 4;
  for (int idx = tid; idx < 4 * 896; idx += 128) sx[idx] = QIN[(size_t)b0 * 896 + idx];
  __syncthreads();
  float acc[4] = {0, 0, 0, 0};
  for (int k = 0; k < 896; ++k) {
    float w = qw[k * 128 + tid];
#pragma unroll
    for (int bb = 0; bb < 4; ++bb) acc[bb] += sx[bb * 896 + k] * w;
  }
  float bj = qb[tid];
  int wv = tid >> 6;
#pragma unroll
  for (int bb = 0; bb < 4; ++bb) {
    acc[bb] += bj;
    float s1 = wredsum(acc[bb]);
    float s2 = wredsum(acc[bb] * acc[bb]);
    if ((tid & 63) == 0) { sr1[bb * 2 + wv] = s1; sr2[bb * 2 + wv] = s2; }
  }
  __syncthreads();
  float gj = qg[tid], tj = qbt[tid];
#pragma unroll
  for (int bb = 0; bb < 4; ++bb) {
    float s1 = sr1[bb * 2] + sr1[bb * 2 + 1];
    float s2 = sr2[bb * 2] + sr2[bb * 2 + 1];
    float mean = s1 / 128.f, var = s2 / 128.f - mean * mean;
    float rstd = rsqrtf(var + 1e-5f);
    query[(size_t)(b0 + bb) * 128 + tid] = siluf((acc[bb] - mean) * rstd * gj + tj);
  }
}

// ---------------------------------------------------------------------------
// attention with polynomial time term; writes hist_s into FB[256:384) bf16.
// grid B_, block 256
__global__ __launch_bounds__(256) void k_attn2(
    const int* __restrict__ htok, const int* __restrict__ hpos,
    const int* __restrict__ hgrp, const int* __restrict__ hmask,
    const float* __restrict__ times,
    const float* __restrict__ tok_emb, const float* __restrict__ pos_emb,
    const float* __restrict__ grp_emb,
    const float* __restrict__ query, const float* __restrict__ E,
    unsigned short* __restrict__ FB) {
  __shared__ float sq[128];
  __shared__ float sE[5 * 128];
  __shared__ float st[LH_];
  __shared__ int smk[LH_];
  __shared__ float sa[LH_];
  __shared__ float sp[4 * 100];
  __shared__ float sred[4], sred2[4];
  __shared__ float seq[5 * 2];
  __shared__ float s_eq[5];
  __shared__ float smom[5 * 4];
  __shared__ float s_m[5];
  __shared__ float sA[2 * 128];
  int tid = threadIdx.x, b = blockIdx.x;
  int i = tid & 127, h = tid >> 7, wv = tid >> 6;
  if (tid < 128) sq[tid] = query[b * 128 + tid];
  for (int idx = tid; idx < 5 * 128; idx += 256) sE[idx] = E[idx];
  for (int l = tid; l < LH_; l += 256) { st[l] = times[b * LH_ + l]; smk[l] = hmask[b * LH_ + l]; }
  __syncthreads();
  if (tid < 128) {
#pragma unroll
    for (int p = 0; p < 5; ++p) {
      float v = sE[p * 128 + tid] * sq[tid];
      v = wredsum(v);
      if ((tid & 63) == 0) seq[p * 2 + wv] = v;
    }
  }
  const int* tokp = htok + b * LH_;
  const int* posp = hpos + b * LH_;
  const int* grpp = hgrp + b * LH_;
  for (int lp = 0; lp < 100; ++lp) {
    int l = 2 * lp + h;
    if (smk[l]) {
      int tok = tokp[l], pos = posp[l], g = grpp[l];
      float v = tok_emb[(size_t)tok * 128 + i] + pos_emb[pos * 128 + i] + grp_emb[g * 128 + i];
      float p = v * sq[i];
      p = wredsum(p);
      if ((tid & 63) == 0) sp[wv * 100 + lp] = p;
    }
  }
  __syncthreads();
  if (tid < 5) s_eq[tid] = seq[tid * 2] + seq[tid * 2 + 1];
  __syncthreads();
  const float scale = 0.08838834764831845f;
  if (tid < LH_) {
    float s;
    if (smk[tid]) {
      int hh = tid & 1, lp = tid >> 1;
      float t = st[tid];
      float poly = (((s_eq[4] * t + s_eq[3]) * t + s_eq[2]) * t + s_eq[1]) * t + s_eq[0];
      s = (sp[(2 * hh) * 100 + lp] + sp[(2 * hh + 1) * 100 + lp] + poly) * scale;
    } else s = -1e9f;
    sa[tid] = s;
  }
  __syncthreads();
  float m = (tid < LH_) ? sa[tid] : -3.0e38f;
  m = wredmax(m);
  if ((tid & 63) == 0) sred[wv] = m;
  __syncthreads();
  m = fmaxf(fmaxf(sred[0], sred[1]), fmaxf(sred[2], sred[3]));
  float e = 0.f;
  if (tid < LH_) { e = __expf(sa[tid] - m); sa[tid] = e; }
  float ssum = wredsum(e);
  if ((tid & 63) == 0) sred2[wv] = ssum;
  __syncthreads();
  float inv = 1.f / (sred2[0] + sred2[1] + sred2[2] + sred2[3]);
  {
    float a = (tid < LH_) ? sa[tid] * inv : 0.f;
    float t = (tid < LH_) ? st[tid] : 0.f;
    float tp = 1.f;
#pragma unroll
    for (int p = 0; p < 5; ++p) {
      float v = wredsum(a * tp);
      if ((tid & 63) == 0) smom[p * 4 + wv] = v;
      tp *= t;
    }
  }
  __syncthreads();
  if (tid < 5) s_m[tid] = smom[tid * 4] + smom[tid * 4 + 1] + smom[tid * 4 + 2] + smom[tid * 4 + 3];
  float hg = 0.f;
  for (int l = h * 100; l < h * 100 + 100; ++l) {
    float a = sa[l] * inv;
    if (a != 0.f) {
      int tok = tokp[l], pos = posp[l], g = grpp[l];
      float v = tok_emb[(size_t)tok * 128 + i] + pos_emb[pos * 128 + i] + grp_emb[g * 128 + i];
      hg += a * v;
    }
  }
  sA[h * 128 + i] = hg;
  __syncthreads();
  if (h == 0) {
    float v = sA[i] + sA[128 + i];
#pragma unroll
    for (int p = 0; p < 5; ++p) v += s_m[p] * sE[p * 128 + i];
    FB[(size_t)b * 1408 + 256 + i] = f2bf(v);
  }
}

// ---------------------------------------------------------------------------
// interaction features in bf16: FB[512:896). grid B_, block 128
__global__ __launch_bounds__(128) void k_fuse_bf(unsigned short* __restrict__ FB) {
  int b = blockIdx.x, i = threadIdx.x;
  unsigned short* row = FB + (size_t)b * 1408;
  float c = bf2f(row[i]), hs = bf2f(row[256 + i]), cm = bf2f(row[384 + i]);
  row[512 + i] = f2bf(c * hs);
  row[640 + i] = f2bf(c * cm);
  row[768 + i] = f2bf(fabsf(hs - cm));
}

// ---------------------------------------------------------------------------
// GEMM1 via bf16 MFMA: H1[2048x512] = FB[2048x1408] @ ow1 (BT pre-transposed
// to [512][1408] bf16). Tile 64(M) x 32(N) per block of 4 waves; no LDS —
// A and B fragments read directly from global (16B/lane, 64B sectors/row).
// grid 512 (32 mtiles x 16 ntiles), block 256.
__global__ __launch_bounds__(256) void k_gemm1(
    const unsigned short* __restrict__ A, const unsigned short* __restrict__ BT,
    float* __restrict__ H1) {
  int tid = threadIdx.x;
  int bm = blockIdx.x >> 4;   // 0..31
  int bn = blockIdx.x & 15;   // 0..15
  int w = tid >> 6, lane = tid & 63;
  int m = lane & 15, quad = lane >> 4;
  const unsigned short* ap = A + (size_t)(bm * 64 + w * 16 + m) * 1408 + quad * 8;
  const unsigned short* bp0 = BT + (size_t)(bn * 32 + m) * 1408 + quad * 8;
  const unsigned short* bp1 = bp0 + 16 * 1408;
  floatx4 acc0 = {0.f, 0.f, 0.f, 0.f};
  floatx4 acc1 = {0.f, 0.f, 0.f, 0.f};
#pragma unroll 4
  for (int kc = 0; kc < 1408; kc += 32) {
    short8v af = *(const short8v*)&ap[kc];
    short8v b0 = *(const short8v*)&bp0[kc];
    short8v b1 = *(const short8v*)&bp1[kc];
    acc0 = __builtin_amdgcn_mfma_f32_16x16x32_bf16(af, b0, acc0, 0, 0, 0);
    acc1 = __builtin_amdgcn_mfma_f32_16x16x32_bf16(af, b1, acc1, 0, 0, 0);
  }
  // C/D layout: col = lane&15, row = quad*4 + reg
  int row = bm * 64 + w * 16 + quad * 4;
  int col = bn * 32 + m;
#pragma unroll
  for (int r = 0; r < 4; ++r) {
    H1[(size_t)(row + r) * 512 + col] = acc0[r];
    H1[(size_t)(row + r) * 512 + col + 16] = acc1[r];
  }
}

// ---------------------------------------------------------------------------
// post: h1 = silu(ln(H1 + ob1)); h2 = silu(h1 @ ow2 + ob2); out = h2 @ ow3 + ob3
// grid B_/8, block 256 (8 rows/block)
__global__ __launch_bounds__(256) void k_post(
    const float* __restrict__ H1, const float* __restrict__ ob1,
    const float* __restrict__ og, const float* __restrict__ obt,
    const float* __restrict__ ow2, const float* __restrict__ ob2,
    const float* __restrict__ ow3, const float* __restrict__ ob3,
    float* __restrict__ out) {
  __shared__ float sh1[8 * 512];
  __shared__ float sr1[32], sr2[32];
  __shared__ float sdot[16];
  int tid = threadIdx.x;
  int b0 = blockIdx.x * 8;
  int wv = tid >> 6;
  float bi0 = ob1[tid], bi1 = ob1[tid + 256];
  float a0[8], a1[8];
#pragma unroll
  for (int r = 0; r < 8; ++r) {
    a0[r] = H1[(size_t)(b0 + r) * 512 + tid] + bi0;
    a1[r] = H1[(size_t)(b0 + r) * 512 + tid + 256] + bi1;
    float s1 = wredsum(a0[r] + a1[r]);
    float s2 = wredsum(a0[r] * a0[r] + a1[r] * a1[r]);
    if ((tid & 63) == 0) { sr1[r * 4 + wv] = s1; sr2[r * 4 + wv] = s2; }
  }
  __syncthreads();
  float g0 = og[tid], g1 = og[tid + 256], t0 = obt[tid], t1 = obt[tid + 256];
#pragma unroll
  for (int r = 0; r < 8; ++r) {
    float s1 = sr1[r * 4] + sr1[r * 4 + 1] + sr1[r * 4 + 2] + sr1[r * 4 + 3];
    float s2 = sr2[r * 4] + sr2[r * 4 + 1] + sr2[r * 4 + 2] + sr2[r * 4 + 3];
    float mean = s1 / 512.f, var = s2 / 512.f - mean * mean;
    float rstd = rsqrtf(var + 1e-5f);
    sh1[r * 512 + tid] = siluf((a0[r] - mean) * rstd * g0 + t0);
    sh1[r * 512 + tid + 256] = siluf((a1[r] - mean) * rstd * g1 + t1);
  }
  __syncthreads();
  // GEMM2: thread -> cols (c, c+128), rowgroup rg -> rows rg*4..+3
  int c = tid & 127, rg = tid >> 7;
  const float* h1b = &sh1[rg * 4 * 512];
  float acca[4] = {0, 0, 0, 0}, accb[4] = {0, 0, 0, 0};
  for (int k = 0; k < 512; k += 4) {
    float w00 = ow2[(k + 0) * 256 + c], w01 = ow2[(k + 0) * 256 + c + 128];
    float w10 = ow2[(k + 1) * 256 + c], w11 = ow2[(k + 1) * 256 + c + 128];
    float w20 = ow2[(k + 2) * 256 + c], w21 = ow2[(k + 2) * 256 + c + 128];
    float w30 = ow2[(k + 3) * 256 + c], w31 = ow2[(k + 3) * 256 + c + 128];
#pragma unroll
    for (int r = 0; r < 4; ++r) {
      const float4 x = *(const float4*)&h1b[r * 512 + k];
      acca[r] += x.x * w00 + x.y * w10 + x.z * w20 + x.w * w30;
      accb[r] += x.x * w01 + x.y * w11 + x.z * w21 + x.w * w31;
    }
  }
  float b2a = ob2[c], b2b = ob2[c + 128];
  float w3a = ow3[c], w3b = ow3[c + 128];
#pragma unroll
  for (int r = 0; r < 4; ++r) {
    float h2a = siluf(acca[r] + b2a);
    float h2b = siluf(accb[r] + b2b);
    float p = wredsum(h2a * w3a + h2b * w3b);
    if ((tid & 63) == 0) sdot[(rg * 4 + r) * 2 + (wv & 1)] = p;
  }
  __syncthreads();
  if (tid < 8) out[b0 + tid] = sdot[tid * 2] + sdot[tid * 2 + 1] + ob3[0];
}

// ---------------------------------------------------------------------------
extern "C" void kernel_launch(void* const* d_in, const int* in_sizes, int n_in,
                              void* d_out, int out_size, void* d_ws, size_t ws_size,
                              hipStream_t stream) {
  const int* cand_tok = (const int*)d_in[0];
  const int* ctx_tok = (const int*)d_in[1];
  const int* hist_tok = (const int*)d_in[2];
  const int* hist_pos = (const int*)d_in[3];
  const int* hist_grp = (const int*)d_in[4];
  const int* cand_mask = (const int*)d_in[5];
  const int* ctx_mask = (const int*)d_in[6];
  const int* hist_mask = (const int*)d_in[7];
  const float* hist_times = (const float*)d_in[8];
  const float* dense_feat = (const float*)d_in[9];
  const float* tok_emb = (const float*)d_in[10];
  const float* pos_emb = (const float*)d_in[11];
  const float* grp_emb = (const float*)d_in[12];
  const float* time_w1 = (const float*)d_in[13];
  const float* time_b1 = (const float*)d_in[14];
  const float* time_w2 = (const float*)d_in[15];
  const float* time_b2 = (const float*)d_in[16];
  const float* comp_w = (const float*)d_in[17];
  const float* comp_b = (const float*)d_in[18];
  const float* comp_g = (const float*)d_in[19];
  const float* comp_bt = (const float*)d_in[20];
  const float* dense_w = (const float*)d_in[21];
  const float* dense_b = (const float*)d_in[22];
  const float* dense_g = (const float*)d_in[23];
  const float* dense_bt = (const float*)d_in[24];
  const float* query_w = (const float*)d_in[25];
  const float* query_b = (const float*)d_in[26];
  const float* query_g = (const float*)d_in[27];
  const float* query_bt = (const float*)d_in[28];
  const float* out_w1 = (const float*)d_in[29];
  const float* out_b1 = (const float*)d_in[30];
  const float* out_g = (const float*)d_in[31];
  const float* out_bt = (const float*)d_in[32];
  const float* out_w2 = (const float*)d_in[33];
  const float* out_b2 = (const float*)d_in[34];
  const float* out_w3 = (const float*)d_in[35];
  const float* out_b3 = (const float*)d_in[36];
  float* out = (float*)d_out;

  float* ws = (float*)d_ws;
  float* E = ws;                                    // 640
  float* F = ws + 640;                              // 640
  float* gvec = ws + 1280;                          // 512 (pad to 2048)
  float* query = ws + 2048;                         // 262144
  float* QIN = ws + 264192;                         // 2048*896 = 1835008
  float* H1 = ws + 2099200;                         // 2048*512 = 1048576
  unsigned short* FB = (unsigned short*)(ws + 3147776);   // 2048*1408 u16 = 1441792 fl
  unsigned short* OW1BT = (unsigned short*)(ws + 4589568); // 512*1408 u16 = 360448 fl
  // total 4950016 floats = 19.8 MB

  k0_poly<<<1, 128, 0, stream>>>(time_w1, time_b1, time_w2, time_b2,
                                 comp_w, comp_b, grp_emb, E, F, gvec);
  k_convw1<<<2816, 256, 0, stream>>>(out_w1, OW1BT);
  k_candctx<<<B_, 128, 0, stream>>>(cand_tok, ctx_tok, cand_mask, ctx_mask,
                                    tok_emb, QIN, FB);
  k_comp_poly<<<B_, 256, 0, stream>>>(hist_times, hist_grp, hist_mask,
                                      F, gvec, comp_g, comp_bt, QIN, FB);
  k_dense<<<B_ / 4, 256, 0, stream>>>(dense_feat, dense_w, dense_b, dense_g, dense_bt,
                                      QIN, FB);
  k_query<<<B_ / 4, 128, 0, stream>>>(QIN, query_w, query_b, query_g, query_bt, query);
  k_attn2<<<B_, 256, 0, stream>>>(hist_tok, hist_pos, hist_grp, hist_mask, hist_times,
                                  tok_emb, pos_emb, grp_emb, query, E, FB);
  k_fuse_bf<<<B_, 128, 0, stream>>>(FB);
  k_gemm1<<<512, 256, 0, stream>>>(FB, OW1BT, H1);
  k_post<<<B_ / 8, 256, 0, stream>>>(H1, out_b1, out_g, out_bt,
                                     out_w2, out_b2, out_w3, out_b3, out);
}

// Round 5
// 460.012 us; speedup vs baseline: 1.3372x; 1.1287x over previous
//
#include <hip/hip_runtime.h>
#include <hip/hip_bf16.h>

#define B_ 2048
#define LC_ 20
#define LX_ 20
#define LH_ 200
#define D_ 128
#define H_ 512
#define DENSE_ 256

typedef __attribute__((ext_vector_type(8))) short short8v;
typedef __attribute__((ext_vector_type(4))) float floatx4;

__device__ __forceinline__ float siluf(float x) { return x / (1.f + __expf(-x)); }

__device__ __forceinline__ unsigned short f2bf(float f) {
  return __builtin_bit_cast(unsigned short, __float2bfloat16(f));
}
__device__ __forceinline__ float bf2f(unsigned short u) {
  return __bfloat162float(__builtin_bit_cast(__hip_bfloat16, u));
}

__device__ __forceinline__ float wredsum(float v) {
#pragma unroll
  for (int off = 32; off > 0; off >>= 1) v += __shfl_xor(v, off, 64);
  return v;
}

// ---------------------------------------------------------------------------
// K0 (1 block, 128 threads): degree-4 poly of u(t)=silu(t*w1+b1) per channel;
// E_p = c_p @ W2 (E_0 += time_b2); F_p = E_p @ comp_w[128:,:] (F_0 += comp_b);
// gvec[g] = grp_emb[g] @ comp_w[:128,:]
__global__ __launch_bounds__(128) void k0_poly(
    const float* __restrict__ w1, const float* __restrict__ b1,
    const float* __restrict__ W2, const float* __restrict__ b2,
    const float* __restrict__ comp_w, const float* __restrict__ comp_b,
    const float* __restrict__ grp_emb,
    float* __restrict__ E, float* __restrict__ F, float* __restrict__ gvec) {
  __shared__ float sc[5 * 128];
  __shared__ float sE[5 * 128];
  int k = threadIdx.x;
  {
    float w = w1[k], bb = b1[k];
    float y0 = siluf(bb);
    float y1 = siluf(0.25f * w + bb);
    float y2 = siluf(0.50f * w + bb);
    float y3 = siluf(0.75f * w + bb);
    float y4 = siluf(w + bb);
    float d1 = y1 - y0;
    float d2 = y2 - 2.f * y1 + y0;
    float d3 = y3 - 3.f * y2 + 3.f * y1 - y0;
    float d4 = y4 - 4.f * y3 + 6.f * y2 - 4.f * y1 + y0;
    float c0 = y0;
    float c1 = d1 - 0.5f * d2 + d3 * (1.f / 3.f) - 0.25f * d4;
    float c2 = 0.5f * d2 - 0.5f * d3 + (11.f / 24.f) * d4;
    float c3 = d3 * (1.f / 6.f) - 0.25f * d4;
    float c4 = d4 * (1.f / 24.f);
    sc[0 * 128 + k] = c0;
    sc[1 * 128 + k] = c1 * 4.f;
    sc[2 * 128 + k] = c2 * 16.f;
    sc[3 * 128 + k] = c3 * 64.f;
    sc[4 * 128 + k] = c4 * 256.f;
  }
  __syncthreads();
  int j = k;
  float e[5] = {0, 0, 0, 0, 0};
  for (int kk = 0; kk < 128; ++kk) {
    float wv = W2[kk * 128 + j];
#pragma unroll
    for (int p = 0; p < 5; ++p) e[p] += sc[p * 128 + kk] * wv;
  }
  e[0] += b2[j];
#pragma unroll
  for (int p = 0; p < 5; ++p) { sE[p * 128 + j] = e[p]; E[p * 128 + j] = e[p]; }
  __syncthreads();
  float f[5] = {0, 0, 0, 0, 0};
  for (int kk = 0; kk < 128; ++kk) {
    float wv = comp_w[(128 + kk) * 128 + j];
#pragma unroll
    for (int p = 0; p < 5; ++p) f[p] += sE[p * 128 + kk] * wv;
  }
  f[0] += comp_b[j];
#pragma unroll
  for (int p = 0; p < 5; ++p) F[p * 128 + j] = f[p];
  for (int g = 0; g < 4; ++g) {
    float acc = 0.f;
    for (int kk = 0; kk < 128; ++kk) acc += grp_emb[g * 128 + kk] * comp_w[kk * 128 + j];
    gvec[g * 128 + j] = acc;
  }
}

// ---------------------------------------------------------------------------
// transpose+convert out_w1 [1408x512] f32 -> BT [512x1408] bf16. grid 2816, 256
__global__ __launch_bounds__(256) void k_convw1(
    const float* __restrict__ ow1, unsigned short* __restrict__ BT) {
  int idx = blockIdx.x * 256 + threadIdx.x;
  if (idx < 512 * 1408) {
    int n = idx / 1408, k = idx - n * 1408;
    BT[(size_t)n * 1408 + k] = f2bf(ow1[(size_t)k * 512 + n]);
  }
}

// ---------------------------------------------------------------------------
// cand_s / ctx_s masked means -> QIN[0:256) fp32, FB[0:256) bf16. grid B_, 128
__global__ __launch_bounds__(128) void k_candctx(
    const int* __restrict__ ctok, const int* __restrict__ xtok,
    const int* __restrict__ cmask, const int* __restrict__ xmask,
    const float* __restrict__ tok_emb,
    float* __restrict__ QIN, unsigned short* __restrict__ FB) {
  int b = blockIdx.x, j = threadIdx.x;
  float acc = 0.f, cnt = 0.f;
#pragma unroll
  for (int l = 0; l < LC_; ++l) {
    float mv = (float)cmask[b * LC_ + l];
    acc += mv * tok_emb[(size_t)ctok[b * LC_ + l] * 128 + j];
    cnt += mv;
  }
  float cs = acc / fmaxf(cnt, 1.f);
  acc = 0.f; cnt = 0.f;
#pragma unroll
  for (int l = 0; l < LX_; ++l) {
    float mv = (float)xmask[b * LX_ + l];
    acc += mv * tok_emb[(size_t)xtok[b * LX_ + l] * 128 + j];
    cnt += mv;
  }
  float xs = acc / fmaxf(cnt, 1.f);
  QIN[(size_t)b * 896 + j] = cs;
  QIN[(size_t)b * 896 + 128 + j] = xs;
  FB[(size_t)b * 1408 + j] = f2bf(cs);
  FB[(size_t)b * 1408 + 128 + j] = f2bf(xs);
}

// ---------------------------------------------------------------------------
// comp summary via polynomial -> QIN[256:384) fp32, FB[384:512) bf16. grid B_, 256
__global__ __launch_bounds__(256) void k_comp_poly(
    const float* __restrict__ times, const int* __restrict__ groups,
    const int* __restrict__ hmask,
    const float* __restrict__ F, const float* __restrict__ gvec,
    const float* __restrict__ comp_g, const float* __restrict__ comp_bt,
    float* __restrict__ QIN, unsigned short* __restrict__ FB) {
  __shared__ float sF[5 * 128];
  __shared__ float sG[4 * 128];
  __shared__ float sCs[4 * 128];
  int tid = threadIdx.x, b = blockIdx.x;
  int lane = tid & 63, w = tid >> 6;
  for (int idx = tid; idx < 5 * 128; idx += 256) sF[idx] = F[idx];
  for (int idx = tid; idx < 4 * 128; idx += 256) sG[idx] = gvec[idx];
  __syncthreads();
  const float* tptr = times + b * LH_;
  const int* gptr = groups + b * LH_;
  const int* mptr = hmask + b * LH_;
  int j0 = lane, j1 = lane + 64;
  float g0 = comp_g[j0], g1 = comp_g[j1], bt0 = comp_bt[j0], bt1 = comp_bt[j1];
  float cnt = 0.f;
  for (int l = lane; l < LH_; l += 64) cnt += (float)mptr[l];
  cnt = wredsum(cnt);
  float cs0 = 0.f, cs1 = 0.f;
  for (int l = w; l < LH_; l += 4) {
    float t = tptr[l];
    int g = gptr[l];
    int mk = mptr[l];
    float p0 = sG[g * 128 + j0] +
               (((sF[4 * 128 + j0] * t + sF[3 * 128 + j0]) * t + sF[2 * 128 + j0]) * t +
                sF[128 + j0]) * t + sF[j0];
    float p1 = sG[g * 128 + j1] +
               (((sF[4 * 128 + j1] * t + sF[3 * 128 + j1]) * t + sF[2 * 128 + j1]) * t +
                sF[128 + j1]) * t + sF[j1];
    float s1 = wredsum(p0 + p1);
    float s2 = wredsum(p0 * p0 + p1 * p1);
    float mean = s1 * (1.f / 128.f);
    float var = s2 * (1.f / 128.f) - mean * mean;
    float rstd = rsqrtf(var + 1e-5f);
    if (mk) {
      cs0 += siluf((p0 - mean) * rstd * g0 + bt0);
      cs1 += siluf((p1 - mean) * rstd * g1 + bt1);
    }
  }
  sCs[w * 128 + j0] = cs0;
  sCs[w * 128 + j1] = cs1;
  __syncthreads();
  if (tid < 128) {
    float v = sCs[tid] + sCs[128 + tid] + sCs[256 + tid] + sCs[384 + tid];
    float cm = v / fmaxf(cnt, 1.f);
    QIN[(size_t)b * 896 + 256 + tid] = cm;
    FB[(size_t)b * 1408 + 384 + tid] = f2bf(cm);
  }
}

// ---------------------------------------------------------------------------
// dense: LDS-staged GEMM [8 rows x 512], LN, silu -> QIN[384:896), FB[896:1408)
// grid B_/8, block 256
__global__ __launch_bounds__(256) void k_dense(
    const float* __restrict__ df, const float* __restrict__ dw,
    const float* __restrict__ dbias, const float* __restrict__ dg,
    const float* __restrict__ dbt,
    float* __restrict__ QIN, unsigned short* __restrict__ FB) {
  __shared__ float sx[8 * DENSE_];
  __shared__ float sr1[32], sr2[32];
  int tid = threadIdx.x;
  int b0 = blockIdx.x * 8;
  for (int idx = tid; idx < 8 * DENSE_; idx += 256) sx[idx] = df[(size_t)b0 * DENSE_ + idx];
  __syncthreads();
  float a0[8] = {0, 0, 0, 0, 0, 0, 0, 0}, a1[8] = {0, 0, 0, 0, 0, 0, 0, 0};
  for (int k = 0; k < DENSE_; ++k) {
    float w0 = dw[k * H_ + tid];
    float w1 = dw[k * H_ + tid + 256];
#pragma unroll
    for (int r = 0; r < 8; ++r) {
      float x = sx[r * DENSE_ + k];
      a0[r] += x * w0;
      a1[r] += x * w1;
    }
  }
  float bi0 = dbias[tid], bi1 = dbias[tid + 256];
  int wv = tid >> 6;
#pragma unroll
  for (int r = 0; r < 8; ++r) {
    a0[r] += bi0; a1[r] += bi1;
    float s1 = wredsum(a0[r] + a1[r]);
    float s2 = wredsum(a0[r] * a0[r] + a1[r] * a1[r]);
    if ((tid & 63) == 0) { sr1[r * 4 + wv] = s1; sr2[r * 4 + wv] = s2; }
  }
  __syncthreads();
  float g0 = dg[tid], g1 = dg[tid + 256], t0 = dbt[tid], t1 = dbt[tid + 256];
#pragma unroll
  for (int r = 0; r < 8; ++r) {
    float s1 = sr1[r * 4] + sr1[r * 4 + 1] + sr1[r * 4 + 2] + sr1[r * 4 + 3];
    float s2 = sr2[r * 4] + sr2[r * 4 + 1] + sr2[r * 4 + 2] + sr2[r * 4 + 3];
    float mean = s1 / (float)H_;
    float var = s2 / (float)H_ - mean * mean;
    float rstd = rsqrtf(var + 1e-5f);
    float y0 = siluf((a0[r] - mean) * rstd * g0 + t0);
    float y1 = siluf((a1[r] - mean) * rstd * g1 + t1);
    QIN[(size_t)(b0 + r) * 896 + 384 + tid] = y0;
    QIN[(size_t)(b0 + r) * 896 + 384 + tid + 256] = y1;
    FB[(size_t)(b0 + r) * 1408 + 896 + tid] = f2bf(y0);
    FB[(size_t)(b0 + r) * 1408 + 896 + tid + 256] = f2bf(y1);
  }
}

// ---------------------------------------------------------------------------
// query = silu(ln(QIN @ query_w + b)). 8 rows/block; rh=tid>>7 -> rows 0-3/4-7.
// grid B_/8, block 256
__global__ __launch_bounds__(256) void k_query(
    const float* __restrict__ QIN, const float* __restrict__ qw,
    const float* __restrict__ qb, const float* __restrict__ qg,
    const float* __restrict__ qbt, float* __restrict__ query) {
  __shared__ float sx[8 * 896];
  __shared__ float sr1[16], sr2[16];
  int tid = threadIdx.x;
  int b0 = blockIdx.x * 8;
  for (int idx = tid; idx < 8 * 896; idx += 256) sx[idx] = QIN[(size_t)b0 * 896 + idx];
  __syncthreads();
  int j = tid & 127, rh = tid >> 7;
  float acc[4] = {0, 0, 0, 0};
  const float* xb = &sx[rh * 4 * 896];
  for (int k = 0; k < 896; ++k) {
    float w = qw[k * 128 + j];
#pragma unroll
    for (int r = 0; r < 4; ++r) acc[r] += xb[r * 896 + k] * w;
  }
  float bj = qb[j];
  int wh = (tid >> 6) & 1;
#pragma unroll
  for (int r = 0; r < 4; ++r) {
    int rr = rh * 4 + r;
    acc[r] += bj;
    float s1 = wredsum(acc[r]);
    float s2 = wredsum(acc[r] * acc[r]);
    if ((tid & 63) == 0) { sr1[rr * 2 + wh] = s1; sr2[rr * 2 + wh] = s2; }
  }
  __syncthreads();
  float gj = qg[j], tj = qbt[j];
#pragma unroll
  for (int r = 0; r < 4; ++r) {
    int rr = rh * 4 + r;
    float s1 = sr1[rr * 2] + sr1[rr * 2 + 1];
    float s2 = sr2[rr * 2] + sr2[rr * 2 + 1];
    float mean = s1 / 128.f, var = s2 / 128.f - mean * mean;
    float rstd = rsqrtf(var + 1e-5f);
    query[(size_t)(b0 + rr) * 128 + j] = siluf((acc[r] - mean) * rstd * gj + tj);
  }
}

// ---------------------------------------------------------------------------
// single-pass online-softmax attention (no max-subtract: |scores| << 80).
// Each wave covers full rows (lane -> cols j0=lane, j1=lane+64), 50 rows/wave.
// Accumulates sum(e*v), sum(e), unnormalized moments sum(e*t^p); epilogue
// normalizes, adds poly time term, and writes hist + interaction features.
// grid B_, block 256
__global__ __launch_bounds__(256) void k_attn3(
    const int* __restrict__ htok, const int* __restrict__ hpos,
    const int* __restrict__ hgrp, const int* __restrict__ hmask,
    const float* __restrict__ times,
    const float* __restrict__ tok_emb, const float* __restrict__ pos_emb,
    const float* __restrict__ grp_emb,
    const float* __restrict__ query, const float* __restrict__ E,
    unsigned short* __restrict__ FB) {
  __shared__ float sq[128];
  __shared__ float sE[5 * 128];
  __shared__ float sG[4 * 128];
  __shared__ float st[LH_];
  __shared__ int stok[LH_], spos[LH_], sgrp[LH_], smk[LH_];
  __shared__ float seq[5 * 2];
  __shared__ float s_eq[5];
  __shared__ float sA[4 * 128];
  __shared__ float sL[4];
  __shared__ float sM[4 * 5];
  int tid = threadIdx.x, b = blockIdx.x;
  int lane = tid & 63, w = tid >> 6;
  if (tid < 128) sq[tid] = query[b * 128 + tid];
  for (int idx = tid; idx < 5 * 128; idx += 256) sE[idx] = E[idx];
  for (int idx = tid; idx < 4 * 128; idx += 256) sG[idx] = grp_emb[idx];
  for (int l = tid; l < LH_; l += 256) {
    st[l] = times[b * LH_ + l];
    stok[l] = htok[b * LH_ + l];
    spos[l] = hpos[b * LH_ + l];
    sgrp[l] = hgrp[b * LH_ + l];
    smk[l] = hmask[b * LH_ + l];
  }
  __syncthreads();
  // eq_p = E_p . q
  if (tid < 128) {
    int wh = (tid >> 6) & 1;
#pragma unroll
    for (int p = 0; p < 5; ++p) {
      float v = sE[p * 128 + tid] * sq[tid];
      v = wredsum(v);
      if ((tid & 63) == 0) seq[p * 2 + wh] = v;
    }
  }
  __syncthreads();
  if (tid < 5) s_eq[tid] = seq[tid * 2] + seq[tid * 2 + 1];
  __syncthreads();
  int j0 = lane, j1 = lane + 64;
  float q0 = sq[j0], q1 = sq[j1];
  const float scale = 0.08838834764831845f;  // 1/sqrt(128)
  float acc0 = 0.f, acc1 = 0.f, lsum = 0.f;
  float mom1 = 0.f, mom2 = 0.f, mom3 = 0.f, mom4 = 0.f;
  for (int l = w; l < LH_; l += 4) {
    if (smk[l]) {
      int tok = stok[l], pos = spos[l], g = sgrp[l];
      float v0 = tok_emb[(size_t)tok * 128 + j0] + pos_emb[pos * 128 + j0] + sG[g * 128 + j0];
      float v1 = tok_emb[(size_t)tok * 128 + j1] + pos_emb[pos * 128 + j1] + sG[g * 128 + j1];
      float t = st[l];
      float dot = wredsum(v0 * q0 + v1 * q1);
      float poly = (((s_eq[4] * t + s_eq[3]) * t + s_eq[2]) * t + s_eq[1]) * t + s_eq[0];
      float e = __expf((dot + poly) * scale);
      lsum += e;
      acc0 += e * v0;
      acc1 += e * v1;
      float tp = e * t;
      mom1 += tp; tp *= t;
      mom2 += tp; tp *= t;
      mom3 += tp; tp *= t;
      mom4 += tp;
    }
  }
  sA[w * 128 + j0] = acc0;
  sA[w * 128 + j1] = acc1;
  if (lane == 0) {
    sL[w] = lsum;
    sM[w * 5 + 1] = mom1; sM[w * 5 + 2] = mom2;
    sM[w * 5 + 3] = mom3; sM[w * 5 + 4] = mom4;
  }
  __syncthreads();
  if (tid < 128) {
    int i = tid;
    float L = sL[0] + sL[1] + sL[2] + sL[3];
    float inv = 1.f / L;
    float v = (sA[i] + sA[128 + i] + sA[256 + i] + sA[384 + i]) * inv;
    v += sE[i];  // p=0 term (normalized moment = 1)
#pragma unroll
    for (int p = 1; p < 5; ++p) {
      float mp = (sM[0 * 5 + p] + sM[1 * 5 + p] + sM[2 * 5 + p] + sM[3 * 5 + p]) * inv;
      v += mp * sE[p * 128 + i];
    }
    unsigned short* row = FB + (size_t)b * 1408;
    float c = bf2f(row[i]), cm = bf2f(row[384 + i]);
    row[256 + i] = f2bf(v);
    row[512 + i] = f2bf(c * v);
    row[640 + i] = f2bf(c * cm);
    row[768 + i] = f2bf(fabsf(v - cm));
  }
}

// ---------------------------------------------------------------------------
// GEMM1 via bf16 MFMA: H1[2048x512] = FB @ BT^T. Tile 64(M) x 64(N) per block
// (4 waves, each wave 16 rows x 64 cols); frags straight from global.
// grid 256 (32 mtiles x 8 ntiles), block 256.
__global__ __launch_bounds__(256) void k_gemm1(
    const unsigned short* __restrict__ A, const unsigned short* __restrict__ BT,
    float* __restrict__ H1) {
  int tid = threadIdx.x;
  int bm = blockIdx.x >> 3;   // 0..31
  int bn = blockIdx.x & 7;    // 0..7
  int w = tid >> 6, lane = tid & 63;
  int m = lane & 15, quad = lane >> 4;
  const unsigned short* ap = A + (size_t)(bm * 64 + w * 16 + m) * 1408 + quad * 8;
  const unsigned short* bp0 = BT + (size_t)(bn * 64 + m) * 1408 + quad * 8;
  const unsigned short* bp1 = bp0 + 16 * 1408;
  const unsigned short* bp2 = bp0 + 32 * 1408;
  const unsigned short* bp3 = bp0 + 48 * 1408;
  floatx4 acc0 = {0.f, 0.f, 0.f, 0.f};
  floatx4 acc1 = {0.f, 0.f, 0.f, 0.f};
  floatx4 acc2 = {0.f, 0.f, 0.f, 0.f};
  floatx4 acc3 = {0.f, 0.f, 0.f, 0.f};
#pragma unroll 4
  for (int kc = 0; kc < 1408; kc += 32) {
    short8v af = *(const short8v*)&ap[kc];
    short8v b0 = *(const short8v*)&bp0[kc];
    short8v b1 = *(const short8v*)&bp1[kc];
    short8v b2 = *(const short8v*)&bp2[kc];
    short8v b3 = *(const short8v*)&bp3[kc];
    acc0 = __builtin_amdgcn_mfma_f32_16x16x32_bf16(af, b0, acc0, 0, 0, 0);
    acc1 = __builtin_amdgcn_mfma_f32_16x16x32_bf16(af, b1, acc1, 0, 0, 0);
    acc2 = __builtin_amdgcn_mfma_f32_16x16x32_bf16(af, b2, acc2, 0, 0, 0);
    acc3 = __builtin_amdgcn_mfma_f32_16x16x32_bf16(af, b3, acc3, 0, 0, 0);
  }
  // C/D layout: col = lane&15, row = quad*4 + reg
  int row = bm * 64 + w * 16 + quad * 4;
  int col = bn * 64 + m;
#pragma unroll
  for (int r = 0; r < 4; ++r) {
    H1[(size_t)(row + r) * 512 + col] = acc0[r];
    H1[(size_t)(row + r) * 512 + col + 16] = acc1[r];
    H1[(size_t)(row + r) * 512 + col + 32] = acc2[r];
    H1[(size_t)(row + r) * 512 + col + 48] = acc3[r];
  }
}

// ---------------------------------------------------------------------------
// post: h1 = silu(ln(H1 + ob1)); h2 = silu(h1 @ ow2 + ob2); out = h2 @ ow3 + ob3
// grid B_/8, block 256 (8 rows/block)
__global__ __launch_bounds__(256) void k_post(
    const float* __restrict__ H1, const float* __restrict__ ob1,
    const float* __restrict__ og, const float* __restrict__ obt,
    const float* __restrict__ ow2, const float* __restrict__ ob2,
    const float* __restrict__ ow3, const float* __restrict__ ob3,
    float* __restrict__ out) {
  __shared__ float sh1[8 * 512];
  __shared__ float sr1[32], sr2[32];
  __shared__ float sdot[16];
  int tid = threadIdx.x;
  int b0 = blockIdx.x * 8;
  int wv = tid >> 6;
  float bi0 = ob1[tid], bi1 = ob1[tid + 256];
  float a0[8], a1[8];
#pragma unroll
  for (int r = 0; r < 8; ++r) {
    a0[r] = H1[(size_t)(b0 + r) * 512 + tid] + bi0;
    a1[r] = H1[(size_t)(b0 + r) * 512 + tid + 256] + bi1;
    float s1 = wredsum(a0[r] + a1[r]);
    float s2 = wredsum(a0[r] * a0[r] + a1[r] * a1[r]);
    if ((tid & 63) == 0) { sr1[r * 4 + wv] = s1; sr2[r * 4 + wv] = s2; }
  }
  __syncthreads();
  float g0 = og[tid], g1 = og[tid + 256], t0 = obt[tid], t1 = obt[tid + 256];
#pragma unroll
  for (int r = 0; r < 8; ++r) {
    float s1 = sr1[r * 4] + sr1[r * 4 + 1] + sr1[r * 4 + 2] + sr1[r * 4 + 3];
    float s2 = sr2[r * 4] + sr2[r * 4 + 1] + sr2[r * 4 + 2] + sr2[r * 4 + 3];
    float mean = s1 / 512.f, var = s2 / 512.f - mean * mean;
    float rstd = rsqrtf(var + 1e-5f);
    sh1[r * 512 + tid] = siluf((a0[r] - mean) * rstd * g0 + t0);
    sh1[r * 512 + tid + 256] = siluf((a1[r] - mean) * rstd * g1 + t1);
  }
  __syncthreads();
  int c = tid & 127, rg = tid >> 7;
  const float* h1b = &sh1[rg * 4 * 512];
  float acca[4] = {0, 0, 0, 0}, accb[4] = {0, 0, 0, 0};
  for (int k = 0; k < 512; k += 4) {
    float w00 = ow2[(k + 0) * 256 + c], w01 = ow2[(k + 0) * 256 + c + 128];
    float w10 = ow2[(k + 1) * 256 + c], w11 = ow2[(k + 1) * 256 + c + 128];
    float w20 = ow2[(k + 2) * 256 + c], w21 = ow2[(k + 2) * 256 + c + 128];
    float w30 = ow2[(k + 3) * 256 + c], w31 = ow2[(k + 3) * 256 + c + 128];
#pragma unroll
    for (int r = 0; r < 4; ++r) {
      const float4 x = *(const float4*)&h1b[r * 512 + k];
      acca[r] += x.x * w00 + x.y * w10 + x.z * w20 + x.w * w30;
      accb[r] += x.x * w01 + x.y * w11 + x.z * w21 + x.w * w31;
    }
  }
  float b2a = ob2[c], b2b = ob2[c + 128];
  float w3a = ow3[c], w3b = ow3[c + 128];
#pragma unroll
  for (int r = 0; r < 4; ++r) {
    float h2a = siluf(acca[r] + b2a);
    float h2b = siluf(accb[r] + b2b);
    float p = wredsum(h2a * w3a + h2b * w3b);
    if ((tid & 63) == 0) sdot[(rg * 4 + r) * 2 + (wv & 1)] = p;
  }
  __syncthreads();
  if (tid < 8) out[b0 + tid] = sdot[tid * 2] + sdot[tid * 2 + 1] + ob3[0];
}

// ---------------------------------------------------------------------------
extern "C" void kernel_launch(void* const* d_in, const int* in_sizes, int n_in,
                              void* d_out, int out_size, void* d_ws, size_t ws_size,
                              hipStream_t stream) {
  const int* cand_tok = (const int*)d_in[0];
  const int* ctx_tok = (const int*)d_in[1];
  const int* hist_tok = (const int*)d_in[2];
  const int* hist_pos = (const int*)d_in[3];
  const int* hist_grp = (const int*)d_in[4];
  const int* cand_mask = (const int*)d_in[5];
  const int* ctx_mask = (const int*)d_in[6];
  const int* hist_mask = (const int*)d_in[7];
  const float* hist_times = (const float*)d_in[8];
  const float* dense_feat = (const float*)d_in[9];
  const float* tok_emb = (const float*)d_in[10];
  const float* pos_emb = (const float*)d_in[11];
  const float* grp_emb = (const float*)d_in[12];
  const float* time_w1 = (const float*)d_in[13];
  const float* time_b1 = (const float*)d_in[14];
  const float* time_w2 = (const float*)d_in[15];
  const float* time_b2 = (const float*)d_in[16];
  const float* comp_w = (const float*)d_in[17];
  const float* comp_b = (const float*)d_in[18];
  const float* comp_g = (const float*)d_in[19];
  const float* comp_bt = (const float*)d_in[20];
  const float* dense_w = (const float*)d_in[21];
  const float* dense_b = (const float*)d_in[22];
  const float* dense_g = (const float*)d_in[23];
  const float* dense_bt = (const float*)d_in[24];
  const float* query_w = (const float*)d_in[25];
  const float* query_b = (const float*)d_in[26];
  const float* query_g = (const float*)d_in[27];
  const float* query_bt = (const float*)d_in[28];
  const float* out_w1 = (const float*)d_in[29];
  const float* out_b1 = (const float*)d_in[30];
  const float* out_g = (const float*)d_in[31];
  const float* out_bt = (const float*)d_in[32];
  const float* out_w2 = (const float*)d_in[33];
  const float* out_b2 = (const float*)d_in[34];
  const float* out_w3 = (const float*)d_in[35];
  const float* out_b3 = (const float*)d_in[36];
  float* out = (float*)d_out;

  float* ws = (float*)d_ws;
  float* E = ws;                                    // 640
  float* F = ws + 640;                              // 640
  float* gvec = ws + 1280;                          // 512 (pad to 2048)
  float* query = ws + 2048;                         // 262144
  float* QIN = ws + 264192;                         // 2048*896 = 1835008
  float* H1 = ws + 2099200;                         // 2048*512 = 1048576
  unsigned short* FB = (unsigned short*)(ws + 3147776);    // 2048*1408 u16
  unsigned short* OW1BT = (unsigned short*)(ws + 4589568); // 512*1408 u16

  k0_poly<<<1, 128, 0, stream>>>(time_w1, time_b1, time_w2, time_b2,
                                 comp_w, comp_b, grp_emb, E, F, gvec);
  k_convw1<<<2816, 256, 0, stream>>>(out_w1, OW1BT);
  k_candctx<<<B_, 128, 0, stream>>>(cand_tok, ctx_tok, cand_mask, ctx_mask,
                                    tok_emb, QIN, FB);
  k_comp_poly<<<B_, 256, 0, stream>>>(hist_times, hist_grp, hist_mask,
                                      F, gvec, comp_g, comp_bt, QIN, FB);
  k_dense<<<B_ / 8, 256, 0, stream>>>(dense_feat, dense_w, dense_b, dense_g, dense_bt,
                                      QIN, FB);
  k_query<<<B_ / 8, 256, 0, stream>>>(QIN, query_w, query_b, query_g, query_bt, query);
  k_attn3<<<B_, 256, 0, stream>>>(hist_tok, hist_pos, hist_grp, hist_mask, hist_times,
                                  tok_emb, pos_emb, grp_emb, query, E, FB);
  k_gemm1<<<256, 256, 0, stream>>>(FB, OW1BT, H1);
  k_post<<<B_ / 8, 256, 0, stream>>>(H1, out_b1, out_g, out_bt,
                                     out_w2, out_b2, out_w3, out_b3, out);
}

// Round 6
// 409.299 us; speedup vs baseline: 1.5028x; 1.1239x over previous
//
#include <hip/hip_runtime.h>
#include <hip/hip_bf16.h>

#define B_ 2048
#define LC_ 20
#define LX_ 20
#define LH_ 200
#define D_ 128
#define H_ 512
#define DENSE_ 256

typedef __attribute__((ext_vector_type(8))) short short8v;
typedef __attribute__((ext_vector_type(4))) float floatx4;

__device__ __forceinline__ float siluf(float x) { return x / (1.f + __expf(-x)); }

__device__ __forceinline__ unsigned short f2bf(float f) {
  return __builtin_bit_cast(unsigned short, __float2bfloat16(f));
}
__device__ __forceinline__ float bf2f(unsigned short u) {
  return __bfloat162float(__builtin_bit_cast(__hip_bfloat16, u));
}

__device__ __forceinline__ float wredsum(float v) {
#pragma unroll
  for (int off = 32; off > 0; off >>= 1) v += __shfl_xor(v, off, 64);
  return v;
}

// pair index into the 15-entry upper-triangular (p<=q, 5x5) list
__device__ __forceinline__ int cidx(int a, int b) {
  if (a > b) { int t = a; a = b; b = t; }
  const int base[5] = {0, 5, 9, 12, 14};
  return base[a] + (b - a);
}

// ---------------------------------------------------------------------------
// K0 (1 block, 128 threads): degree-4 poly of u(t)=silu(t*w1+b1) per channel;
// E_p = c_p @ W2 (E_0 += time_b2); F_p = E_p @ comp_w[128:,:] (F_0 += comp_b);
// gvec[g] = grp_emb[g] @ comp_w[:128,:].
// Also: analytic LN moments for comp: MV[0:20) = mcoef[g][p] (mean poly, deg4),
// MV[20:56) = vcoef[g][k] (E[x^2] poly, deg8).
__global__ __launch_bounds__(128) void k0_poly(
    const float* __restrict__ w1, const float* __restrict__ b1,
    const float* __restrict__ W2, const float* __restrict__ b2,
    const float* __restrict__ comp_w, const float* __restrict__ comp_b,
    const float* __restrict__ grp_emb,
    float* __restrict__ E, float* __restrict__ F, float* __restrict__ gvec,
    float* __restrict__ MV) {
  __shared__ float sc[5 * 128];
  __shared__ float sE[5 * 128];
  __shared__ float sF2[5 * 128];
  __shared__ float sGv[4 * 128];
  __shared__ float s48[48];
  int k = threadIdx.x;
  {
    float w = w1[k], bb = b1[k];
    float y0 = siluf(bb);
    float y1 = siluf(0.25f * w + bb);
    float y2 = siluf(0.50f * w + bb);
    float y3 = siluf(0.75f * w + bb);
    float y4 = siluf(w + bb);
    float d1 = y1 - y0;
    float d2 = y2 - 2.f * y1 + y0;
    float d3 = y3 - 3.f * y2 + 3.f * y1 - y0;
    float d4 = y4 - 4.f * y3 + 6.f * y2 - 4.f * y1 + y0;
    float c0 = y0;
    float c1 = d1 - 0.5f * d2 + d3 * (1.f / 3.f) - 0.25f * d4;
    float c2 = 0.5f * d2 - 0.5f * d3 + (11.f / 24.f) * d4;
    float c3 = d3 * (1.f / 6.f) - 0.25f * d4;
    float c4 = d4 * (1.f / 24.f);
    sc[0 * 128 + k] = c0;
    sc[1 * 128 + k] = c1 * 4.f;
    sc[2 * 128 + k] = c2 * 16.f;
    sc[3 * 128 + k] = c3 * 64.f;
    sc[4 * 128 + k] = c4 * 256.f;
  }
  __syncthreads();
  int j = k;
  float e[5] = {0, 0, 0, 0, 0};
  for (int kk = 0; kk < 128; ++kk) {
    float wv = W2[kk * 128 + j];
#pragma unroll
    for (int p = 0; p < 5; ++p) e[p] += sc[p * 128 + kk] * wv;
  }
  e[0] += b2[j];
#pragma unroll
  for (int p = 0; p < 5; ++p) { sE[p * 128 + j] = e[p]; E[p * 128 + j] = e[p]; }
  __syncthreads();
  float f[5] = {0, 0, 0, 0, 0};
  for (int kk = 0; kk < 128; ++kk) {
    float wv = comp_w[(128 + kk) * 128 + j];
#pragma unroll
    for (int p = 0; p < 5; ++p) f[p] += sE[p * 128 + kk] * wv;
  }
  f[0] += comp_b[j];
#pragma unroll
  for (int p = 0; p < 5; ++p) { F[p * 128 + j] = f[p]; sF2[p * 128 + j] = f[p]; }
  for (int g = 0; g < 4; ++g) {
    float acc = 0.f;
    for (int kk = 0; kk < 128; ++kk) acc += grp_emb[g * 128 + kk] * comp_w[kk * 128 + j];
    gvec[g * 128 + j] = acc;
    sGv[g * 128 + j] = acc;
  }
  __syncthreads();
  // 48 channel-mean reductions:
  // [0,5): fmean_p; [5,9): gmean_g; [9,13): A_g=<gvec^2>; [13,33): B_{g,p}=<gvec F_p>;
  // [33,48): C_{p,q}=<F_p F_q> (p<=q, cidx order)
  if (k < 48) {
    const float* va;
    const float* vb = nullptr;
    int t = k;
    if (t < 5) va = &sF2[t * 128];
    else if (t < 9) va = &sGv[(t - 5) * 128];
    else if (t < 13) { va = &sGv[(t - 9) * 128]; vb = va; }
    else if (t < 33) {
      int g = (t - 13) / 5, p = (t - 13) % 5;
      va = &sGv[g * 128]; vb = &sF2[p * 128];
    } else {
      int idx = t - 33;
      int a = 0;
      if (idx >= 14) a = 4;
      else if (idx >= 12) a = 3;
      else if (idx >= 9) a = 2;
      else if (idx >= 5) a = 1;
      const int base[5] = {0, 5, 9, 12, 14};
      int bcol = a + (idx - base[a]);
      va = &sF2[a * 128]; vb = &sF2[bcol * 128];
    }
    float s = 0.f;
    if (vb) { for (int kk = 0; kk < 128; ++kk) s += va[kk] * vb[kk]; }
    else    { for (int kk = 0; kk < 128; ++kk) s += va[kk]; }
    s48[t] = s * (1.f / 128.f);
  }
  __syncthreads();
  if (k < 20) {
    int g = k / 5, p = k % 5;
    MV[g * 5 + p] = s48[p] + (p == 0 ? s48[5 + g] : 0.f);
  }
  if (k < 36) {
    int g = k / 9, kk = k % 9;
    float v = (kk == 0 ? s48[9 + g] : 0.f);
    if (kk < 5) v += 2.f * s48[13 + g * 5 + kk];
#pragma unroll
    for (int p = 0; p < 5; ++p) {
      int q = kk - p;
      if (q >= 0 && q <= 4) v += s48[33 + cidx(p, q)];
    }
    MV[20 + g * 9 + kk] = v;
  }
}

// ---------------------------------------------------------------------------
// transpose+convert out_w1 [1408x512] f32 -> BT [512x1408] bf16. grid 2816, 256
__global__ __launch_bounds__(256) void k_convw1(
    const float* __restrict__ ow1, unsigned short* __restrict__ BT) {
  int idx = blockIdx.x * 256 + threadIdx.x;
  if (idx < 512 * 1408) {
    int n = idx / 1408, k = idx - n * 1408;
    BT[(size_t)n * 1408 + k] = f2bf(ow1[(size_t)k * 512 + n]);
  }
}

// ---------------------------------------------------------------------------
// cand_s / ctx_s masked means -> QIN[0:256) fp32, FB[0:256) bf16. grid B_, 128
__global__ __launch_bounds__(128) void k_candctx(
    const int* __restrict__ ctok, const int* __restrict__ xtok,
    const int* __restrict__ cmask, const int* __restrict__ xmask,
    const float* __restrict__ tok_emb,
    float* __restrict__ QIN, unsigned short* __restrict__ FB) {
  int b = blockIdx.x, j = threadIdx.x;
  float acc = 0.f, cnt = 0.f;
#pragma unroll
  for (int l = 0; l < LC_; ++l) {
    float mv = (float)cmask[b * LC_ + l];
    acc += mv * tok_emb[(size_t)ctok[b * LC_ + l] * 128 + j];
    cnt += mv;
  }
  float cs = acc / fmaxf(cnt, 1.f);
  acc = 0.f; cnt = 0.f;
#pragma unroll
  for (int l = 0; l < LX_; ++l) {
    float mv = (float)xmask[b * LX_ + l];
    acc += mv * tok_emb[(size_t)xtok[b * LX_ + l] * 128 + j];
    cnt += mv;
  }
  float xs = acc / fmaxf(cnt, 1.f);
  QIN[(size_t)b * 896 + j] = cs;
  QIN[(size_t)b * 896 + 128 + j] = xs;
  FB[(size_t)b * 1408 + j] = f2bf(cs);
  FB[(size_t)b * 1408 + 128 + j] = f2bf(xs);
}

// ---------------------------------------------------------------------------
// comp summary, fully analytic LN moments (no cross-lane per row).
// pre = gvec[g] + horner(F,t); mean = poly4(mcoef[g],t); E[x^2] = poly8(vcoef[g],t)
// grid B_, block 256 (4 waves, rows strided by 4; lane covers ch lane, lane+64)
__global__ __launch_bounds__(256) void k_comp_poly(
    const float* __restrict__ times, const int* __restrict__ groups,
    const int* __restrict__ hmask,
    const float* __restrict__ F, const float* __restrict__ gvec,
    const float* __restrict__ MV,
    const float* __restrict__ comp_g, const float* __restrict__ comp_bt,
    float* __restrict__ QIN, unsigned short* __restrict__ FB) {
  __shared__ float sF[5 * 128];
  __shared__ float sG[4 * 128];
  __shared__ float sMV[56];
  __shared__ float sCs[4 * 128];
  int tid = threadIdx.x, b = blockIdx.x;
  int lane = tid & 63, w = tid >> 6;
  for (int idx = tid; idx < 5 * 128; idx += 256) sF[idx] = F[idx];
  for (int idx = tid; idx < 4 * 128; idx += 256) sG[idx] = gvec[idx];
  if (tid < 56) sMV[tid] = MV[tid];
  __syncthreads();
  int j0 = lane, j1 = lane + 64;
  // hoist per-channel F into registers
  float f0a = sF[j0], f1a = sF[128 + j0], f2a = sF[256 + j0], f3a = sF[384 + j0], f4a = sF[512 + j0];
  float f0b = sF[j1], f1b = sF[128 + j1], f2b = sF[256 + j1], f3b = sF[384 + j1], f4b = sF[512 + j1];
  float cg0 = comp_g[j0], cg1 = comp_g[j1], bt0 = comp_bt[j0], bt1 = comp_bt[j1];
  const float* tptr = times + b * LH_;
  const int* gptr = groups + b * LH_;
  const int* mptr = hmask + b * LH_;
  float cnt = 0.f;
  for (int l = lane; l < LH_; l += 64) cnt += (float)mptr[l];
  cnt = wredsum(cnt);
  float cs0 = 0.f, cs1 = 0.f;
  for (int l = w; l < LH_; l += 4) {
    if (!mptr[l]) continue;
    float t = tptr[l];
    int g = gptr[l];
    const float* mc = &sMV[g * 5];
    const float* vc = &sMV[20 + g * 9];
    float mean = (((mc[4] * t + mc[3]) * t + mc[2]) * t + mc[1]) * t + mc[0];
    float e2 = vc[8];
#pragma unroll
    for (int p = 7; p >= 0; --p) e2 = e2 * t + vc[p];
    float var = e2 - mean * mean;
    float rstd = rsqrtf(var + 1e-5f);
    float pre0 = sG[g * 128 + j0] + ((((f4a * t + f3a) * t + f2a) * t + f1a) * t + f0a);
    float pre1 = sG[g * 128 + j1] + ((((f4b * t + f3b) * t + f2b) * t + f1b) * t + f0b);
    cs0 += siluf((pre0 - mean) * rstd * cg0 + bt0);
    cs1 += siluf((pre1 - mean) * rstd * cg1 + bt1);
  }
  sCs[w * 128 + j0] = cs0;
  sCs[w * 128 + j1] = cs1;
  __syncthreads();
  if (tid < 128) {
    float v = sCs[tid] + sCs[128 + tid] + sCs[256 + tid] + sCs[384 + tid];
    float cm = v / fmaxf(cnt, 1.f);
    QIN[(size_t)b * 896 + 256 + tid] = cm;
    FB[(size_t)b * 1408 + 384 + tid] = f2bf(cm);
  }
}

// ---------------------------------------------------------------------------
// dense: LDS-staged GEMM [8 rows x 512], LN, silu -> QIN[384:896), FB[896:1408)
// grid B_/8, block 256
__global__ __launch_bounds__(256) void k_dense(
    const float* __restrict__ df, const float* __restrict__ dw,
    const float* __restrict__ dbias, const float* __restrict__ dg,
    const float* __restrict__ dbt,
    float* __restrict__ QIN, unsigned short* __restrict__ FB) {
  __shared__ float sx[8 * DENSE_];
  __shared__ float sr1[32], sr2[32];
  int tid = threadIdx.x;
  int b0 = blockIdx.x * 8;
  for (int idx = tid; idx < 8 * DENSE_; idx += 256) sx[idx] = df[(size_t)b0 * DENSE_ + idx];
  __syncthreads();
  float a0[8] = {0, 0, 0, 0, 0, 0, 0, 0}, a1[8] = {0, 0, 0, 0, 0, 0, 0, 0};
  for (int k = 0; k < DENSE_; ++k) {
    float w0 = dw[k * H_ + tid];
    float w1 = dw[k * H_ + tid + 256];
#pragma unroll
    for (int r = 0; r < 8; ++r) {
      float x = sx[r * DENSE_ + k];
      a0[r] += x * w0;
      a1[r] += x * w1;
    }
  }
  float bi0 = dbias[tid], bi1 = dbias[tid + 256];
  int wv = tid >> 6;
#pragma unroll
  for (int r = 0; r < 8; ++r) {
    a0[r] += bi0; a1[r] += bi1;
    float s1 = wredsum(a0[r] + a1[r]);
    float s2 = wredsum(a0[r] * a0[r] + a1[r] * a1[r]);
    if ((tid & 63) == 0) { sr1[r * 4 + wv] = s1; sr2[r * 4 + wv] = s2; }
  }
  __syncthreads();
  float g0 = dg[tid], g1 = dg[tid + 256], t0 = dbt[tid], t1 = dbt[tid + 256];
#pragma unroll
  for (int r = 0; r < 8; ++r) {
    float s1 = sr1[r * 4] + sr1[r * 4 + 1] + sr1[r * 4 + 2] + sr1[r * 4 + 3];
    float s2 = sr2[r * 4] + sr2[r * 4 + 1] + sr2[r * 4 + 2] + sr2[r * 4 + 3];
    float mean = s1 / (float)H_;
    float var = s2 / (float)H_ - mean * mean;
    float rstd = rsqrtf(var + 1e-5f);
    float y0 = siluf((a0[r] - mean) * rstd * g0 + t0);
    float y1 = siluf((a1[r] - mean) * rstd * g1 + t1);
    QIN[(size_t)(b0 + r) * 896 + 384 + tid] = y0;
    QIN[(size_t)(b0 + r) * 896 + 384 + tid + 256] = y1;
    FB[(size_t)(b0 + r) * 1408 + 896 + tid] = f2bf(y0);
    FB[(size_t)(b0 + r) * 1408 + 896 + tid + 256] = f2bf(y1);
  }
}

// ---------------------------------------------------------------------------
// query = silu(ln(QIN @ query_w + b)). 8 rows/block; rh=tid>>7 -> rows 0-3/4-7.
// grid B_/8, block 256
__global__ __launch_bounds__(256) void k_query(
    const float* __restrict__ QIN, const float* __restrict__ qw,
    const float* __restrict__ qb, const float* __restrict__ qg,
    const float* __restrict__ qbt, float* __restrict__ query) {
  __shared__ float sx[8 * 896];
  __shared__ float sr1[16], sr2[16];
  int tid = threadIdx.x;
  int b0 = blockIdx.x * 8;
  for (int idx = tid; idx < 8 * 896; idx += 256) sx[idx] = QIN[(size_t)b0 * 896 + idx];
  __syncthreads();
  int j = tid & 127, rh = tid >> 7;
  float acc[4] = {0, 0, 0, 0};
  const float* xb = &sx[rh * 4 * 896];
  for (int k = 0; k < 896; ++k) {
    float w = qw[k * 128 + j];
#pragma unroll
    for (int r = 0; r < 4; ++r) acc[r] += xb[r * 896 + k] * w;
  }
  float bj = qb[j];
  int wh = (tid >> 6) & 1;
#pragma unroll
  for (int r = 0; r < 4; ++r) {
    int rr = rh * 4 + r;
    acc[r] += bj;
    float s1 = wredsum(acc[r]);
    float s2 = wredsum(acc[r] * acc[r]);
    if ((tid & 63) == 0) { sr1[rr * 2 + wh] = s1; sr2[rr * 2 + wh] = s2; }
  }
  __syncthreads();
  float gj = qg[j], tj = qbt[j];
#pragma unroll
  for (int r = 0; r < 4; ++r) {
    int rr = rh * 4 + r;
    float s1 = sr1[rr * 2] + sr1[rr * 2 + 1];
    float s2 = sr2[rr * 2] + sr2[rr * 2 + 1];
    float mean = s1 / 128.f, var = s2 / 128.f - mean * mean;
    float rstd = rsqrtf(var + 1e-5f);
    query[(size_t)(b0 + rr) * 128 + j] = siluf((acc[r] - mean) * rstd * gj + tj);
  }
}

// ---------------------------------------------------------------------------
// single-pass online-softmax attention; lane covers channel pair (2l, 2l+1)
// so each embedding-table read is one dwordx2. grid B_, block 256
__global__ __launch_bounds__(256) void k_attn3(
    const int* __restrict__ htok, const int* __restrict__ hpos,
    const int* __restrict__ hgrp, const int* __restrict__ hmask,
    const float* __restrict__ times,
    const float* __restrict__ tok_emb, const float* __restrict__ pos_emb,
    const float* __restrict__ grp_emb,
    const float* __restrict__ query, const float* __restrict__ E,
    unsigned short* __restrict__ FB) {
  __shared__ float sq[128];
  __shared__ float sE[5 * 128];
  __shared__ float sG[4 * 128];
  __shared__ float st[LH_];
  __shared__ int stok[LH_], spos[LH_], sgrp[LH_], smk[LH_];
  __shared__ float seq[5 * 2];
  __shared__ float s_eq[5];
  __shared__ float sA[4 * 128];
  __shared__ float sL[4];
  __shared__ float sM[4 * 5];
  int tid = threadIdx.x, b = blockIdx.x;
  int lane = tid & 63, w = tid >> 6;
  if (tid < 128) sq[tid] = query[b * 128 + tid];
  for (int idx = tid; idx < 5 * 128; idx += 256) sE[idx] = E[idx];
  for (int idx = tid; idx < 4 * 128; idx += 256) sG[idx] = grp_emb[idx];
  for (int l = tid; l < LH_; l += 256) {
    st[l] = times[b * LH_ + l];
    stok[l] = htok[b * LH_ + l];
    spos[l] = hpos[b * LH_ + l];
    sgrp[l] = hgrp[b * LH_ + l];
    smk[l] = hmask[b * LH_ + l];
  }
  __syncthreads();
  // eq_p = E_p . q
  if (tid < 128) {
    int wh = (tid >> 6) & 1;
#pragma unroll
    for (int p = 0; p < 5; ++p) {
      float v = sE[p * 128 + tid] * sq[tid];
      v = wredsum(v);
      if ((tid & 63) == 0) seq[p * 2 + wh] = v;
    }
  }
  __syncthreads();
  if (tid < 5) s_eq[tid] = seq[tid * 2] + seq[tid * 2 + 1];
  __syncthreads();
  float2 qv = *(const float2*)&sq[2 * lane];
  const float scale = 0.08838834764831845f;  // 1/sqrt(128)
  float acc0 = 0.f, acc1 = 0.f, lsum = 0.f;
  float mom1 = 0.f, mom2 = 0.f, mom3 = 0.f, mom4 = 0.f;
  for (int l = w; l < LH_; l += 4) {
    if (smk[l]) {
      int tok = stok[l], pos = spos[l], g = sgrp[l];
      float2 tv = *(const float2*)&tok_emb[(size_t)tok * 128 + 2 * lane];
      float2 pv = *(const float2*)&pos_emb[pos * 128 + 2 * lane];
      float2 gv = *(const float2*)&sG[g * 128 + 2 * lane];
      float v0 = tv.x + pv.x + gv.x;
      float v1 = tv.y + pv.y + gv.y;
      float t = st[l];
      float dot = wredsum(v0 * qv.x + v1 * qv.y);
      float poly = (((s_eq[4] * t + s_eq[3]) * t + s_eq[2]) * t + s_eq[1]) * t + s_eq[0];
      float e = __expf((dot + poly) * scale);
      lsum += e;
      acc0 += e * v0;
      acc1 += e * v1;
      float tp = e * t;
      mom1 += tp; tp *= t;
      mom2 += tp; tp *= t;
      mom3 += tp; tp *= t;
      mom4 += tp;
    }
  }
  sA[w * 128 + 2 * lane] = acc0;
  sA[w * 128 + 2 * lane + 1] = acc1;
  if (lane == 0) {
    sL[w] = lsum;
    sM[w * 5 + 1] = mom1; sM[w * 5 + 2] = mom2;
    sM[w * 5 + 3] = mom3; sM[w * 5 + 4] = mom4;
  }
  __syncthreads();
  if (tid < 128) {
    int i = tid;
    float L = sL[0] + sL[1] + sL[2] + sL[3];
    float inv = 1.f / L;
    float v = (sA[i] + sA[128 + i] + sA[256 + i] + sA[384 + i]) * inv;
    v += sE[i];  // p=0 term (normalized moment = 1)
#pragma unroll
    for (int p = 1; p < 5; ++p) {
      float mp = (sM[0 * 5 + p] + sM[1 * 5 + p] + sM[2 * 5 + p] + sM[3 * 5 + p]) * inv;
      v += mp * sE[p * 128 + i];
    }
    unsigned short* row = FB + (size_t)b * 1408;
    float c = bf2f(row[i]), cm = bf2f(row[384 + i]);
    row[256 + i] = f2bf(v);
    row[512 + i] = f2bf(c * v);
    row[640 + i] = f2bf(c * cm);
    row[768 + i] = f2bf(fabsf(v - cm));
  }
}

// ---------------------------------------------------------------------------
// GEMM1 via bf16 MFMA: H1[2048x512] = FB @ BT^T. Tile 64(M) x 64(N) per block
// (4 waves, each wave 16 rows x 64 cols); frags straight from global.
// grid 256 (32 mtiles x 8 ntiles), block 256.
__global__ __launch_bounds__(256) void k_gemm1(
    const unsigned short* __restrict__ A, const unsigned short* __restrict__ BT,
    float* __restrict__ H1) {
  int tid = threadIdx.x;
  int bm = blockIdx.x >> 3;   // 0..31
  int bn = blockIdx.x & 7;    // 0..7
  int w = tid >> 6, lane = tid & 63;
  int m = lane & 15, quad = lane >> 4;
  const unsigned short* ap = A + (size_t)(bm * 64 + w * 16 + m) * 1408 + quad * 8;
  const unsigned short* bp0 = BT + (size_t)(bn * 64 + m) * 1408 + quad * 8;
  const unsigned short* bp1 = bp0 + 16 * 1408;
  const unsigned short* bp2 = bp0 + 32 * 1408;
  const unsigned short* bp3 = bp0 + 48 * 1408;
  floatx4 acc0 = {0.f, 0.f, 0.f, 0.f};
  floatx4 acc1 = {0.f, 0.f, 0.f, 0.f};
  floatx4 acc2 = {0.f, 0.f, 0.f, 0.f};
  floatx4 acc3 = {0.f, 0.f, 0.f, 0.f};
#pragma unroll 4
  for (int kc = 0; kc < 1408; kc += 32) {
    short8v af = *(const short8v*)&ap[kc];
    short8v b0 = *(const short8v*)&bp0[kc];
    short8v b1 = *(const short8v*)&bp1[kc];
    short8v b2 = *(const short8v*)&bp2[kc];
    short8v b3 = *(const short8v*)&bp3[kc];
    acc0 = __builtin_amdgcn_mfma_f32_16x16x32_bf16(af, b0, acc0, 0, 0, 0);
    acc1 = __builtin_amdgcn_mfma_f32_16x16x32_bf16(af, b1, acc1, 0, 0, 0);
    acc2 = __builtin_amdgcn_mfma_f32_16x16x32_bf16(af, b2, acc2, 0, 0, 0);
    acc3 = __builtin_amdgcn_mfma_f32_16x16x32_bf16(af, b3, acc3, 0, 0, 0);
  }
  // C/D layout: col = lane&15, row = quad*4 + reg
  int row = bm * 64 + w * 16 + quad * 4;
  int col = bn * 64 + m;
#pragma unroll
  for (int r = 0; r < 4; ++r) {
    H1[(size_t)(row + r) * 512 + col] = acc0[r];
    H1[(size_t)(row + r) * 512 + col + 16] = acc1[r];
    H1[(size_t)(row + r) * 512 + col + 32] = acc2[r];
    H1[(size_t)(row + r) * 512 + col + 48] = acc3[r];
  }
}

// ---------------------------------------------------------------------------
// post: h1 = silu(ln(H1 + ob1)); h2 = silu(h1 @ ow2 + ob2); out = h2 @ ow3 + ob3
// grid B_/8, block 256 (8 rows/block)
__global__ __launch_bounds__(256) void k_post(
    const float* __restrict__ H1, const float* __restrict__ ob1,
    const float* __restrict__ og, const float* __restrict__ obt,
    const float* __restrict__ ow2, const float* __restrict__ ob2,
    const float* __restrict__ ow3, const float* __restrict__ ob3,
    float* __restrict__ out) {
  __shared__ float sh1[8 * 512];
  __shared__ float sr1[32], sr2[32];
  __shared__ float sdot[16];
  int tid = threadIdx.x;
  int b0 = blockIdx.x * 8;
  int wv = tid >> 6;
  float bi0 = ob1[tid], bi1 = ob1[tid + 256];
  float a0[8], a1[8];
#pragma unroll
  for (int r = 0; r < 8; ++r) {
    a0[r] = H1[(size_t)(b0 + r) * 512 + tid] + bi0;
    a1[r] = H1[(size_t)(b0 + r) * 512 + tid + 256] + bi1;
    float s1 = wredsum(a0[r] + a1[r]);
    float s2 = wredsum(a0[r] * a0[r] + a1[r] * a1[r]);
    if ((tid & 63) == 0) { sr1[r * 4 + wv] = s1; sr2[r * 4 + wv] = s2; }
  }
  __syncthreads();
  float g0 = og[tid], g1 = og[tid + 256], t0 = obt[tid], t1 = obt[tid + 256];
#pragma unroll
  for (int r = 0; r < 8; ++r) {
    float s1 = sr1[r * 4] + sr1[r * 4 + 1] + sr1[r * 4 + 2] + sr1[r * 4 + 3];
    float s2 = sr2[r * 4] + sr2[r * 4 + 1] + sr2[r * 4 + 2] + sr2[r * 4 + 3];
    float mean = s1 / 512.f, var = s2 / 512.f - mean * mean;
    float rstd = rsqrtf(var + 1e-5f);
    sh1[r * 512 + tid] = siluf((a0[r] - mean) * rstd * g0 + t0);
    sh1[r * 512 + tid + 256] = siluf((a1[r] - mean) * rstd * g1 + t1);
  }
  __syncthreads();
  int c = tid & 127, rg = tid >> 7;
  const float* h1b = &sh1[rg * 4 * 512];
  float acca[4] = {0, 0, 0, 0}, accb[4] = {0, 0, 0, 0};
  for (int k = 0; k < 512; k += 4) {
    float w00 = ow2[(k + 0) * 256 + c], w01 = ow2[(k + 0) * 256 + c + 128];
    float w10 = ow2[(k + 1) * 256 + c], w11 = ow2[(k + 1) * 256 + c + 128];
    float w20 = ow2[(k + 2) * 256 + c], w21 = ow2[(k + 2) * 256 + c + 128];
    float w30 = ow2[(k + 3) * 256 + c], w31 = ow2[(k + 3) * 256 + c + 128];
#pragma unroll
    for (int r = 0; r < 4; ++r) {
      const float4 x = *(const float4*)&h1b[r * 512 + k];
      acca[r] += x.x * w00 + x.y * w10 + x.z * w20 + x.w * w30;
      accb[r] += x.x * w01 + x.y * w11 + x.z * w21 + x.w * w31;
    }
  }
  float b2a = ob2[c], b2b = ob2[c + 128];
  float w3a = ow3[c], w3b = ow3[c + 128];
#pragma unroll
  for (int r = 0; r < 4; ++r) {
    float h2a = siluf(acca[r] + b2a);
    float h2b = siluf(accb[r] + b2b);
    float p = wredsum(h2a * w3a + h2b * w3b);
    if ((tid & 63) == 0) sdot[(rg * 4 + r) * 2 + (wv & 1)] = p;
  }
  __syncthreads();
  if (tid < 8) out[b0 + tid] = sdot[tid * 2] + sdot[tid * 2 + 1] + ob3[0];
}

// ---------------------------------------------------------------------------
extern "C" void kernel_launch(void* const* d_in, const int* in_sizes, int n_in,
                              void* d_out, int out_size, void* d_ws, size_t ws_size,
                              hipStream_t stream) {
  const int* cand_tok = (const int*)d_in[0];
  const int* ctx_tok = (const int*)d_in[1];
  const int* hist_tok = (const int*)d_in[2];
  const int* hist_pos = (const int*)d_in[3];
  const int* hist_grp = (const int*)d_in[4];
  const int* cand_mask = (const int*)d_in[5];
  const int* ctx_mask = (const int*)d_in[6];
  const int* hist_mask = (const int*)d_in[7];
  const float* hist_times = (const float*)d_in[8];
  const float* dense_feat = (const float*)d_in[9];
  const float* tok_emb = (const float*)d_in[10];
  const float* pos_emb = (const float*)d_in[11];
  const float* grp_emb = (const float*)d_in[12];
  const float* time_w1 = (const float*)d_in[13];
  const float* time_b1 = (const float*)d_in[14];
  const float* time_w2 = (const float*)d_in[15];
  const float* time_b2 = (const float*)d_in[16];
  const float* comp_w = (const float*)d_in[17];
  const float* comp_b = (const float*)d_in[18];
  const float* comp_g = (const float*)d_in[19];
  const float* comp_bt = (const float*)d_in[20];
  const float* dense_w = (const float*)d_in[21];
  const float* dense_b = (const float*)d_in[22];
  const float* dense_g = (const float*)d_in[23];
  const float* dense_bt = (const float*)d_in[24];
  const float* query_w = (const float*)d_in[25];
  const float* query_b = (const float*)d_in[26];
  const float* query_g = (const float*)d_in[27];
  const float* query_bt = (const float*)d_in[28];
  const float* out_w1 = (const float*)d_in[29];
  const float* out_b1 = (const float*)d_in[30];
  const float* out_g = (const float*)d_in[31];
  const float* out_bt = (const float*)d_in[32];
  const float* out_w2 = (const float*)d_in[33];
  const float* out_b2 = (const float*)d_in[34];
  const float* out_w3 = (const float*)d_in[35];
  const float* out_b3 = (const float*)d_in[36];
  float* out = (float*)d_out;

  float* ws = (float*)d_ws;
  float* E = ws;                                    // 640
  float* F = ws + 640;                              // 640
  float* gvec = ws + 1280;                          // 512
  float* MV = ws + 1792;                            // 56 (pad to 2048)
  float* query = ws + 2048;                         // 262144
  float* QIN = ws + 264192;                         // 2048*896 = 1835008
  float* H1 = ws + 2099200;                         // 2048*512 = 1048576
  unsigned short* FB = (unsigned short*)(ws + 3147776);    // 2048*1408 u16
  unsigned short* OW1BT = (unsigned short*)(ws + 4589568); // 512*1408 u16

  k0_poly<<<1, 128, 0, stream>>>(time_w1, time_b1, time_w2, time_b2,
                                 comp_w, comp_b, grp_emb, E, F, gvec, MV);
  k_convw1<<<2816, 256, 0, stream>>>(out_w1, OW1BT);
  k_candctx<<<B_, 128, 0, stream>>>(cand_tok, ctx_tok, cand_mask, ctx_mask,
                                    tok_emb, QIN, FB);
  k_comp_poly<<<B_, 256, 0, stream>>>(hist_times, hist_grp, hist_mask,
                                      F, gvec, MV, comp_g, comp_bt, QIN, FB);
  k_dense<<<B_ / 8, 256, 0, stream>>>(dense_feat, dense_w, dense_b, dense_g, dense_bt,
                                      QIN, FB);
  k_query<<<B_ / 8, 256, 0, stream>>>(QIN, query_w, query_b, query_g, query_bt, query);
  k_attn3<<<B_, 256, 0, stream>>>(hist_tok, hist_pos, hist_grp, hist_mask, hist_times,
                                  tok_emb, pos_emb, grp_emb, query, E, FB);
  k_gemm1<<<256, 256, 0, stream>>>(FB, OW1BT, H1);
  k_post<<<B_ / 8, 256, 0, stream>>>(H1, out_b1, out_g, out_bt,
                                     out_w2, out_b2, out_w3, out_b3, out);
}

// Round 8
// 384.122 us; speedup vs baseline: 1.6013x; 1.0655x over previous
//
#include <hip/hip_runtime.h>
#include <hip/hip_bf16.h>

#define B_ 2048
#define LC_ 20
#define LX_ 20
#define LH_ 200
#define D_ 128
#define H_ 512
#define DENSE_ 256

typedef __attribute__((ext_vector_type(8))) short short8v;
typedef __attribute__((ext_vector_type(4))) float floatx4;

__device__ __forceinline__ float siluf(float x) { return x / (1.f + __expf(-x)); }

__device__ __forceinline__ unsigned short f2bf(float f) {
  return __builtin_bit_cast(unsigned short, __float2bfloat16(f));
}
__device__ __forceinline__ float bf2f(unsigned short u) {
  return __bfloat162float(__builtin_bit_cast(__hip_bfloat16, u));
}

__device__ __forceinline__ float wredsum(float v) {
#pragma unroll
  for (int off = 32; off > 0; off >>= 1) v += __shfl_xor(v, off, 64);
  return v;
}

// pair index into the 15-entry upper-triangular (p<=q, 5x5) list
__device__ __forceinline__ int cidx(int a, int b) {
  if (a > b) { int t = a; a = b; b = t; }
  const int base[5] = {0, 5, 9, 12, 14};
  return base[a] + (b - a);
}

// ---------------------------------------------------------------------------
// K0 (1 block, 128 threads): degree-4 poly of u(t)=silu(t*w1+b1) per channel;
// E_p = c_p @ W2 (E_0 += time_b2); F_p = E_p @ comp_w[128:,:] (F_0 += comp_b);
// gvec[g] = grp_emb[g] @ comp_w[:128,:].
// Also analytic LN moments: MV[0:20) mean poly (deg4), MV[20:56) E[x^2] poly (deg8).
__global__ __launch_bounds__(128) void k0_poly(
    const float* __restrict__ w1, const float* __restrict__ b1,
    const float* __restrict__ W2, const float* __restrict__ b2,
    const float* __restrict__ comp_w, const float* __restrict__ comp_b,
    const float* __restrict__ grp_emb,
    float* __restrict__ E, float* __restrict__ F, float* __restrict__ gvec,
    float* __restrict__ MV) {
  __shared__ float sc[5 * 128];
  __shared__ float sE[5 * 128];
  __shared__ float sF2[5 * 128];
  __shared__ float sGv[4 * 128];
  __shared__ float s48[48];
  int k = threadIdx.x;
  {
    float w = w1[k], bb = b1[k];
    float y0 = siluf(bb);
    float y1 = siluf(0.25f * w + bb);
    float y2 = siluf(0.50f * w + bb);
    float y3 = siluf(0.75f * w + bb);
    float y4 = siluf(w + bb);
    float d1 = y1 - y0;
    float d2 = y2 - 2.f * y1 + y0;
    float d3 = y3 - 3.f * y2 + 3.f * y1 - y0;
    float d4 = y4 - 4.f * y3 + 6.f * y2 - 4.f * y1 + y0;
    float c0 = y0;
    float c1 = d1 - 0.5f * d2 + d3 * (1.f / 3.f) - 0.25f * d4;
    float c2 = 0.5f * d2 - 0.5f * d3 + (11.f / 24.f) * d4;
    float c3 = d3 * (1.f / 6.f) - 0.25f * d4;
    float c4 = d4 * (1.f / 24.f);
    sc[0 * 128 + k] = c0;
    sc[1 * 128 + k] = c1 * 4.f;
    sc[2 * 128 + k] = c2 * 16.f;
    sc[3 * 128 + k] = c3 * 64.f;
    sc[4 * 128 + k] = c4 * 256.f;
  }
  __syncthreads();
  int j = k;
  float e[5] = {0, 0, 0, 0, 0};
  for (int kk = 0; kk < 128; ++kk) {
    float wv = W2[kk * 128 + j];
#pragma unroll
    for (int p = 0; p < 5; ++p) e[p] += sc[p * 128 + kk] * wv;
  }
  e[0] += b2[j];
#pragma unroll
  for (int p = 0; p < 5; ++p) { sE[p * 128 + j] = e[p]; E[p * 128 + j] = e[p]; }
  __syncthreads();
  float f[5] = {0, 0, 0, 0, 0};
  for (int kk = 0; kk < 128; ++kk) {
    float wv = comp_w[(128 + kk) * 128 + j];
#pragma unroll
    for (int p = 0; p < 5; ++p) f[p] += sE[p * 128 + kk] * wv;
  }
  f[0] += comp_b[j];
#pragma unroll
  for (int p = 0; p < 5; ++p) { F[p * 128 + j] = f[p]; sF2[p * 128 + j] = f[p]; }
  for (int g = 0; g < 4; ++g) {
    float acc = 0.f;
    for (int kk = 0; kk < 128; ++kk) acc += grp_emb[g * 128 + kk] * comp_w[kk * 128 + j];
    gvec[g * 128 + j] = acc;
    sGv[g * 128 + j] = acc;
  }
  __syncthreads();
  if (k < 48) {
    const float* va;
    const float* vb = nullptr;
    int t = k;
    if (t < 5) va = &sF2[t * 128];
    else if (t < 9) va = &sGv[(t - 5) * 128];
    else if (t < 13) { va = &sGv[(t - 9) * 128]; vb = va; }
    else if (t < 33) {
      int g = (t - 13) / 5, p = (t - 13) % 5;
      va = &sGv[g * 128]; vb = &sF2[p * 128];
    } else {
      int idx = t - 33;
      int a = 0;
      if (idx >= 14) a = 4;
      else if (idx >= 12) a = 3;
      else if (idx >= 9) a = 2;
      else if (idx >= 5) a = 1;
      const int base[5] = {0, 5, 9, 12, 14};
      int bcol = a + (idx - base[a]);
      va = &sF2[a * 128]; vb = &sF2[bcol * 128];
    }
    float s = 0.f;
    if (vb) { for (int kk = 0; kk < 128; ++kk) s += va[kk] * vb[kk]; }
    else    { for (int kk = 0; kk < 128; ++kk) s += va[kk]; }
    s48[t] = s * (1.f / 128.f);
  }
  __syncthreads();
  if (k < 20) {
    int g = k / 5, p = k % 5;
    MV[g * 5 + p] = s48[p] + (p == 0 ? s48[5 + g] : 0.f);
  }
  if (k < 36) {
    int g = k / 9, kk = k % 9;
    float v = (kk == 0 ? s48[9 + g] : 0.f);
    if (kk < 5) v += 2.f * s48[13 + g * 5 + kk];
#pragma unroll
    for (int p = 0; p < 5; ++p) {
      int q = kk - p;
      if (q >= 0 && q <= 4) v += s48[33 + cidx(p, q)];
    }
    MV[20 + g * 9 + kk] = v;
  }
}

// ---------------------------------------------------------------------------
// transpose+convert out_w1 [1408x512] f32 -> BT [512x1408] bf16. grid 2816, 256
__global__ __launch_bounds__(256) void k_convw1(
    const float* __restrict__ ow1, unsigned short* __restrict__ BT) {
  int idx = blockIdx.x * 256 + threadIdx.x;
  if (idx < 512 * 1408) {
    int n = idx / 1408, k = idx - n * 1408;
    BT[(size_t)n * 1408 + k] = f2bf(ow1[(size_t)k * 512 + n]);
  }
}

// transpose+convert ow2 [512x256] f32 -> BT2 [256x512] bf16. grid 512, 256
__global__ __launch_bounds__(256) void k_convw2(
    const float* __restrict__ ow2, unsigned short* __restrict__ BT2) {
  int idx = blockIdx.x * 256 + threadIdx.x;
  int n = idx >> 9, k = idx & 511;
  BT2[(size_t)n * 512 + k] = f2bf(ow2[(size_t)k * 256 + n]);
}

// ---------------------------------------------------------------------------
// cand_s / ctx_s masked means -> QIN[0:256) fp32, FB[0:256) bf16. grid B_, 128
__global__ __launch_bounds__(128) void k_candctx(
    const int* __restrict__ ctok, const int* __restrict__ xtok,
    const int* __restrict__ cmask, const int* __restrict__ xmask,
    const float* __restrict__ tok_emb,
    float* __restrict__ QIN, unsigned short* __restrict__ FB) {
  int b = blockIdx.x, j = threadIdx.x;
  float acc = 0.f, cnt = 0.f;
#pragma unroll
  for (int l = 0; l < LC_; ++l) {
    float mv = (float)cmask[b * LC_ + l];
    acc += mv * tok_emb[(size_t)ctok[b * LC_ + l] * 128 + j];
    cnt += mv;
  }
  float cs = acc / fmaxf(cnt, 1.f);
  acc = 0.f; cnt = 0.f;
#pragma unroll
  for (int l = 0; l < LX_; ++l) {
    float mv = (float)xmask[b * LX_ + l];
    acc += mv * tok_emb[(size_t)xtok[b * LX_ + l] * 128 + j];
    cnt += mv;
  }
  float xs = acc / fmaxf(cnt, 1.f);
  QIN[(size_t)b * 896 + j] = cs;
  QIN[(size_t)b * 896 + 128 + j] = xs;
  FB[(size_t)b * 1408 + j] = f2bf(cs);
  FB[(size_t)b * 1408 + 128 + j] = f2bf(xs);
}

// ---------------------------------------------------------------------------
// comp summary, fully analytic LN moments. grid B_, block 256
__global__ __launch_bounds__(256) void k_comp_poly(
    const float* __restrict__ times, const int* __restrict__ groups,
    const int* __restrict__ hmask,
    const float* __restrict__ F, const float* __restrict__ gvec,
    const float* __restrict__ MV,
    const float* __restrict__ comp_g, const float* __restrict__ comp_bt,
    float* __restrict__ QIN, unsigned short* __restrict__ FB) {
  __shared__ float sF[5 * 128];
  __shared__ float sG[4 * 128];
  __shared__ float sMV[56];
  __shared__ float sCs[4 * 128];
  int tid = threadIdx.x, b = blockIdx.x;
  int lane = tid & 63, w = tid >> 6;
  for (int idx = tid; idx < 5 * 128; idx += 256) sF[idx] = F[idx];
  for (int idx = tid; idx < 4 * 128; idx += 256) sG[idx] = gvec[idx];
  if (tid < 56) sMV[tid] = MV[tid];
  __syncthreads();
  int j0 = lane, j1 = lane + 64;
  float f0a = sF[j0], f1a = sF[128 + j0], f2a = sF[256 + j0], f3a = sF[384 + j0], f4a = sF[512 + j0];
  float f0b = sF[j1], f1b = sF[128 + j1], f2b = sF[256 + j1], f3b = sF[384 + j1], f4b = sF[512 + j1];
  float cg0 = comp_g[j0], cg1 = comp_g[j1], bt0 = comp_bt[j0], bt1 = comp_bt[j1];
  const float* tptr = times + b * LH_;
  const int* gptr = groups + b * LH_;
  const int* mptr = hmask + b * LH_;
  float cnt = 0.f;
  for (int l = lane; l < LH_; l += 64) cnt += (float)mptr[l];
  cnt = wredsum(cnt);
  float cs0 = 0.f, cs1 = 0.f;
  for (int l = w; l < LH_; l += 4) {
    if (!mptr[l]) continue;
    float t = tptr[l];
    int g = gptr[l];
    const float* mc = &sMV[g * 5];
    const float* vc = &sMV[20 + g * 9];
    float mean = (((mc[4] * t + mc[3]) * t + mc[2]) * t + mc[1]) * t + mc[0];
    float e2 = vc[8];
#pragma unroll
    for (int p = 7; p >= 0; --p) e2 = e2 * t + vc[p];
    float var = e2 - mean * mean;
    float rstd = rsqrtf(var + 1e-5f);
    float pre0 = sG[g * 128 + j0] + ((((f4a * t + f3a) * t + f2a) * t + f1a) * t + f0a);
    float pre1 = sG[g * 128 + j1] + ((((f4b * t + f3b) * t + f2b) * t + f1b) * t + f0b);
    cs0 += siluf((pre0 - mean) * rstd * cg0 + bt0);
    cs1 += siluf((pre1 - mean) * rstd * cg1 + bt1);
  }
  sCs[w * 128 + j0] = cs0;
  sCs[w * 128 + j1] = cs1;
  __syncthreads();
  if (tid < 128) {
    float v = sCs[tid] + sCs[128 + tid] + sCs[256 + tid] + sCs[384 + tid];
    float cm = v / fmaxf(cnt, 1.f);
    QIN[(size_t)b * 896 + 256 + tid] = cm;
    FB[(size_t)b * 1408 + 384 + tid] = f2bf(cm);
  }
}

// ---------------------------------------------------------------------------
// dense: LDS-staged GEMM [8 rows x 512], LN, silu -> QIN[384:896), FB[896:1408)
// grid B_/8, block 256
__global__ __launch_bounds__(256) void k_dense(
    const float* __restrict__ df, const float* __restrict__ dw,
    const float* __restrict__ dbias, const float* __restrict__ dg,
    const float* __restrict__ dbt,
    float* __restrict__ QIN, unsigned short* __restrict__ FB) {
  __shared__ float sx[8 * DENSE_];
  __shared__ float sr1[32], sr2[32];
  int tid = threadIdx.x;
  int b0 = blockIdx.x * 8;
  for (int idx = tid; idx < 8 * DENSE_; idx += 256) sx[idx] = df[(size_t)b0 * DENSE_ + idx];
  __syncthreads();
  float a0[8] = {0, 0, 0, 0, 0, 0, 0, 0}, a1[8] = {0, 0, 0, 0, 0, 0, 0, 0};
  for (int k = 0; k < DENSE_; ++k) {
    float w0 = dw[k * H_ + tid];
    float w1 = dw[k * H_ + tid + 256];
#pragma unroll
    for (int r = 0; r < 8; ++r) {
      float x = sx[r * DENSE_ + k];
      a0[r] += x * w0;
      a1[r] += x * w1;
    }
  }
  float bi0 = dbias[tid], bi1 = dbias[tid + 256];
  int wv = tid >> 6;
#pragma unroll
  for (int r = 0; r < 8; ++r) {
    a0[r] += bi0; a1[r] += bi1;
    float s1 = wredsum(a0[r] + a1[r]);
    float s2 = wredsum(a0[r] * a0[r] + a1[r] * a1[r]);
    if ((tid & 63) == 0) { sr1[r * 4 + wv] = s1; sr2[r * 4 + wv] = s2; }
  }
  __syncthreads();
  float g0 = dg[tid], g1 = dg[tid + 256], t0 = dbt[tid], t1 = dbt[tid + 256];
#pragma unroll
  for (int r = 0; r < 8; ++r) {
    float s1 = sr1[r * 4] + sr1[r * 4 + 1] + sr1[r * 4 + 2] + sr1[r * 4 + 3];
    float s2 = sr2[r * 4] + sr2[r * 4 + 1] + sr2[r * 4 + 2] + sr2[r * 4 + 3];
    float mean = s1 / (float)H_;
    float var = s2 / (float)H_ - mean * mean;
    float rstd = rsqrtf(var + 1e-5f);
    float y0 = siluf((a0[r] - mean) * rstd * g0 + t0);
    float y1 = siluf((a1[r] - mean) * rstd * g1 + t1);
    QIN[(size_t)(b0 + r) * 896 + 384 + tid] = y0;
    QIN[(size_t)(b0 + r) * 896 + 384 + tid + 256] = y1;
    FB[(size_t)(b0 + r) * 1408 + 896 + tid] = f2bf(y0);
    FB[(size_t)(b0 + r) * 1408 + 896 + tid + 256] = f2bf(y1);
  }
}

// ---------------------------------------------------------------------------
// query = silu(ln(QIN @ query_w + b)). 8 rows/block. grid B_/8, block 256
__global__ __launch_bounds__(256) void k_query(
    const float* __restrict__ QIN, const float* __restrict__ qw,
    const float* __restrict__ qb, const float* __restrict__ qg,
    const float* __restrict__ qbt, float* __restrict__ query) {
  __shared__ float sx[8 * 896];
  __shared__ float sr1[16], sr2[16];
  int tid = threadIdx.x;
  int b0 = blockIdx.x * 8;
  for (int idx = tid; idx < 8 * 896; idx += 256) sx[idx] = QIN[(size_t)b0 * 896 + idx];
  __syncthreads();
  int j = tid & 127, rh = tid >> 7;
  float acc[4] = {0, 0, 0, 0};
  const float* xb = &sx[rh * 4 * 896];
  for (int k = 0; k < 896; ++k) {
    float w = qw[k * 128 + j];
#pragma unroll
    for (int r = 0; r < 4; ++r) acc[r] += xb[r * 896 + k] * w;
  }
  float bj = qb[j];
  int wh = (tid >> 6) & 1;
#pragma unroll
  for (int r = 0; r < 4; ++r) {
    int rr = rh * 4 + r;
    acc[r] += bj;
    float s1 = wredsum(acc[r]);
    float s2 = wredsum(acc[r] * acc[r]);
    if ((tid & 63) == 0) { sr1[rr * 2 + wh] = s1; sr2[rr * 2 + wh] = s2; }
  }
  __syncthreads();
  float gj = qg[j], tj = qbt[j];
#pragma unroll
  for (int r = 0; r < 4; ++r) {
    int rr = rh * 4 + r;
    float s1 = sr1[rr * 2] + sr1[rr * 2 + 1];
    float s2 = sr2[rr * 2] + sr2[rr * 2 + 1];
    float mean = s1 / 128.f, var = s2 / 128.f - mean * mean;
    float rstd = rsqrtf(var + 1e-5f);
    query[(size_t)(b0 + rr) * 128 + j] = siluf((acc[r] - mean) * rstd * gj + tj);
  }
}

// ---------------------------------------------------------------------------
// single-pass online-softmax attention; lane covers channel pair (2l, 2l+1).
// grid B_, block 256
__global__ __launch_bounds__(256) void k_attn3(
    const int* __restrict__ htok, const int* __restrict__ hpos,
    const int* __restrict__ hgrp, const int* __restrict__ hmask,
    const float* __restrict__ times,
    const float* __restrict__ tok_emb, const float* __restrict__ pos_emb,
    const float* __restrict__ grp_emb,
    const float* __restrict__ query, const float* __restrict__ E,
    unsigned short* __restrict__ FB) {
  __shared__ float sq[128];
  __shared__ float sE[5 * 128];
  __shared__ float sG[4 * 128];
  __shared__ float st[LH_];
  __shared__ int stok[LH_], spos[LH_], sgrp[LH_], smk[LH_];
  __shared__ float seq[5 * 2];
  __shared__ float s_eq[5];
  __shared__ float sA[4 * 128];
  __shared__ float sL[4];
  __shared__ float sM[4 * 5];
  int tid = threadIdx.x, b = blockIdx.x;
  int lane = tid & 63, w = tid >> 6;
  if (tid < 128) sq[tid] = query[b * 128 + tid];
  for (int idx = tid; idx < 5 * 128; idx += 256) sE[idx] = E[idx];
  for (int idx = tid; idx < 4 * 128; idx += 256) sG[idx] = grp_emb[idx];
  for (int l = tid; l < LH_; l += 256) {
    st[l] = times[b * LH_ + l];
    stok[l] = htok[b * LH_ + l];
    spos[l] = hpos[b * LH_ + l];
    sgrp[l] = hgrp[b * LH_ + l];
    smk[l] = hmask[b * LH_ + l];
  }
  __syncthreads();
  if (tid < 128) {
    int wh = (tid >> 6) & 1;
#pragma unroll
    for (int p = 0; p < 5; ++p) {
      float v = sE[p * 128 + tid] * sq[tid];
      v = wredsum(v);
      if ((tid & 63) == 0) seq[p * 2 + wh] = v;
    }
  }
  __syncthreads();
  if (tid < 5) s_eq[tid] = seq[tid * 2] + seq[tid * 2 + 1];
  __syncthreads();
  float2 qv = *(const float2*)&sq[2 * lane];
  const float scale = 0.08838834764831845f;  // 1/sqrt(128)
  float acc0 = 0.f, acc1 = 0.f, lsum = 0.f;
  float mom1 = 0.f, mom2 = 0.f, mom3 = 0.f, mom4 = 0.f;
  for (int l = w; l < LH_; l += 4) {
    if (smk[l]) {
      int tok = stok[l], pos = spos[l], g = sgrp[l];
      float2 tv = *(const float2*)&tok_emb[(size_t)tok * 128 + 2 * lane];
      float2 pv = *(const float2*)&pos_emb[pos * 128 + 2 * lane];
      float2 gv = *(const float2*)&sG[g * 128 + 2 * lane];
      float v0 = tv.x + pv.x + gv.x;
      float v1 = tv.y + pv.y + gv.y;
      float t = st[l];
      float dot = wredsum(v0 * qv.x + v1 * qv.y);
      float poly = (((s_eq[4] * t + s_eq[3]) * t + s_eq[2]) * t + s_eq[1]) * t + s_eq[0];
      float e = __expf((dot + poly) * scale);
      lsum += e;
      acc0 += e * v0;
      acc1 += e * v1;
      float tp = e * t;
      mom1 += tp; tp *= t;
      mom2 += tp; tp *= t;
      mom3 += tp; tp *= t;
      mom4 += tp;
    }
  }
  sA[w * 128 + 2 * lane] = acc0;
  sA[w * 128 + 2 * lane + 1] = acc1;
  if (lane == 0) {
    sL[w] = lsum;
    sM[w * 5 + 1] = mom1; sM[w * 5 + 2] = mom2;
    sM[w * 5 + 3] = mom3; sM[w * 5 + 4] = mom4;
  }
  __syncthreads();
  if (tid < 128) {
    int i = tid;
    float L = sL[0] + sL[1] + sL[2] + sL[3];
    float inv = 1.f / L;
    float v = (sA[i] + sA[128 + i] + sA[256 + i] + sA[384 + i]) * inv;
    v += sE[i];
#pragma unroll
    for (int p = 1; p < 5; ++p) {
      float mp = (sM[0 * 5 + p] + sM[1 * 5 + p] + sM[2 * 5 + p] + sM[3 * 5 + p]) * inv;
      v += mp * sE[p * 128 + i];
    }
    unsigned short* row = FB + (size_t)b * 1408;
    float c = bf2f(row[i]), cm = bf2f(row[384 + i]);
    row[256 + i] = f2bf(v);
    row[512 + i] = f2bf(c * v);
    row[640 + i] = f2bf(c * cm);
    row[768 + i] = f2bf(fabsf(v - cm));
  }
}

// ---------------------------------------------------------------------------
// GEMM1 via bf16 MFMA: H1[2048x512] = FB @ OW1BT^T. Tile 64x64, grid 256, 256.
__global__ __launch_bounds__(256) void k_gemm1(
    const unsigned short* __restrict__ A, const unsigned short* __restrict__ BT,
    float* __restrict__ H1) {
  int tid = threadIdx.x;
  int bm = blockIdx.x >> 3;
  int bn = blockIdx.x & 7;
  int w = tid >> 6, lane = tid & 63;
  int m = lane & 15, quad = lane >> 4;
  const unsigned short* ap = A + (size_t)(bm * 64 + w * 16 + m) * 1408 + quad * 8;
  const unsigned short* bp0 = BT + (size_t)(bn * 64 + m) * 1408 + quad * 8;
  const unsigned short* bp1 = bp0 + 16 * 1408;
  const unsigned short* bp2 = bp0 + 32 * 1408;
  const unsigned short* bp3 = bp0 + 48 * 1408;
  floatx4 acc0 = {0.f, 0.f, 0.f, 0.f};
  floatx4 acc1 = {0.f, 0.f, 0.f, 0.f};
  floatx4 acc2 = {0.f, 0.f, 0.f, 0.f};
  floatx4 acc3 = {0.f, 0.f, 0.f, 0.f};
#pragma unroll 4
  for (int kc = 0; kc < 1408; kc += 32) {
    short8v af = *(const short8v*)&ap[kc];
    short8v b0 = *(const short8v*)&bp0[kc];
    short8v b1 = *(const short8v*)&bp1[kc];
    short8v b2 = *(const short8v*)&bp2[kc];
    short8v b3 = *(const short8v*)&bp3[kc];
    acc0 = __builtin_amdgcn_mfma_f32_16x16x32_bf16(af, b0, acc0, 0, 0, 0);
    acc1 = __builtin_amdgcn_mfma_f32_16x16x32_bf16(af, b1, acc1, 0, 0, 0);
    acc2 = __builtin_amdgcn_mfma_f32_16x16x32_bf16(af, b2, acc2, 0, 0, 0);
    acc3 = __builtin_amdgcn_mfma_f32_16x16x32_bf16(af, b3, acc3, 0, 0, 0);
  }
  int row = bm * 64 + w * 16 + quad * 4;
  int col = bn * 64 + m;
#pragma unroll
  for (int r = 0; r < 4; ++r) {
    H1[(size_t)(row + r) * 512 + col] = acc0[r];
    H1[(size_t)(row + r) * 512 + col + 16] = acc1[r];
    H1[(size_t)(row + r) * 512 + col + 32] = acc2[r];
    H1[(size_t)(row + r) * 512 + col + 48] = acc3[r];
  }
}

// ---------------------------------------------------------------------------
// LN+silu on H1 (+ob1) -> H1S bf16. 4 rows/block, grid B_/4, block 256
__global__ __launch_bounds__(256) void k_ln1(
    const float* __restrict__ H1, const float* __restrict__ ob1,
    const float* __restrict__ og, const float* __restrict__ obt,
    unsigned short* __restrict__ H1S) {
  __shared__ float sr1[16], sr2[16];
  int tid = threadIdx.x;
  int b0 = blockIdx.x * 4;
  int wv = tid >> 6;
  float bi0 = ob1[tid], bi1 = ob1[tid + 256];
  float a0[4], a1[4];
#pragma unroll
  for (int r = 0; r < 4; ++r) {
    a0[r] = H1[(size_t)(b0 + r) * 512 + tid] + bi0;
    a1[r] = H1[(size_t)(b0 + r) * 512 + tid + 256] + bi1;
    float s1 = wredsum(a0[r] + a1[r]);
    float s2 = wredsum(a0[r] * a0[r] + a1[r] * a1[r]);
    if ((tid & 63) == 0) { sr1[r * 4 + wv] = s1; sr2[r * 4 + wv] = s2; }
  }
  __syncthreads();
  float g0 = og[tid], g1 = og[tid + 256], t0 = obt[tid], t1 = obt[tid + 256];
#pragma unroll
  for (int r = 0; r < 4; ++r) {
    float s1 = sr1[r * 4] + sr1[r * 4 + 1] + sr1[r * 4 + 2] + sr1[r * 4 + 3];
    float s2 = sr2[r * 4] + sr2[r * 4 + 1] + sr2[r * 4 + 2] + sr2[r * 4 + 3];
    float mean = s1 / 512.f, var = s2 / 512.f - mean * mean;
    float rstd = rsqrtf(var + 1e-5f);
    H1S[(size_t)(b0 + r) * 512 + tid] = f2bf(siluf((a0[r] - mean) * rstd * g0 + t0));
    H1S[(size_t)(b0 + r) * 512 + tid + 256] = f2bf(siluf((a1[r] - mean) * rstd * g1 + t1));
  }
}

// ---------------------------------------------------------------------------
// GEMM2 via bf16 MFMA: H2[2048x256] = H1S @ OW2BT^T. Tile 64(M)x32(N),
// grid 256 (32m x 8n), block 256.
__global__ __launch_bounds__(256) void k_gemm2(
    const unsigned short* __restrict__ A, const unsigned short* __restrict__ BT,
    float* __restrict__ H2) {
  int tid = threadIdx.x;
  int bm = blockIdx.x >> 3;
  int bn = blockIdx.x & 7;
  int w = tid >> 6, lane = tid & 63;
  int m = lane & 15, quad = lane >> 4;
  const unsigned short* ap = A + (size_t)(bm * 64 + w * 16 + m) * 512 + quad * 8;
  const unsigned short* bp0 = BT + (size_t)(bn * 32 + m) * 512 + quad * 8;
  const unsigned short* bp1 = bp0 + 16 * 512;
  floatx4 acc0 = {0.f, 0.f, 0.f, 0.f};
  floatx4 acc1 = {0.f, 0.f, 0.f, 0.f};
#pragma unroll
  for (int kc = 0; kc < 512; kc += 32) {
    short8v af = *(const short8v*)&ap[kc];
    short8v b0 = *(const short8v*)&bp0[kc];
    short8v b1 = *(const short8v*)&bp1[kc];
    acc0 = __builtin_amdgcn_mfma_f32_16x16x32_bf16(af, b0, acc0, 0, 0, 0);
    acc1 = __builtin_amdgcn_mfma_f32_16x16x32_bf16(af, b1, acc1, 0, 0, 0);
  }
  int row = bm * 64 + w * 16 + quad * 4;
  int col = bn * 32 + m;
#pragma unroll
  for (int r = 0; r < 4; ++r) {
    H2[(size_t)(row + r) * 256 + col] = acc0[r];
    H2[(size_t)(row + r) * 256 + col + 16] = acc1[r];
  }
}

// ---------------------------------------------------------------------------
// out[b] = sum_c silu(H2[b,c]+ob2[c])*ow3[c] + ob3. 8 rows/block, grid B_/8, 256
__global__ __launch_bounds__(256) void k_out(
    const float* __restrict__ H2, const float* __restrict__ ob2,
    const float* __restrict__ ow3, const float* __restrict__ ob3,
    float* __restrict__ out) {
  __shared__ float sdot[32];
  int tid = threadIdx.x;
  int b0 = blockIdx.x * 8;
  int wv = tid >> 6;
  float b2 = ob2[tid], w3 = ow3[tid];
#pragma unroll
  for (int r = 0; r < 8; ++r) {
    float v = siluf(H2[(size_t)(b0 + r) * 256 + tid] + b2) * w3;
    v = wredsum(v);
    if ((tid & 63) == 0) sdot[r * 4 + wv] = v;
  }
  __syncthreads();
  if (tid < 8) {
    out[b0 + tid] = sdot[tid * 4] + sdot[tid * 4 + 1] + sdot[tid * 4 + 2] + sdot[tid * 4 + 3] +
                    ob3[0];
  }
}

// ---------------------------------------------------------------------------
extern "C" void kernel_launch(void* const* d_in, const int* in_sizes, int n_in,
                              void* d_out, int out_size, void* d_ws, size_t ws_size,
                              hipStream_t stream) {
  const int* cand_tok = (const int*)d_in[0];
  const int* ctx_tok = (const int*)d_in[1];
  const int* hist_tok = (const int*)d_in[2];
  const int* hist_pos = (const int*)d_in[3];
  const int* hist_grp = (const int*)d_in[4];
  const int* cand_mask = (const int*)d_in[5];
  const int* ctx_mask = (const int*)d_in[6];
  const int* hist_mask = (const int*)d_in[7];
  const float* hist_times = (const float*)d_in[8];
  const float* dense_feat = (const float*)d_in[9];
  const float* tok_emb = (const float*)d_in[10];
  const float* pos_emb = (const float*)d_in[11];
  const float* grp_emb = (const float*)d_in[12];
  const float* time_w1 = (const float*)d_in[13];
  const float* time_b1 = (const float*)d_in[14];
  const float* time_w2 = (const float*)d_in[15];
  const float* time_b2 = (const float*)d_in[16];
  const float* comp_w = (const float*)d_in[17];
  const float* comp_b = (const float*)d_in[18];
  const float* comp_g = (const float*)d_in[19];
  const float* comp_bt = (const float*)d_in[20];
  const float* dense_w = (const float*)d_in[21];
  const float* dense_b = (const float*)d_in[22];
  const float* dense_g = (const float*)d_in[23];
  const float* dense_bt = (const float*)d_in[24];
  const float* query_w = (const float*)d_in[25];
  const float* query_b = (const float*)d_in[26];
  const float* query_g = (const float*)d_in[27];
  const float* query_bt = (const float*)d_in[28];
  const float* out_w1 = (const float*)d_in[29];
  const float* out_b1 = (const float*)d_in[30];
  const float* out_g = (const float*)d_in[31];
  const float* out_bt = (const float*)d_in[32];
  const float* out_w2 = (const float*)d_in[33];
  const float* out_b2 = (const float*)d_in[34];
  const float* out_w3 = (const float*)d_in[35];
  const float* out_b3 = (const float*)d_in[36];
  float* out = (float*)d_out;

  // Workspace layout — packed into the SAME 4,950,016-float footprint that
  // passed rounds 4-6 (round 7 overflowed ws_size by placing new buffers past
  // the end). New buffers alias dead regions:
  //   H1S  aliases query (dead after k_attn3; k_ln1 writes it after)
  //   H2   aliases QIN[0:524288) (dead after k_query)
  //   OW2BT aliases QIN[524288:589824) — k_convw2 launched AFTER k_query
  float* ws = (float*)d_ws;
  float* E = ws;                                    // 640
  float* F = ws + 640;                              // 640
  float* gvec = ws + 1280;                          // 512
  float* MV = ws + 1792;                            // 56 (pad to 2048)
  float* query = ws + 2048;                         // 262144
  unsigned short* H1S = (unsigned short*)(ws + 2048);      // aliases query
  float* QIN = ws + 264192;                         // 1835008
  float* H2 = QIN;                                  // 524288 (aliases dead QIN)
  unsigned short* OW2BT = (unsigned short*)(ws + 264192 + 524288); // 65536 fl
  float* H1 = ws + 2099200;                         // 1048576
  unsigned short* FB = (unsigned short*)(ws + 3147776);    // 1441792 fl
  unsigned short* OW1BT = (unsigned short*)(ws + 4589568); // 360448 fl
  // total = 4950016 floats (19.8 MB) — verified-fitting footprint

  k0_poly<<<1, 128, 0, stream>>>(time_w1, time_b1, time_w2, time_b2,
                                 comp_w, comp_b, grp_emb, E, F, gvec, MV);
  k_convw1<<<2816, 256, 0, stream>>>(out_w1, OW1BT);
  k_candctx<<<B_, 128, 0, stream>>>(cand_tok, ctx_tok, cand_mask, ctx_mask,
                                    tok_emb, QIN, FB);
  k_comp_poly<<<B_, 256, 0, stream>>>(hist_times, hist_grp, hist_mask,
                                      F, gvec, MV, comp_g, comp_bt, QIN, FB);
  k_dense<<<B_ / 8, 256, 0, stream>>>(dense_feat, dense_w, dense_b, dense_g, dense_bt,
                                      QIN, FB);
  k_query<<<B_ / 8, 256, 0, stream>>>(QIN, query_w, query_b, query_g, query_bt, query);
  k_convw2<<<512, 256, 0, stream>>>(out_w2, OW2BT);  // after k_query: QIN dead
  k_attn3<<<B_, 256, 0, stream>>>(hist_tok, hist_pos, hist_grp, hist_mask, hist_times,
                                  tok_emb, pos_emb, grp_emb, query, E, FB);
  k_gemm1<<<256, 256, 0, stream>>>(FB, OW1BT, H1);
  k_ln1<<<B_ / 4, 256, 0, stream>>>(H1, out_b1, out_g, out_bt, H1S);
  k_gemm2<<<256, 256, 0, stream>>>(H1S, OW2BT, H2);
  k_out<<<B_ / 8, 256, 0, stream>>>(H2, out_b2, out_w3, out_b3, out);
}

// Round 9
// 373.375 us; speedup vs baseline: 1.6474x; 1.0288x over previous
//
#include <hip/hip_runtime.h>
#include <hip/hip_bf16.h>

#define B_ 2048
#define LC_ 20
#define LX_ 20
#define LH_ 200
#define D_ 128
#define H_ 512
#define DENSE_ 256

typedef __attribute__((ext_vector_type(8))) short short8v;
typedef __attribute__((ext_vector_type(4))) float floatx4;

__device__ __forceinline__ float siluf(float x) { return x / (1.f + __expf(-x)); }

__device__ __forceinline__ unsigned short f2bf(float f) {
  return __builtin_bit_cast(unsigned short, __float2bfloat16(f));
}
__device__ __forceinline__ float bf2f(unsigned short u) {
  return __bfloat162float(__builtin_bit_cast(__hip_bfloat16, u));
}

__device__ __forceinline__ float wredsum(float v) {
#pragma unroll
  for (int off = 32; off > 0; off >>= 1) v += __shfl_xor(v, off, 64);
  return v;
}

// pair index into the 15-entry upper-triangular (p<=q, 5x5) list
__device__ __forceinline__ int cidx(int a, int b) {
  if (a > b) { int t = a; a = b; b = t; }
  const int base[5] = {0, 5, 9, 12, 14};
  return base[a] + (b - a);
}

// ---------------------------------------------------------------------------
// K0 (1 block, 128 threads): degree-4 poly of u(t)=silu(t*w1+b1) per channel;
// E_p = c_p @ W2 (E_0 += time_b2); F_p = E_p @ comp_w[128:,:] (F_0 += comp_b);
// gvec[g] = grp_emb[g] @ comp_w[:128,:].
// Also analytic LN moments: MV[0:20) mean poly (deg4), MV[20:56) E[x^2] poly (deg8).
__global__ __launch_bounds__(128) void k0_poly(
    const float* __restrict__ w1, const float* __restrict__ b1,
    const float* __restrict__ W2, const float* __restrict__ b2,
    const float* __restrict__ comp_w, const float* __restrict__ comp_b,
    const float* __restrict__ grp_emb,
    float* __restrict__ E, float* __restrict__ F, float* __restrict__ gvec,
    float* __restrict__ MV) {
  __shared__ float sc[5 * 128];
  __shared__ float sE[5 * 128];
  __shared__ float sF2[5 * 128];
  __shared__ float sGv[4 * 128];
  __shared__ float s48[48];
  int k = threadIdx.x;
  {
    float w = w1[k], bb = b1[k];
    float y0 = siluf(bb);
    float y1 = siluf(0.25f * w + bb);
    float y2 = siluf(0.50f * w + bb);
    float y3 = siluf(0.75f * w + bb);
    float y4 = siluf(w + bb);
    float d1 = y1 - y0;
    float d2 = y2 - 2.f * y1 + y0;
    float d3 = y3 - 3.f * y2 + 3.f * y1 - y0;
    float d4 = y4 - 4.f * y3 + 6.f * y2 - 4.f * y1 + y0;
    float c0 = y0;
    float c1 = d1 - 0.5f * d2 + d3 * (1.f / 3.f) - 0.25f * d4;
    float c2 = 0.5f * d2 - 0.5f * d3 + (11.f / 24.f) * d4;
    float c3 = d3 * (1.f / 6.f) - 0.25f * d4;
    float c4 = d4 * (1.f / 24.f);
    sc[0 * 128 + k] = c0;
    sc[1 * 128 + k] = c1 * 4.f;
    sc[2 * 128 + k] = c2 * 16.f;
    sc[3 * 128 + k] = c3 * 64.f;
    sc[4 * 128 + k] = c4 * 256.f;
  }
  __syncthreads();
  int j = k;
  float e[5] = {0, 0, 0, 0, 0};
  for (int kk = 0; kk < 128; ++kk) {
    float wv = W2[kk * 128 + j];
#pragma unroll
    for (int p = 0; p < 5; ++p) e[p] += sc[p * 128 + kk] * wv;
  }
  e[0] += b2[j];
#pragma unroll
  for (int p = 0; p < 5; ++p) { sE[p * 128 + j] = e[p]; E[p * 128 + j] = e[p]; }
  __syncthreads();
  float f[5] = {0, 0, 0, 0, 0};
  for (int kk = 0; kk < 128; ++kk) {
    float wv = comp_w[(128 + kk) * 128 + j];
#pragma unroll
    for (int p = 0; p < 5; ++p) f[p] += sE[p * 128 + kk] * wv;
  }
  f[0] += comp_b[j];
#pragma unroll
  for (int p = 0; p < 5; ++p) { F[p * 128 + j] = f[p]; sF2[p * 128 + j] = f[p]; }
  for (int g = 0; g < 4; ++g) {
    float acc = 0.f;
    for (int kk = 0; kk < 128; ++kk) acc += grp_emb[g * 128 + kk] * comp_w[kk * 128 + j];
    gvec[g * 128 + j] = acc;
    sGv[g * 128 + j] = acc;
  }
  __syncthreads();
  if (k < 48) {
    const float* va;
    const float* vb = nullptr;
    int t = k;
    if (t < 5) va = &sF2[t * 128];
    else if (t < 9) va = &sGv[(t - 5) * 128];
    else if (t < 13) { va = &sGv[(t - 9) * 128]; vb = va; }
    else if (t < 33) {
      int g = (t - 13) / 5, p = (t - 13) % 5;
      va = &sGv[g * 128]; vb = &sF2[p * 128];
    } else {
      int idx = t - 33;
      int a = 0;
      if (idx >= 14) a = 4;
      else if (idx >= 12) a = 3;
      else if (idx >= 9) a = 2;
      else if (idx >= 5) a = 1;
      const int base[5] = {0, 5, 9, 12, 14};
      int bcol = a + (idx - base[a]);
      va = &sF2[a * 128]; vb = &sF2[bcol * 128];
    }
    float s = 0.f;
    if (vb) { for (int kk = 0; kk < 128; ++kk) s += va[kk] * vb[kk]; }
    else    { for (int kk = 0; kk < 128; ++kk) s += va[kk]; }
    s48[t] = s * (1.f / 128.f);
  }
  __syncthreads();
  if (k < 20) {
    int g = k / 5, p = k % 5;
    MV[g * 5 + p] = s48[p] + (p == 0 ? s48[5 + g] : 0.f);
  }
  if (k < 36) {
    int g = k / 9, kk = k % 9;
    float v = (kk == 0 ? s48[9 + g] : 0.f);
    if (kk < 5) v += 2.f * s48[13 + g * 5 + kk];
#pragma unroll
    for (int p = 0; p < 5; ++p) {
      int q = kk - p;
      if (q >= 0 && q <= 4) v += s48[33 + cidx(p, q)];
    }
    MV[20 + g * 9 + kk] = v;
  }
}

// ---------------------------------------------------------------------------
// weight conversions
__global__ __launch_bounds__(256) void k_convw1(
    const float* __restrict__ ow1, unsigned short* __restrict__ BT) {
  int idx = blockIdx.x * 256 + threadIdx.x;
  if (idx < 512 * 1408) {
    int n = idx / 1408, k = idx - n * 1408;
    BT[(size_t)n * 1408 + k] = f2bf(ow1[(size_t)k * 512 + n]);
  }
}

__global__ __launch_bounds__(256) void k_convw2(
    const float* __restrict__ ow2, unsigned short* __restrict__ BT2) {
  int idx = blockIdx.x * 256 + threadIdx.x;
  int n = idx >> 9, k = idx & 511;
  BT2[(size_t)n * 512 + k] = f2bf(ow2[(size_t)k * 256 + n]);
}

// query_w [896][128] -> QWBT [128][896] bf16. grid 448, 256
__global__ __launch_bounds__(256) void k_convqw(
    const float* __restrict__ qw, unsigned short* __restrict__ QWBT) {
  int idx = blockIdx.x * 256 + threadIdx.x;
  if (idx < 128 * 896) {
    int n = idx / 896, k = idx - n * 896;
    QWBT[(size_t)n * 896 + k] = f2bf(qw[(size_t)k * 128 + n]);
  }
}

// dense_w [256][512] -> DWBT [512][256] bf16. grid 512, 256
__global__ __launch_bounds__(256) void k_convdw(
    const float* __restrict__ dw, unsigned short* __restrict__ DWBT) {
  int idx = blockIdx.x * 256 + threadIdx.x;
  int n = idx >> 8, k = idx & 255;
  DWBT[(size_t)n * 256 + k] = f2bf(dw[(size_t)k * 512 + n]);
}

// dense_features f32 -> DB bf16 [2048][256]. grid 2048, 256
__global__ __launch_bounds__(256) void k_convdf(
    const float* __restrict__ df, unsigned short* __restrict__ DB) {
  int idx = blockIdx.x * 256 + threadIdx.x;
  DB[idx] = f2bf(df[idx]);
}

// ---------------------------------------------------------------------------
// cand_s / ctx_s masked means -> FB[0:256) bf16. grid B_, 128
__global__ __launch_bounds__(128) void k_candctx(
    const int* __restrict__ ctok, const int* __restrict__ xtok,
    const int* __restrict__ cmask, const int* __restrict__ xmask,
    const float* __restrict__ tok_emb, unsigned short* __restrict__ FB) {
  int b = blockIdx.x, j = threadIdx.x;
  float acc = 0.f, cnt = 0.f;
#pragma unroll
  for (int l = 0; l < LC_; ++l) {
    float mv = (float)cmask[b * LC_ + l];
    acc += mv * tok_emb[(size_t)ctok[b * LC_ + l] * 128 + j];
    cnt += mv;
  }
  float cs = acc / fmaxf(cnt, 1.f);
  acc = 0.f; cnt = 0.f;
#pragma unroll
  for (int l = 0; l < LX_; ++l) {
    float mv = (float)xmask[b * LX_ + l];
    acc += mv * tok_emb[(size_t)xtok[b * LX_ + l] * 128 + j];
    cnt += mv;
  }
  float xs = acc / fmaxf(cnt, 1.f);
  FB[(size_t)b * 1408 + j] = f2bf(cs);
  FB[(size_t)b * 1408 + 128 + j] = f2bf(xs);
}

// ---------------------------------------------------------------------------
// comp summary, fully analytic LN moments -> FB[384:512) bf16. grid B_, 256
__global__ __launch_bounds__(256) void k_comp_poly(
    const float* __restrict__ times, const int* __restrict__ groups,
    const int* __restrict__ hmask,
    const float* __restrict__ F, const float* __restrict__ gvec,
    const float* __restrict__ MV,
    const float* __restrict__ comp_g, const float* __restrict__ comp_bt,
    unsigned short* __restrict__ FB) {
  __shared__ float sF[5 * 128];
  __shared__ float sG[4 * 128];
  __shared__ float sMV[56];
  __shared__ float sCs[4 * 128];
  int tid = threadIdx.x, b = blockIdx.x;
  int lane = tid & 63, w = tid >> 6;
  for (int idx = tid; idx < 5 * 128; idx += 256) sF[idx] = F[idx];
  for (int idx = tid; idx < 4 * 128; idx += 256) sG[idx] = gvec[idx];
  if (tid < 56) sMV[tid] = MV[tid];
  __syncthreads();
  int j0 = lane, j1 = lane + 64;
  float f0a = sF[j0], f1a = sF[128 + j0], f2a = sF[256 + j0], f3a = sF[384 + j0], f4a = sF[512 + j0];
  float f0b = sF[j1], f1b = sF[128 + j1], f2b = sF[256 + j1], f3b = sF[384 + j1], f4b = sF[512 + j1];
  float cg0 = comp_g[j0], cg1 = comp_g[j1], bt0 = comp_bt[j0], bt1 = comp_bt[j1];
  const float* tptr = times + b * LH_;
  const int* gptr = groups + b * LH_;
  const int* mptr = hmask + b * LH_;
  float cnt = 0.f;
  for (int l = lane; l < LH_; l += 64) cnt += (float)mptr[l];
  cnt = wredsum(cnt);
  float cs0 = 0.f, cs1 = 0.f;
  for (int l = w; l < LH_; l += 4) {
    if (!mptr[l]) continue;
    float t = tptr[l];
    int g = gptr[l];
    const float* mc = &sMV[g * 5];
    const float* vc = &sMV[20 + g * 9];
    float mean = (((mc[4] * t + mc[3]) * t + mc[2]) * t + mc[1]) * t + mc[0];
    float e2 = vc[8];
#pragma unroll
    for (int p = 7; p >= 0; --p) e2 = e2 * t + vc[p];
    float var = e2 - mean * mean;
    float rstd = rsqrtf(var + 1e-5f);
    float pre0 = sG[g * 128 + j0] + ((((f4a * t + f3a) * t + f2a) * t + f1a) * t + f0a);
    float pre1 = sG[g * 128 + j1] + ((((f4b * t + f3b) * t + f2b) * t + f1b) * t + f0b);
    cs0 += siluf((pre0 - mean) * rstd * cg0 + bt0);
    cs1 += siluf((pre1 - mean) * rstd * cg1 + bt1);
  }
  sCs[w * 128 + j0] = cs0;
  sCs[w * 128 + j1] = cs1;
  __syncthreads();
  if (tid < 128) {
    float v = sCs[tid] + sCs[128 + tid] + sCs[256 + tid] + sCs[384 + tid];
    float cm = v / fmaxf(cnt, 1.f);
    FB[(size_t)b * 1408 + 384 + tid] = f2bf(cm);
  }
}

// ---------------------------------------------------------------------------
// dense GEMM via bf16 MFMA: H_D[2048x512] = DB @ DWBT^T (no bias). Tile 64x64,
// grid 256 (32m x 8n), block 256.
__global__ __launch_bounds__(256) void k_gemm_d(
    const unsigned short* __restrict__ A, const unsigned short* __restrict__ BT,
    float* __restrict__ HD) {
  int tid = threadIdx.x;
  int bm = blockIdx.x >> 3;
  int bn = blockIdx.x & 7;
  int w = tid >> 6, lane = tid & 63;
  int m = lane & 15, quad = lane >> 4;
  const unsigned short* ap = A + (size_t)(bm * 64 + w * 16 + m) * 256 + quad * 8;
  const unsigned short* bp0 = BT + (size_t)(bn * 64 + m) * 256 + quad * 8;
  const unsigned short* bp1 = bp0 + 16 * 256;
  const unsigned short* bp2 = bp0 + 32 * 256;
  const unsigned short* bp3 = bp0 + 48 * 256;
  floatx4 acc0 = {0.f, 0.f, 0.f, 0.f};
  floatx4 acc1 = {0.f, 0.f, 0.f, 0.f};
  floatx4 acc2 = {0.f, 0.f, 0.f, 0.f};
  floatx4 acc3 = {0.f, 0.f, 0.f, 0.f};
#pragma unroll
  for (int kc = 0; kc < 256; kc += 32) {
    short8v af = *(const short8v*)&ap[kc];
    short8v b0 = *(const short8v*)&bp0[kc];
    short8v b1 = *(const short8v*)&bp1[kc];
    short8v b2 = *(const short8v*)&bp2[kc];
    short8v b3 = *(const short8v*)&bp3[kc];
    acc0 = __builtin_amdgcn_mfma_f32_16x16x32_bf16(af, b0, acc0, 0, 0, 0);
    acc1 = __builtin_amdgcn_mfma_f32_16x16x32_bf16(af, b1, acc1, 0, 0, 0);
    acc2 = __builtin_amdgcn_mfma_f32_16x16x32_bf16(af, b2, acc2, 0, 0, 0);
    acc3 = __builtin_amdgcn_mfma_f32_16x16x32_bf16(af, b3, acc3, 0, 0, 0);
  }
  int row = bm * 64 + w * 16 + quad * 4;
  int col = bn * 64 + m;
#pragma unroll
  for (int r = 0; r < 4; ++r) {
    HD[(size_t)(row + r) * 512 + col] = acc0[r];
    HD[(size_t)(row + r) * 512 + col + 16] = acc1[r];
    HD[(size_t)(row + r) * 512 + col + 32] = acc2[r];
    HD[(size_t)(row + r) * 512 + col + 48] = acc3[r];
  }
}

// ---------------------------------------------------------------------------
// bias+LN+silu on H_D -> FB[896:1408) bf16. 4 rows/block, grid B_/4, block 256
__global__ __launch_bounds__(256) void k_dense_ln(
    const float* __restrict__ HD, const float* __restrict__ dbias,
    const float* __restrict__ dg, const float* __restrict__ dbt,
    unsigned short* __restrict__ FB) {
  __shared__ float sr1[16], sr2[16];
  int tid = threadIdx.x;
  int b0 = blockIdx.x * 4;
  int wv = tid >> 6;
  float bi0 = dbias[tid], bi1 = dbias[tid + 256];
  float a0[4], a1[4];
#pragma unroll
  for (int r = 0; r < 4; ++r) {
    a0[r] = HD[(size_t)(b0 + r) * 512 + tid] + bi0;
    a1[r] = HD[(size_t)(b0 + r) * 512 + tid + 256] + bi1;
    float s1 = wredsum(a0[r] + a1[r]);
    float s2 = wredsum(a0[r] * a0[r] + a1[r] * a1[r]);
    if ((tid & 63) == 0) { sr1[r * 4 + wv] = s1; sr2[r * 4 + wv] = s2; }
  }
  __syncthreads();
  float g0 = dg[tid], g1 = dg[tid + 256], t0 = dbt[tid], t1 = dbt[tid + 256];
#pragma unroll
  for (int r = 0; r < 4; ++r) {
    float s1 = sr1[r * 4] + sr1[r * 4 + 1] + sr1[r * 4 + 2] + sr1[r * 4 + 3];
    float s2 = sr2[r * 4] + sr2[r * 4 + 1] + sr2[r * 4 + 2] + sr2[r * 4 + 3];
    float mean = s1 / 512.f, var = s2 / 512.f - mean * mean;
    float rstd = rsqrtf(var + 1e-5f);
    FB[(size_t)(b0 + r) * 1408 + 896 + tid] = f2bf(siluf((a0[r] - mean) * rstd * g0 + t0));
    FB[(size_t)(b0 + r) * 1408 + 896 + tid + 256] = f2bf(siluf((a1[r] - mean) * rstd * g1 + t1));
  }
}

// ---------------------------------------------------------------------------
// query via bf16 MFMA, A straight from FB (28 K-chunks map concat inputs),
// fused LN+silu epilogue via quad shuffles. Tile 64M x 128N, grid 32, block 256.
__global__ __launch_bounds__(256) void k_query_mfma(
    const unsigned short* __restrict__ FB, const unsigned short* __restrict__ QWBT,
    const float* __restrict__ qb, const float* __restrict__ qg,
    const float* __restrict__ qbt, float* __restrict__ query) {
  int tid = threadIdx.x;
  int w = tid >> 6, lane = tid & 63;
  int m = lane & 15, quad = lane >> 4;
  const unsigned short* ap = FB + (size_t)(blockIdx.x * 64 + w * 16 + m) * 1408 + quad * 8;
  const unsigned short* bp = QWBT + (size_t)m * 896 + quad * 8;
  floatx4 acc[8];
#pragma unroll
  for (int nt = 0; nt < 8; ++nt) acc[nt] = {0.f, 0.f, 0.f, 0.f};
#pragma unroll 4
  for (int kc = 0; kc < 28; ++kc) {
    int fo = (kc < 8) ? kc * 32 : (kc < 12 ? 384 + (kc - 8) * 32 : 896 + (kc - 12) * 32);
    short8v af = *(const short8v*)&ap[fo];
#pragma unroll
    for (int nt = 0; nt < 8; ++nt) {
      short8v bf = *(const short8v*)&bp[(size_t)nt * 16 * 896 + kc * 32];
      acc[nt] = __builtin_amdgcn_mfma_f32_16x16x32_bf16(af, bf, acc[nt], 0, 0, 0);
    }
  }
  float bj[8], gj[8], tj[8];
#pragma unroll
  for (int nt = 0; nt < 8; ++nt) {
    bj[nt] = qb[nt * 16 + m];
    gj[nt] = qg[nt * 16 + m];
    tj[nt] = qbt[nt * 16 + m];
  }
#pragma unroll
  for (int r = 0; r < 4; ++r) {
    float x[8];
    float s1 = 0.f, s2 = 0.f;
#pragma unroll
    for (int nt = 0; nt < 8; ++nt) {
      x[nt] = acc[nt][r] + bj[nt];
      s1 += x[nt];
      s2 += x[nt] * x[nt];
    }
#pragma unroll
    for (int off = 1; off < 16; off <<= 1) {
      s1 += __shfl_xor(s1, off, 64);
      s2 += __shfl_xor(s2, off, 64);
    }
    float mean = s1 * (1.f / 128.f);
    float var = s2 * (1.f / 128.f) - mean * mean;
    float rstd = rsqrtf(var + 1e-5f);
    int row = blockIdx.x * 64 + w * 16 + quad * 4 + r;
#pragma unroll
    for (int nt = 0; nt < 8; ++nt) {
      query[(size_t)row * 128 + nt * 16 + m] = siluf((x[nt] - mean) * rstd * gj[nt] + tj[nt]);
    }
  }
}

// ---------------------------------------------------------------------------
// single-pass online-softmax attention; lane covers channel pair (2l, 2l+1).
// grid B_, block 256
__global__ __launch_bounds__(256) void k_attn3(
    const int* __restrict__ htok, const int* __restrict__ hpos,
    const int* __restrict__ hgrp, const int* __restrict__ hmask,
    const float* __restrict__ times,
    const float* __restrict__ tok_emb, const float* __restrict__ pos_emb,
    const float* __restrict__ grp_emb,
    const float* __restrict__ query, const float* __restrict__ E,
    unsigned short* __restrict__ FB) {
  __shared__ float sq[128];
  __shared__ float sE[5 * 128];
  __shared__ float sG[4 * 128];
  __shared__ float st[LH_];
  __shared__ int stok[LH_], spos[LH_], sgrp[LH_], smk[LH_];
  __shared__ float seq[5 * 2];
  __shared__ float s_eq[5];
  __shared__ float sA[4 * 128];
  __shared__ float sL[4];
  __shared__ float sM[4 * 5];
  int tid = threadIdx.x, b = blockIdx.x;
  int lane = tid & 63, w = tid >> 6;
  if (tid < 128) sq[tid] = query[b * 128 + tid];
  for (int idx = tid; idx < 5 * 128; idx += 256) sE[idx] = E[idx];
  for (int idx = tid; idx < 4 * 128; idx += 256) sG[idx] = grp_emb[idx];
  for (int l = tid; l < LH_; l += 256) {
    st[l] = times[b * LH_ + l];
    stok[l] = htok[b * LH_ + l];
    spos[l] = hpos[b * LH_ + l];
    sgrp[l] = hgrp[b * LH_ + l];
    smk[l] = hmask[b * LH_ + l];
  }
  __syncthreads();
  if (tid < 128) {
    int wh = (tid >> 6) & 1;
#pragma unroll
    for (int p = 0; p < 5; ++p) {
      float v = sE[p * 128 + tid] * sq[tid];
      v = wredsum(v);
      if ((tid & 63) == 0) seq[p * 2 + wh] = v;
    }
  }
  __syncthreads();
  if (tid < 5) s_eq[tid] = seq[tid * 2] + seq[tid * 2 + 1];
  __syncthreads();
  float2 qv = *(const float2*)&sq[2 * lane];
  const float scale = 0.08838834764831845f;  // 1/sqrt(128)
  float acc0 = 0.f, acc1 = 0.f, lsum = 0.f;
  float mom1 = 0.f, mom2 = 0.f, mom3 = 0.f, mom4 = 0.f;
  for (int l = w; l < LH_; l += 4) {
    if (smk[l]) {
      int tok = stok[l], pos = spos[l], g = sgrp[l];
      float2 tv = *(const float2*)&tok_emb[(size_t)tok * 128 + 2 * lane];
      float2 pv = *(const float2*)&pos_emb[pos * 128 + 2 * lane];
      float2 gv = *(const float2*)&sG[g * 128 + 2 * lane];
      float v0 = tv.x + pv.x + gv.x;
      float v1 = tv.y + pv.y + gv.y;
      float t = st[l];
      float dot = wredsum(v0 * qv.x + v1 * qv.y);
      float poly = (((s_eq[4] * t + s_eq[3]) * t + s_eq[2]) * t + s_eq[1]) * t + s_eq[0];
      float e = __expf((dot + poly) * scale);
      lsum += e;
      acc0 += e * v0;
      acc1 += e * v1;
      float tp = e * t;
      mom1 += tp; tp *= t;
      mom2 += tp; tp *= t;
      mom3 += tp; tp *= t;
      mom4 += tp;
    }
  }
  sA[w * 128 + 2 * lane] = acc0;
  sA[w * 128 + 2 * lane + 1] = acc1;
  if (lane == 0) {
    sL[w] = lsum;
    sM[w * 5 + 1] = mom1; sM[w * 5 + 2] = mom2;
    sM[w * 5 + 3] = mom3; sM[w * 5 + 4] = mom4;
  }
  __syncthreads();
  if (tid < 128) {
    int i = tid;
    float L = sL[0] + sL[1] + sL[2] + sL[3];
    float inv = 1.f / L;
    float v = (sA[i] + sA[128 + i] + sA[256 + i] + sA[384 + i]) * inv;
    v += sE[i];
#pragma unroll
    for (int p = 1; p < 5; ++p) {
      float mp = (sM[0 * 5 + p] + sM[1 * 5 + p] + sM[2 * 5 + p] + sM[3 * 5 + p]) * inv;
      v += mp * sE[p * 128 + i];
    }
    unsigned short* row = FB + (size_t)b * 1408;
    float c = bf2f(row[i]), cm = bf2f(row[384 + i]);
    row[256 + i] = f2bf(v);
    row[512 + i] = f2bf(c * v);
    row[640 + i] = f2bf(c * cm);
    row[768 + i] = f2bf(fabsf(v - cm));
  }
}

// ---------------------------------------------------------------------------
// GEMM1 via bf16 MFMA: H1[2048x512] = FB @ OW1BT^T. Tile 64x64, grid 256, 256.
__global__ __launch_bounds__(256) void k_gemm1(
    const unsigned short* __restrict__ A, const unsigned short* __restrict__ BT,
    float* __restrict__ H1) {
  int tid = threadIdx.x;
  int bm = blockIdx.x >> 3;
  int bn = blockIdx.x & 7;
  int w = tid >> 6, lane = tid & 63;
  int m = lane & 15, quad = lane >> 4;
  const unsigned short* ap = A + (size_t)(bm * 64 + w * 16 + m) * 1408 + quad * 8;
  const unsigned short* bp0 = BT + (size_t)(bn * 64 + m) * 1408 + quad * 8;
  const unsigned short* bp1 = bp0 + 16 * 1408;
  const unsigned short* bp2 = bp0 + 32 * 1408;
  const unsigned short* bp3 = bp0 + 48 * 1408;
  floatx4 acc0 = {0.f, 0.f, 0.f, 0.f};
  floatx4 acc1 = {0.f, 0.f, 0.f, 0.f};
  floatx4 acc2 = {0.f, 0.f, 0.f, 0.f};
  floatx4 acc3 = {0.f, 0.f, 0.f, 0.f};
#pragma unroll 4
  for (int kc = 0; kc < 1408; kc += 32) {
    short8v af = *(const short8v*)&ap[kc];
    short8v b0 = *(const short8v*)&bp0[kc];
    short8v b1 = *(const short8v*)&bp1[kc];
    short8v b2 = *(const short8v*)&bp2[kc];
    short8v b3 = *(const short8v*)&bp3[kc];
    acc0 = __builtin_amdgcn_mfma_f32_16x16x32_bf16(af, b0, acc0, 0, 0, 0);
    acc1 = __builtin_amdgcn_mfma_f32_16x16x32_bf16(af, b1, acc1, 0, 0, 0);
    acc2 = __builtin_amdgcn_mfma_f32_16x16x32_bf16(af, b2, acc2, 0, 0, 0);
    acc3 = __builtin_amdgcn_mfma_f32_16x16x32_bf16(af, b3, acc3, 0, 0, 0);
  }
  int row = bm * 64 + w * 16 + quad * 4;
  int col = bn * 64 + m;
#pragma unroll
  for (int r = 0; r < 4; ++r) {
    H1[(size_t)(row + r) * 512 + col] = acc0[r];
    H1[(size_t)(row + r) * 512 + col + 16] = acc1[r];
    H1[(size_t)(row + r) * 512 + col + 32] = acc2[r];
    H1[(size_t)(row + r) * 512 + col + 48] = acc3[r];
  }
}

// ---------------------------------------------------------------------------
// LN+silu on H1 (+ob1) -> H1S bf16. 4 rows/block, grid B_/4, block 256
__global__ __launch_bounds__(256) void k_ln1(
    const float* __restrict__ H1, const float* __restrict__ ob1,
    const float* __restrict__ og, const float* __restrict__ obt,
    unsigned short* __restrict__ H1S) {
  __shared__ float sr1[16], sr2[16];
  int tid = threadIdx.x;
  int b0 = blockIdx.x * 4;
  int wv = tid >> 6;
  float bi0 = ob1[tid], bi1 = ob1[tid + 256];
  float a0[4], a1[4];
#pragma unroll
  for (int r = 0; r < 4; ++r) {
    a0[r] = H1[(size_t)(b0 + r) * 512 + tid] + bi0;
    a1[r] = H1[(size_t)(b0 + r) * 512 + tid + 256] + bi1;
    float s1 = wredsum(a0[r] + a1[r]);
    float s2 = wredsum(a0[r] * a0[r] + a1[r] * a1[r]);
    if ((tid & 63) == 0) { sr1[r * 4 + wv] = s1; sr2[r * 4 + wv] = s2; }
  }
  __syncthreads();
  float g0 = og[tid], g1 = og[tid + 256], t0 = obt[tid], t1 = obt[tid + 256];
#pragma unroll
  for (int r = 0; r < 4; ++r) {
    float s1 = sr1[r * 4] + sr1[r * 4 + 1] + sr1[r * 4 + 2] + sr1[r * 4 + 3];
    float s2 = sr2[r * 4] + sr2[r * 4 + 1] + sr2[r * 4 + 2] + sr2[r * 4 + 3];
    float mean = s1 / 512.f, var = s2 / 512.f - mean * mean;
    float rstd = rsqrtf(var + 1e-5f);
    H1S[(size_t)(b0 + r) * 512 + tid] = f2bf(siluf((a0[r] - mean) * rstd * g0 + t0));
    H1S[(size_t)(b0 + r) * 512 + tid + 256] = f2bf(siluf((a1[r] - mean) * rstd * g1 + t1));
  }
}

// ---------------------------------------------------------------------------
// GEMM2 via bf16 MFMA: H2[2048x256] = H1S @ OW2BT^T. Tile 64(M)x32(N),
// grid 256 (32m x 8n), block 256.
__global__ __launch_bounds__(256) void k_gemm2(
    const unsigned short* __restrict__ A, const unsigned short* __restrict__ BT,
    float* __restrict__ H2) {
  int tid = threadIdx.x;
  int bm = blockIdx.x >> 3;
  int bn = blockIdx.x & 7;
  int w = tid >> 6, lane = tid & 63;
  int m = lane & 15, quad = lane >> 4;
  const unsigned short* ap = A + (size_t)(bm * 64 + w * 16 + m) * 512 + quad * 8;
  const unsigned short* bp0 = BT + (size_t)(bn * 32 + m) * 512 + quad * 8;
  const unsigned short* bp1 = bp0 + 16 * 512;
  floatx4 acc0 = {0.f, 0.f, 0.f, 0.f};
  floatx4 acc1 = {0.f, 0.f, 0.f, 0.f};
#pragma unroll
  for (int kc = 0; kc < 512; kc += 32) {
    short8v af = *(const short8v*)&ap[kc];
    short8v b0 = *(const short8v*)&bp0[kc];
    short8v b1 = *(const short8v*)&bp1[kc];
    acc0 = __builtin_amdgcn_mfma_f32_16x16x32_bf16(af, b0, acc0, 0, 0, 0);
    acc1 = __builtin_amdgcn_mfma_f32_16x16x32_bf16(af, b1, acc1, 0, 0, 0);
  }
  int row = bm * 64 + w * 16 + quad * 4;
  int col = bn * 32 + m;
#pragma unroll
  for (int r = 0; r < 4; ++r) {
    H2[(size_t)(row + r) * 256 + col] = acc0[r];
    H2[(size_t)(row + r) * 256 + col + 16] = acc1[r];
  }
}

// ---------------------------------------------------------------------------
// out[b] = sum_c silu(H2[b,c]+ob2[c])*ow3[c] + ob3. 8 rows/block, grid B_/8, 256
__global__ __launch_bounds__(256) void k_out(
    const float* __restrict__ H2, const float* __restrict__ ob2,
    const float* __restrict__ ow3, const float* __restrict__ ob3,
    float* __restrict__ out) {
  __shared__ float sdot[32];
  int tid = threadIdx.x;
  int b0 = blockIdx.x * 8;
  int wv = tid >> 6;
  float b2 = ob2[tid], w3 = ow3[tid];
#pragma unroll
  for (int r = 0; r < 8; ++r) {
    float v = siluf(H2[(size_t)(b0 + r) * 256 + tid] + b2) * w3;
    v = wredsum(v);
    if ((tid & 63) == 0) sdot[r * 4 + wv] = v;
  }
  __syncthreads();
  if (tid < 8) {
    out[b0 + tid] = sdot[tid * 4] + sdot[tid * 4 + 1] + sdot[tid * 4 + 2] + sdot[tid * 4 + 3] +
                    ob3[0];
  }
}

// ---------------------------------------------------------------------------
extern "C" void kernel_launch(void* const* d_in, const int* in_sizes, int n_in,
                              void* d_out, int out_size, void* d_ws, size_t ws_size,
                              hipStream_t stream) {
  const int* cand_tok = (const int*)d_in[0];
  const int* ctx_tok = (const int*)d_in[1];
  const int* hist_tok = (const int*)d_in[2];
  const int* hist_pos = (const int*)d_in[3];
  const int* hist_grp = (const int*)d_in[4];
  const int* cand_mask = (const int*)d_in[5];
  const int* ctx_mask = (const int*)d_in[6];
  const int* hist_mask = (const int*)d_in[7];
  const float* hist_times = (const float*)d_in[8];
  const float* dense_feat = (const float*)d_in[9];
  const float* tok_emb = (const float*)d_in[10];
  const float* pos_emb = (const float*)d_in[11];
  const float* grp_emb = (const float*)d_in[12];
  const float* time_w1 = (const float*)d_in[13];
  const float* time_b1 = (const float*)d_in[14];
  const float* time_w2 = (const float*)d_in[15];
  const float* time_b2 = (const float*)d_in[16];
  const float* comp_w = (const float*)d_in[17];
  const float* comp_b = (const float*)d_in[18];
  const float* comp_g = (const float*)d_in[19];
  const float* comp_bt = (const float*)d_in[20];
  const float* dense_w = (const float*)d_in[21];
  const float* dense_b = (const float*)d_in[22];
  const float* dense_g = (const float*)d_in[23];
  const float* dense_bt = (const float*)d_in[24];
  const float* query_w = (const float*)d_in[25];
  const float* query_b = (const float*)d_in[26];
  const float* query_g = (const float*)d_in[27];
  const float* query_bt = (const float*)d_in[28];
  const float* out_w1 = (const float*)d_in[29];
  const float* out_b1 = (const float*)d_in[30];
  const float* out_g = (const float*)d_in[31];
  const float* out_bt = (const float*)d_in[32];
  const float* out_w2 = (const float*)d_in[33];
  const float* out_b2 = (const float*)d_in[34];
  const float* out_w3 = (const float*)d_in[35];
  const float* out_b3 = (const float*)d_in[36];
  float* out = (float*)d_out;

  // Workspace — same validated 4,950,016-float footprint. QIN is gone; its
  // region now holds H_D / OW2BT / QWBT / DWBT / DB. H2 aliases H_D (dead
  // after k_dense_ln); H1S aliases query (dead after k_attn3).
  float* ws = (float*)d_ws;
  float* E = ws;                                    // 640
  float* F = ws + 640;                              // 640
  float* gvec = ws + 1280;                          // 512
  float* MV = ws + 1792;                            // 56 (pad to 2048)
  float* query = ws + 2048;                         // 262144 fl
  unsigned short* H1S = (unsigned short*)(ws + 2048);       // aliases query
  float* HD = ws + 264192;                          // 1048576 fl
  float* H2 = HD;                                   // 524288 fl (aliases dead HD)
  unsigned short* OW2BT = (unsigned short*)(ws + 1312768);  // 65536 fl
  unsigned short* QWBT = (unsigned short*)(ws + 1378304);   // 57344 fl
  unsigned short* DWBT = (unsigned short*)(ws + 1435648);   // 65536 fl
  unsigned short* DB = (unsigned short*)(ws + 1501184);     // 262144 fl
  float* H1 = ws + 2099200;                         // 1048576 fl
  unsigned short* FB = (unsigned short*)(ws + 3147776);     // 1441792 fl
  unsigned short* OW1BT = (unsigned short*)(ws + 4589568);  // 360448 fl
  // end = 4950016 floats (19.8 MB)

  k0_poly<<<1, 128, 0, stream>>>(time_w1, time_b1, time_w2, time_b2,
                                 comp_w, comp_b, grp_emb, E, F, gvec, MV);
  k_convw1<<<2816, 256, 0, stream>>>(out_w1, OW1BT);
  k_convw2<<<512, 256, 0, stream>>>(out_w2, OW2BT);
  k_convqw<<<448, 256, 0, stream>>>(query_w, QWBT);
  k_convdw<<<512, 256, 0, stream>>>(dense_w, DWBT);
  k_convdf<<<2048, 256, 0, stream>>>(dense_feat, DB);
  k_candctx<<<B_, 128, 0, stream>>>(cand_tok, ctx_tok, cand_mask, ctx_mask,
                                    tok_emb, FB);
  k_comp_poly<<<B_, 256, 0, stream>>>(hist_times, hist_grp, hist_mask,
                                      F, gvec, MV, comp_g, comp_bt, FB);
  k_gemm_d<<<256, 256, 0, stream>>>(DB, DWBT, HD);
  k_dense_ln<<<B_ / 4, 256, 0, stream>>>(HD, dense_b, dense_g, dense_bt, FB);
  k_query_mfma<<<32, 256, 0, stream>>>(FB, QWBT, query_b, query_g, query_bt, query);
  k_attn3<<<B_, 256, 0, stream>>>(hist_tok, hist_pos, hist_grp, hist_mask, hist_times,
                                  tok_emb, pos_emb, grp_emb, query, E, FB);
  k_gemm1<<<256, 256, 0, stream>>>(FB, OW1BT, H1);
  k_ln1<<<B_ / 4, 256, 0, stream>>>(H1, out_b1, out_g, out_bt, H1S);
  k_gemm2<<<256, 256, 0, stream>>>(H1S, OW2BT, H2);
  k_out<<<B_ / 8, 256, 0, stream>>>(H2, out_b2, out_w3, out_b3, out);
}

// Round 10
// 345.548 us; speedup vs baseline: 1.7801x; 1.0805x over previous
//
#include <hip/hip_runtime.h>
#include <hip/hip_bf16.h>

#define B_ 2048
#define LC_ 20
#define LX_ 20
#define LH_ 200
#define D_ 128
#define H_ 512
#define DENSE_ 256

typedef __attribute__((ext_vector_type(8))) short short8v;
typedef __attribute__((ext_vector_type(4))) float floatx4;

__device__ __forceinline__ float siluf(float x) { return x / (1.f + __expf(-x)); }

__device__ __forceinline__ unsigned short f2bf(float f) {
  return __builtin_bit_cast(unsigned short, __float2bfloat16(f));
}
__device__ __forceinline__ float bf2f(unsigned short u) {
  return __bfloat162float(__builtin_bit_cast(__hip_bfloat16, u));
}

__device__ __forceinline__ float wredsum(float v) {
#pragma unroll
  for (int off = 32; off > 0; off >>= 1) v += __shfl_xor(v, off, 64);
  return v;
}

// pair index into the 15-entry upper-triangular (p<=q, 5x5) list
__device__ __forceinline__ int cidx(int a, int b) {
  if (a > b) { int t = a; a = b; b = t; }
  const int base[5] = {0, 5, 9, 12, 14};
  return base[a] + (b - a);
}

// ---------------------------------------------------------------------------
// K0 (1 block, 128 threads):
//  1) degree-4 poly of u(t)=silu(t*w1+b1); E_p = c_p @ W2 (E_0 += b2) -> E (for attn)
//  2) F_p = E_p @ comp_w[128:,:] (F_0 += comp_b); gvec[g] = grp_emb[g] @ comp_w[:128,:]
//  3) analytic LN channel-moments: mean poly (deg4) + E[x^2] poly (deg8) per g
//  4) CC[g][p][j]: degree-10 Chebyshev-node interpolation of
//     f_{g,j}(t) = silu((pre(t,g)[j]-mean)*rstd*comp_g[j]+comp_bt[j])
__global__ __launch_bounds__(128) void k0_poly(
    const float* __restrict__ w1, const float* __restrict__ b1,
    const float* __restrict__ W2, const float* __restrict__ b2,
    const float* __restrict__ comp_w, const float* __restrict__ comp_b,
    const float* __restrict__ grp_emb,
    const float* __restrict__ cg_, const float* __restrict__ cbt_,
    float* __restrict__ E, float* __restrict__ CC) {
  __shared__ float sc[5 * 128];
  __shared__ float sE[5 * 128];
  __shared__ float sF2[5 * 128];
  __shared__ float sGv[4 * 128];
  __shared__ float s48[48];
  __shared__ float sMC[20], sVC[36];
  int k = threadIdx.x;
  {
    float w = w1[k], bb = b1[k];
    float y0 = siluf(bb);
    float y1 = siluf(0.25f * w + bb);
    float y2 = siluf(0.50f * w + bb);
    float y3 = siluf(0.75f * w + bb);
    float y4 = siluf(w + bb);
    float d1 = y1 - y0;
    float d2 = y2 - 2.f * y1 + y0;
    float d3 = y3 - 3.f * y2 + 3.f * y1 - y0;
    float d4 = y4 - 4.f * y3 + 6.f * y2 - 4.f * y1 + y0;
    float c0 = y0;
    float c1 = d1 - 0.5f * d2 + d3 * (1.f / 3.f) - 0.25f * d4;
    float c2 = 0.5f * d2 - 0.5f * d3 + (11.f / 24.f) * d4;
    float c3 = d3 * (1.f / 6.f) - 0.25f * d4;
    float c4 = d4 * (1.f / 24.f);
    sc[0 * 128 + k] = c0;
    sc[1 * 128 + k] = c1 * 4.f;
    sc[2 * 128 + k] = c2 * 16.f;
    sc[3 * 128 + k] = c3 * 64.f;
    sc[4 * 128 + k] = c4 * 256.f;
  }
  __syncthreads();
  int j = k;
  float e[5] = {0, 0, 0, 0, 0};
  for (int kk = 0; kk < 128; ++kk) {
    float wv = W2[kk * 128 + j];
#pragma unroll
    for (int p = 0; p < 5; ++p) e[p] += sc[p * 128 + kk] * wv;
  }
  e[0] += b2[j];
#pragma unroll
  for (int p = 0; p < 5; ++p) { sE[p * 128 + j] = e[p]; E[p * 128 + j] = e[p]; }
  __syncthreads();
  float f[5] = {0, 0, 0, 0, 0};
  for (int kk = 0; kk < 128; ++kk) {
    float wv = comp_w[(128 + kk) * 128 + j];
#pragma unroll
    for (int p = 0; p < 5; ++p) f[p] += sE[p * 128 + kk] * wv;
  }
  f[0] += comp_b[j];
#pragma unroll
  for (int p = 0; p < 5; ++p) sF2[p * 128 + j] = f[p];
  for (int g = 0; g < 4; ++g) {
    float acc = 0.f;
    for (int kk = 0; kk < 128; ++kk) acc += grp_emb[g * 128 + kk] * comp_w[kk * 128 + j];
    sGv[g * 128 + j] = acc;
  }
  __syncthreads();
  if (k < 48) {
    const float* va;
    const float* vb = nullptr;
    int t = k;
    if (t < 5) va = &sF2[t * 128];
    else if (t < 9) va = &sGv[(t - 5) * 128];
    else if (t < 13) { va = &sGv[(t - 9) * 128]; vb = va; }
    else if (t < 33) {
      int g = (t - 13) / 5, p = (t - 13) % 5;
      va = &sGv[g * 128]; vb = &sF2[p * 128];
    } else {
      int idx = t - 33;
      int a = 0;
      if (idx >= 14) a = 4;
      else if (idx >= 12) a = 3;
      else if (idx >= 9) a = 2;
      else if (idx >= 5) a = 1;
      const int base[5] = {0, 5, 9, 12, 14};
      int bcol = a + (idx - base[a]);
      va = &sF2[a * 128]; vb = &sF2[bcol * 128];
    }
    float s = 0.f;
    if (vb) { for (int kk = 0; kk < 128; ++kk) s += va[kk] * vb[kk]; }
    else    { for (int kk = 0; kk < 128; ++kk) s += va[kk]; }
    s48[t] = s * (1.f / 128.f);
  }
  __syncthreads();
  if (k < 20) {
    int g = k / 5, p = k % 5;
    sMC[g * 5 + p] = s48[p] + (p == 0 ? s48[5 + g] : 0.f);
  }
  if (k < 36) {
    int g = k / 9, kk = k % 9;
    float v = (kk == 0 ? s48[9 + g] : 0.f);
    if (kk < 5) v += 2.f * s48[13 + g * 5 + kk];
#pragma unroll
    for (int p = 0; p < 5; ++p) {
      int q = kk - p;
      if (q >= 0 && q <= 4) v += s48[33 + cidx(p, q)];
    }
    sVC[20 - 20 + g * 9 + kk] = v;
  }
  __syncthreads();
  // degree-10 fit per (g, j): Chebyshev-Lobatto nodes on [0,1]
  const float nodes[11] = {0.f, 0.02447174185f, 0.09549150281f, 0.2061073739f,
                           0.3454915028f, 0.5f, 0.6545084972f, 0.7938926261f,
                           0.9045084972f, 0.9755282581f, 1.f};
  float cgj = cg_[j], btj = cbt_[j];
  float F0 = sF2[j], F1 = sF2[128 + j], F2v = sF2[256 + j], F3 = sF2[384 + j], F4 = sF2[512 + j];
  for (int g = 0; g < 4; ++g) {
    const float* mc = &sMC[g * 5];
    const float* vc = &sVC[g * 9];
    float gv = sGv[g * 128 + j];
    float fv[11];
#pragma unroll
    for (int n = 0; n < 11; ++n) {
      float t = nodes[n];
      float mean = (((mc[4] * t + mc[3]) * t + mc[2]) * t + mc[1]) * t + mc[0];
      float e2 = vc[8];
#pragma unroll
      for (int p = 7; p >= 0; --p) e2 = e2 * t + vc[p];
      float rstd = rsqrtf(e2 - mean * mean + 1e-5f);
      float pre = gv + ((((F4 * t + F3) * t + F2v) * t + F1) * t + F0);
      fv[n] = siluf((pre - mean) * rstd * cgj + btj);
    }
    // Newton divided differences (in place)
#pragma unroll
    for (int ord = 1; ord <= 10; ++ord) {
#pragma unroll
      for (int n = 10; n >= 1; --n) {
        if (n >= ord) fv[n] = (fv[n] - fv[n - 1]) / (nodes[n] - nodes[n - ord]);
      }
    }
    // Newton -> monomial
    float c[11];
#pragma unroll
    for (int i = 0; i < 11; ++i) c[i] = 0.f;
    c[0] = fv[10];
#pragma unroll
    for (int n = 9; n >= 0; --n) {
      int deg = 9 - n;
      float x = nodes[n];
      c[deg + 1] = c[deg];
#pragma unroll
      for (int i = 10; i >= 1; --i) {
        if (i <= deg) c[i] = c[i - 1] - x * c[i];
      }
      c[0] = fv[n] - x * c[0];
    }
#pragma unroll
    for (int p = 0; p < 11; ++p) CC[(g * 11 + p) * 128 + j] = c[p];
  }
}

// ---------------------------------------------------------------------------
// big weight conversion: out_w1 [1408x512] f32 -> OW1BT [512x1408] bf16
__global__ __launch_bounds__(256) void k_convw1(
    const float* __restrict__ ow1, unsigned short* __restrict__ BT) {
  int idx = blockIdx.x * 256 + threadIdx.x;
  if (idx < 512 * 1408) {
    int n = idx / 1408, k = idx - n * 1408;
    BT[(size_t)n * 1408 + k] = f2bf(ow1[(size_t)k * 512 + n]);
  }
}

// fused small conversions: ow2->OW2BT, qw->QWBT, dw->DWBT, df->DB. grid 3520, 256
__global__ __launch_bounds__(256) void k_convmisc(
    const float* __restrict__ ow2, const float* __restrict__ qw,
    const float* __restrict__ dw, const float* __restrict__ df,
    unsigned short* __restrict__ OW2BT, unsigned short* __restrict__ QWBT,
    unsigned short* __restrict__ DWBT, unsigned short* __restrict__ DB) {
  int idx = blockIdx.x * 256 + threadIdx.x;
  if (idx < 131072) {                    // ow2 [512x256] -> [256][512]
    int n = idx >> 9, k = idx & 511;
    OW2BT[(size_t)n * 512 + k] = f2bf(ow2[(size_t)k * 256 + n]);
  } else if (idx < 245760) {             // qw [896x128] -> [128][896]
    int i = idx - 131072;
    int n = i / 896, k = i - n * 896;
    QWBT[(size_t)n * 896 + k] = f2bf(qw[(size_t)k * 128 + n]);
  } else if (idx < 376832) {             // dw [256x512] -> [512][256]
    int i = idx - 245760;
    int n = i >> 8, k = i & 255;
    DWBT[(size_t)n * 256 + k] = f2bf(dw[(size_t)k * 512 + n]);
  } else {                               // df [2048x256] cast
    int i = idx - 376832;
    DB[i] = f2bf(df[i]);
  }
}

// ---------------------------------------------------------------------------
// cand_s / ctx_s masked means -> FB[0:256) bf16. grid B_, 128
__global__ __launch_bounds__(128) void k_candctx(
    const int* __restrict__ ctok, const int* __restrict__ xtok,
    const int* __restrict__ cmask, const int* __restrict__ xmask,
    const float* __restrict__ tok_emb, unsigned short* __restrict__ FB) {
  int b = blockIdx.x, j = threadIdx.x;
  float acc = 0.f, cnt = 0.f;
#pragma unroll
  for (int l = 0; l < LC_; ++l) {
    float mv = (float)cmask[b * LC_ + l];
    acc += mv * tok_emb[(size_t)ctok[b * LC_ + l] * 128 + j];
    cnt += mv;
  }
  float cs = acc / fmaxf(cnt, 1.f);
  acc = 0.f; cnt = 0.f;
#pragma unroll
  for (int l = 0; l < LX_; ++l) {
    float mv = (float)xmask[b * LX_ + l];
    acc += mv * tok_emb[(size_t)xtok[b * LX_ + l] * 128 + j];
    cnt += mv;
  }
  float xs = acc / fmaxf(cnt, 1.f);
  FB[(size_t)b * 1408 + j] = f2bf(cs);
  FB[(size_t)b * 1408 + 128 + j] = f2bf(xs);
}

// ---------------------------------------------------------------------------
// comp summary via per-(g,p) power sums + precomputed poly CC. grid B_, 256
// comp_mean[j] = (1/cnt) * sum_{g,p} S[g][p] * CC[g][p][j]
__global__ __launch_bounds__(256) void k_comp_pow(
    const float* __restrict__ times, const int* __restrict__ groups,
    const int* __restrict__ hmask, const float* __restrict__ CC,
    unsigned short* __restrict__ FB) {
  __shared__ float sPow[LH_ * 11];
  __shared__ int sg[LH_];
  __shared__ float sS[4 * 44];
  __shared__ float sSf[44];
  int tid = threadIdx.x, b = blockIdx.x;
  if (tid < LH_) {
    float t = times[b * LH_ + tid];
    int mk = hmask[b * LH_ + tid];
    sg[tid] = mk ? groups[b * LH_ + tid] : -1;
    float pw = 1.f;
#pragma unroll
    for (int p = 0; p < 11; ++p) { sPow[tid * 11 + p] = pw; pw *= t; }
  }
  __syncthreads();
  int lane = tid & 63, w = tid >> 6;
  if (lane < 44) {
    int g = lane / 11, p = lane - 11 * g;
    float s = 0.f;
    for (int l = w * 50; l < w * 50 + 50; ++l) {
      if (sg[l] == g) s += sPow[l * 11 + p];
    }
    sS[w * 44 + lane] = s;
  }
  __syncthreads();
  if (tid < 44) sSf[tid] = sS[tid] + sS[44 + tid] + sS[88 + tid] + sS[132 + tid];
  __syncthreads();
  if (tid < 128) {
    float cnt = sSf[0] + sSf[11] + sSf[22] + sSf[33];
    float inv = 1.f / fmaxf(cnt, 1.f);
    float acc = 0.f;
#pragma unroll 4
    for (int q = 0; q < 44; ++q) acc += sSf[q] * CC[q * 128 + tid];
    FB[(size_t)b * 1408 + 384 + tid] = f2bf(acc * inv);
  }
}

// ---------------------------------------------------------------------------
// dense GEMM via bf16 MFMA: H_D[2048x512] = DB @ DWBT^T. Tile 64x64, grid 256.
__global__ __launch_bounds__(256) void k_gemm_d(
    const unsigned short* __restrict__ A, const unsigned short* __restrict__ BT,
    float* __restrict__ HD) {
  int tid = threadIdx.x;
  int bm = blockIdx.x >> 3;
  int bn = blockIdx.x & 7;
  int w = tid >> 6, lane = tid & 63;
  int m = lane & 15, quad = lane >> 4;
  const unsigned short* ap = A + (size_t)(bm * 64 + w * 16 + m) * 256 + quad * 8;
  const unsigned short* bp0 = BT + (size_t)(bn * 64 + m) * 256 + quad * 8;
  const unsigned short* bp1 = bp0 + 16 * 256;
  const unsigned short* bp2 = bp0 + 32 * 256;
  const unsigned short* bp3 = bp0 + 48 * 256;
  floatx4 acc0 = {0.f, 0.f, 0.f, 0.f};
  floatx4 acc1 = {0.f, 0.f, 0.f, 0.f};
  floatx4 acc2 = {0.f, 0.f, 0.f, 0.f};
  floatx4 acc3 = {0.f, 0.f, 0.f, 0.f};
#pragma unroll
  for (int kc = 0; kc < 256; kc += 32) {
    short8v af = *(const short8v*)&ap[kc];
    short8v b0 = *(const short8v*)&bp0[kc];
    short8v b1 = *(const short8v*)&bp1[kc];
    short8v b2 = *(const short8v*)&bp2[kc];
    short8v b3 = *(const short8v*)&bp3[kc];
    acc0 = __builtin_amdgcn_mfma_f32_16x16x32_bf16(af, b0, acc0, 0, 0, 0);
    acc1 = __builtin_amdgcn_mfma_f32_16x16x32_bf16(af, b1, acc1, 0, 0, 0);
    acc2 = __builtin_amdgcn_mfma_f32_16x16x32_bf16(af, b2, acc2, 0, 0, 0);
    acc3 = __builtin_amdgcn_mfma_f32_16x16x32_bf16(af, b3, acc3, 0, 0, 0);
  }
  int row = bm * 64 + w * 16 + quad * 4;
  int col = bn * 64 + m;
#pragma unroll
  for (int r = 0; r < 4; ++r) {
    HD[(size_t)(row + r) * 512 + col] = acc0[r];
    HD[(size_t)(row + r) * 512 + col + 16] = acc1[r];
    HD[(size_t)(row + r) * 512 + col + 32] = acc2[r];
    HD[(size_t)(row + r) * 512 + col + 48] = acc3[r];
  }
}

// ---------------------------------------------------------------------------
// bias+LN+silu on H_D -> FB[896:1408) bf16. 4 rows/block, grid B_/4, block 256
__global__ __launch_bounds__(256) void k_dense_ln(
    const float* __restrict__ HD, const float* __restrict__ dbias,
    const float* __restrict__ dg, const float* __restrict__ dbt,
    unsigned short* __restrict__ FB) {
  __shared__ float sr1[16], sr2[16];
  int tid = threadIdx.x;
  int b0 = blockIdx.x * 4;
  int wv = tid >> 6;
  float bi0 = dbias[tid], bi1 = dbias[tid + 256];
  float a0[4], a1[4];
#pragma unroll
  for (int r = 0; r < 4; ++r) {
    a0[r] = HD[(size_t)(b0 + r) * 512 + tid] + bi0;
    a1[r] = HD[(size_t)(b0 + r) * 512 + tid + 256] + bi1;
    float s1 = wredsum(a0[r] + a1[r]);
    float s2 = wredsum(a0[r] * a0[r] + a1[r] * a1[r]);
    if ((tid & 63) == 0) { sr1[r * 4 + wv] = s1; sr2[r * 4 + wv] = s2; }
  }
  __syncthreads();
  float g0 = dg[tid], g1 = dg[tid + 256], t0 = dbt[tid], t1 = dbt[tid + 256];
#pragma unroll
  for (int r = 0; r < 4; ++r) {
    float s1 = sr1[r * 4] + sr1[r * 4 + 1] + sr1[r * 4 + 2] + sr1[r * 4 + 3];
    float s2 = sr2[r * 4] + sr2[r * 4 + 1] + sr2[r * 4 + 2] + sr2[r * 4 + 3];
    float mean = s1 / 512.f, var = s2 / 512.f - mean * mean;
    float rstd = rsqrtf(var + 1e-5f);
    FB[(size_t)(b0 + r) * 1408 + 896 + tid] = f2bf(siluf((a0[r] - mean) * rstd * g0 + t0));
    FB[(size_t)(b0 + r) * 1408 + 896 + tid + 256] = f2bf(siluf((a1[r] - mean) * rstd * g1 + t1));
  }
}

// ---------------------------------------------------------------------------
// query via bf16 MFMA, A straight from FB (28 K-chunks map concat inputs),
// fused LN+silu epilogue via quad shuffles. Tile 64M x 128N, grid 32, block 256.
__global__ __launch_bounds__(256) void k_query_mfma(
    const unsigned short* __restrict__ FB, const unsigned short* __restrict__ QWBT,
    const float* __restrict__ qb, const float* __restrict__ qg,
    const float* __restrict__ qbt, float* __restrict__ query) {
  int tid = threadIdx.x;
  int w = tid >> 6, lane = tid & 63;
  int m = lane & 15, quad = lane >> 4;
  const unsigned short* ap = FB + (size_t)(blockIdx.x * 64 + w * 16 + m) * 1408 + quad * 8;
  const unsigned short* bp = QWBT + (size_t)m * 896 + quad * 8;
  floatx4 acc[8];
#pragma unroll
  for (int nt = 0; nt < 8; ++nt) acc[nt] = {0.f, 0.f, 0.f, 0.f};
#pragma unroll 4
  for (int kc = 0; kc < 28; ++kc) {
    int fo = (kc < 8) ? kc * 32 : (kc < 12 ? 384 + (kc - 8) * 32 : 896 + (kc - 12) * 32);
    short8v af = *(const short8v*)&ap[fo];
#pragma unroll
    for (int nt = 0; nt < 8; ++nt) {
      short8v bf = *(const short8v*)&bp[(size_t)nt * 16 * 896 + kc * 32];
      acc[nt] = __builtin_amdgcn_mfma_f32_16x16x32_bf16(af, bf, acc[nt], 0, 0, 0);
    }
  }
  float bj[8], gj[8], tj[8];
#pragma unroll
  for (int nt = 0; nt < 8; ++nt) {
    bj[nt] = qb[nt * 16 + m];
    gj[nt] = qg[nt * 16 + m];
    tj[nt] = qbt[nt * 16 + m];
  }
#pragma unroll
  for (int r = 0; r < 4; ++r) {
    float x[8];
    float s1 = 0.f, s2 = 0.f;
#pragma unroll
    for (int nt = 0; nt < 8; ++nt) {
      x[nt] = acc[nt][r] + bj[nt];
      s1 += x[nt];
      s2 += x[nt] * x[nt];
    }
#pragma unroll
    for (int off = 1; off < 16; off <<= 1) {
      s1 += __shfl_xor(s1, off, 64);
      s2 += __shfl_xor(s2, off, 64);
    }
    float mean = s1 * (1.f / 128.f);
    float var = s2 * (1.f / 128.f) - mean * mean;
    float rstd = rsqrtf(var + 1e-5f);
    int row = blockIdx.x * 64 + w * 16 + quad * 4 + r;
#pragma unroll
    for (int nt = 0; nt < 8; ++nt) {
      query[(size_t)row * 128 + nt * 16 + m] = siluf((x[nt] - mean) * rstd * gj[nt] + tj[nt]);
    }
  }
}

// ---------------------------------------------------------------------------
// single-pass online-softmax attention; lane covers channel pair (2l, 2l+1).
// grid B_, block 256
__global__ __launch_bounds__(256) void k_attn3(
    const int* __restrict__ htok, const int* __restrict__ hpos,
    const int* __restrict__ hgrp, const int* __restrict__ hmask,
    const float* __restrict__ times,
    const float* __restrict__ tok_emb, const float* __restrict__ pos_emb,
    const float* __restrict__ grp_emb,
    const float* __restrict__ query, const float* __restrict__ E,
    unsigned short* __restrict__ FB) {
  __shared__ float sq[128];
  __shared__ float sE[5 * 128];
  __shared__ float sG[4 * 128];
  __shared__ float st[LH_];
  __shared__ int stok[LH_], spos[LH_], sgrp[LH_], smk[LH_];
  __shared__ float seq[5 * 2];
  __shared__ float s_eq[5];
  __shared__ float sA[4 * 128];
  __shared__ float sL[4];
  __shared__ float sM[4 * 5];
  int tid = threadIdx.x, b = blockIdx.x;
  int lane = tid & 63, w = tid >> 6;
  if (tid < 128) sq[tid] = query[b * 128 + tid];
  for (int idx = tid; idx < 5 * 128; idx += 256) sE[idx] = E[idx];
  for (int idx = tid; idx < 4 * 128; idx += 256) sG[idx] = grp_emb[idx];
  for (int l = tid; l < LH_; l += 256) {
    st[l] = times[b * LH_ + l];
    stok[l] = htok[b * LH_ + l];
    spos[l] = hpos[b * LH_ + l];
    sgrp[l] = hgrp[b * LH_ + l];
    smk[l] = hmask[b * LH_ + l];
  }
  __syncthreads();
  if (tid < 128) {
    int wh = (tid >> 6) & 1;
#pragma unroll
    for (int p = 0; p < 5; ++p) {
      float v = sE[p * 128 + tid] * sq[tid];
      v = wredsum(v);
      if ((tid & 63) == 0) seq[p * 2 + wh] = v;
    }
  }
  __syncthreads();
  if (tid < 5) s_eq[tid] = seq[tid * 2] + seq[tid * 2 + 1];
  __syncthreads();
  float2 qv = *(const float2*)&sq[2 * lane];
  const float scale = 0.08838834764831845f;  // 1/sqrt(128)
  float acc0 = 0.f, acc1 = 0.f, lsum = 0.f;
  float mom1 = 0.f, mom2 = 0.f, mom3 = 0.f, mom4 = 0.f;
  for (int l = w; l < LH_; l += 4) {
    if (smk[l]) {
      int tok = stok[l], pos = spos[l], g = sgrp[l];
      float2 tv = *(const float2*)&tok_emb[(size_t)tok * 128 + 2 * lane];
      float2 pv = *(const float2*)&pos_emb[pos * 128 + 2 * lane];
      float2 gv = *(const float2*)&sG[g * 128 + 2 * lane];
      float v0 = tv.x + pv.x + gv.x;
      float v1 = tv.y + pv.y + gv.y;
      float t = st[l];
      float dot = wredsum(v0 * qv.x + v1 * qv.y);
      float poly = (((s_eq[4] * t + s_eq[3]) * t + s_eq[2]) * t + s_eq[1]) * t + s_eq[0];
      float e = __expf((dot + poly) * scale);
      lsum += e;
      acc0 += e * v0;
      acc1 += e * v1;
      float tp = e * t;
      mom1 += tp; tp *= t;
      mom2 += tp; tp *= t;
      mom3 += tp; tp *= t;
      mom4 += tp;
    }
  }
  sA[w * 128 + 2 * lane] = acc0;
  sA[w * 128 + 2 * lane + 1] = acc1;
  if (lane == 0) {
    sL[w] = lsum;
    sM[w * 5 + 1] = mom1; sM[w * 5 + 2] = mom2;
    sM[w * 5 + 3] = mom3; sM[w * 5 + 4] = mom4;
  }
  __syncthreads();
  if (tid < 128) {
    int i = tid;
    float L = sL[0] + sL[1] + sL[2] + sL[3];
    float inv = 1.f / L;
    float v = (sA[i] + sA[128 + i] + sA[256 + i] + sA[384 + i]) * inv;
    v += sE[i];
#pragma unroll
    for (int p = 1; p < 5; ++p) {
      float mp = (sM[0 * 5 + p] + sM[1 * 5 + p] + sM[2 * 5 + p] + sM[3 * 5 + p]) * inv;
      v += mp * sE[p * 128 + i];
    }
    unsigned short* row = FB + (size_t)b * 1408;
    float c = bf2f(row[i]), cm = bf2f(row[384 + i]);
    row[256 + i] = f2bf(v);
    row[512 + i] = f2bf(c * v);
    row[640 + i] = f2bf(c * cm);
    row[768 + i] = f2bf(fabsf(v - cm));
  }
}

// ---------------------------------------------------------------------------
// GEMM1 via bf16 MFMA: H1[2048x512] = FB @ OW1BT^T. Tile 64x64, grid 256, 256.
__global__ __launch_bounds__(256) void k_gemm1(
    const unsigned short* __restrict__ A, const unsigned short* __restrict__ BT,
    float* __restrict__ H1) {
  int tid = threadIdx.x;
  int bm = blockIdx.x >> 3;
  int bn = blockIdx.x & 7;
  int w = tid >> 6, lane = tid & 63;
  int m = lane & 15, quad = lane >> 4;
  const unsigned short* ap = A + (size_t)(bm * 64 + w * 16 + m) * 1408 + quad * 8;
  const unsigned short* bp0 = BT + (size_t)(bn * 64 + m) * 1408 + quad * 8;
  const unsigned short* bp1 = bp0 + 16 * 1408;
  const unsigned short* bp2 = bp0 + 32 * 1408;
  const unsigned short* bp3 = bp0 + 48 * 1408;
  floatx4 acc0 = {0.f, 0.f, 0.f, 0.f};
  floatx4 acc1 = {0.f, 0.f, 0.f, 0.f};
  floatx4 acc2 = {0.f, 0.f, 0.f, 0.f};
  floatx4 acc3 = {0.f, 0.f, 0.f, 0.f};
#pragma unroll 4
  for (int kc = 0; kc < 1408; kc += 32) {
    short8v af = *(const short8v*)&ap[kc];
    short8v b0 = *(const short8v*)&bp0[kc];
    short8v b1 = *(const short8v*)&bp1[kc];
    short8v b2 = *(const short8v*)&bp2[kc];
    short8v b3 = *(const short8v*)&bp3[kc];
    acc0 = __builtin_amdgcn_mfma_f32_16x16x32_bf16(af, b0, acc0, 0, 0, 0);
    acc1 = __builtin_amdgcn_mfma_f32_16x16x32_bf16(af, b1, acc1, 0, 0, 0);
    acc2 = __builtin_amdgcn_mfma_f32_16x16x32_bf16(af, b2, acc2, 0, 0, 0);
    acc3 = __builtin_amdgcn_mfma_f32_16x16x32_bf16(af, b3, acc3, 0, 0, 0);
  }
  int row = bm * 64 + w * 16 + quad * 4;
  int col = bn * 64 + m;
#pragma unroll
  for (int r = 0; r < 4; ++r) {
    H1[(size_t)(row + r) * 512 + col] = acc0[r];
    H1[(size_t)(row + r) * 512 + col + 16] = acc1[r];
    H1[(size_t)(row + r) * 512 + col + 32] = acc2[r];
    H1[(size_t)(row + r) * 512 + col + 48] = acc3[r];
  }
}

// ---------------------------------------------------------------------------
// LN+silu on H1 (+ob1) -> H1S bf16. 4 rows/block, grid B_/4, block 256
__global__ __launch_bounds__(256) void k_ln1(
    const float* __restrict__ H1, const float* __restrict__ ob1,
    const float* __restrict__ og, const float* __restrict__ obt,
    unsigned short* __restrict__ H1S) {
  __shared__ float sr1[16], sr2[16];
  int tid = threadIdx.x;
  int b0 = blockIdx.x * 4;
  int wv = tid >> 6;
  float bi0 = ob1[tid], bi1 = ob1[tid + 256];
  float a0[4], a1[4];
#pragma unroll
  for (int r = 0; r < 4; ++r) {
    a0[r] = H1[(size_t)(b0 + r) * 512 + tid] + bi0;
    a1[r] = H1[(size_t)(b0 + r) * 512 + tid + 256] + bi1;
    float s1 = wredsum(a0[r] + a1[r]);
    float s2 = wredsum(a0[r] * a0[r] + a1[r] * a1[r]);
    if ((tid & 63) == 0) { sr1[r * 4 + wv] = s1; sr2[r * 4 + wv] = s2; }
  }
  __syncthreads();
  float g0 = og[tid], g1 = og[tid + 256], t0 = obt[tid], t1 = obt[tid + 256];
#pragma unroll
  for (int r = 0; r < 4; ++r) {
    float s1 = sr1[r * 4] + sr1[r * 4 + 1] + sr1[r * 4 + 2] + sr1[r * 4 + 3];
    float s2 = sr2[r * 4] + sr2[r * 4 + 1] + sr2[r * 4 + 2] + sr2[r * 4 + 3];
    float mean = s1 / 512.f, var = s2 / 512.f - mean * mean;
    float rstd = rsqrtf(var + 1e-5f);
    H1S[(size_t)(b0 + r) * 512 + tid] = f2bf(siluf((a0[r] - mean) * rstd * g0 + t0));
    H1S[(size_t)(b0 + r) * 512 + tid + 256] = f2bf(siluf((a1[r] - mean) * rstd * g1 + t1));
  }
}

// ---------------------------------------------------------------------------
// GEMM2 via bf16 MFMA: H2[2048x256] = H1S @ OW2BT^T. Tile 64x32, grid 256.
__global__ __launch_bounds__(256) void k_gemm2(
    const unsigned short* __restrict__ A, const unsigned short* __restrict__ BT,
    float* __restrict__ H2) {
  int tid = threadIdx.x;
  int bm = blockIdx.x >> 3;
  int bn = blockIdx.x & 7;
  int w = tid >> 6, lane = tid & 63;
  int m = lane & 15, quad = lane >> 4;
  const unsigned short* ap = A + (size_t)(bm * 64 + w * 16 + m) * 512 + quad * 8;
  const unsigned short* bp0 = BT + (size_t)(bn * 32 + m) * 512 + quad * 8;
  const unsigned short* bp1 = bp0 + 16 * 512;
  floatx4 acc0 = {0.f, 0.f, 0.f, 0.f};
  floatx4 acc1 = {0.f, 0.f, 0.f, 0.f};
#pragma unroll
  for (int kc = 0; kc < 512; kc += 32) {
    short8v af = *(const short8v*)&ap[kc];
    short8v b0 = *(const short8v*)&bp0[kc];
    short8v b1 = *(const short8v*)&bp1[kc];
    acc0 = __builtin_amdgcn_mfma_f32_16x16x32_bf16(af, b0, acc0, 0, 0, 0);
    acc1 = __builtin_amdgcn_mfma_f32_16x16x32_bf16(af, b1, acc1, 0, 0, 0);
  }
  int row = bm * 64 + w * 16 + quad * 4;
  int col = bn * 32 + m;
#pragma unroll
  for (int r = 0; r < 4; ++r) {
    H2[(size_t)(row + r) * 256 + col] = acc0[r];
    H2[(size_t)(row + r) * 256 + col + 16] = acc1[r];
  }
}

// ---------------------------------------------------------------------------
// out[b] = sum_c silu(H2[b,c]+ob2[c])*ow3[c] + ob3. 8 rows/block, grid B_/8, 256
__global__ __launch_bounds__(256) void k_out(
    const float* __restrict__ H2, const float* __restrict__ ob2,
    const float* __restrict__ ow3, const float* __restrict__ ob3,
    float* __restrict__ out) {
  __shared__ float sdot[32];
  int tid = threadIdx.x;
  int b0 = blockIdx.x * 8;
  int wv = tid >> 6;
  float b2 = ob2[tid], w3 = ow3[tid];
#pragma unroll
  for (int r = 0; r < 8; ++r) {
    float v = siluf(H2[(size_t)(b0 + r) * 256 + tid] + b2) * w3;
    v = wredsum(v);
    if ((tid & 63) == 0) sdot[r * 4 + wv] = v;
  }
  __syncthreads();
  if (tid < 8) {
    out[b0 + tid] = sdot[tid * 4] + sdot[tid * 4 + 1] + sdot[tid * 4 + 2] + sdot[tid * 4 + 3] +
                    ob3[0];
  }
}

// ---------------------------------------------------------------------------
extern "C" void kernel_launch(void* const* d_in, const int* in_sizes, int n_in,
                              void* d_out, int out_size, void* d_ws, size_t ws_size,
                              hipStream_t stream) {
  const int* cand_tok = (const int*)d_in[0];
  const int* ctx_tok = (const int*)d_in[1];
  const int* hist_tok = (const int*)d_in[2];
  const int* hist_pos = (const int*)d_in[3];
  const int* hist_grp = (const int*)d_in[4];
  const int* cand_mask = (const int*)d_in[5];
  const int* ctx_mask = (const int*)d_in[6];
  const int* hist_mask = (const int*)d_in[7];
  const float* hist_times = (const float*)d_in[8];
  const float* dense_feat = (const float*)d_in[9];
  const float* tok_emb = (const float*)d_in[10];
  const float* pos_emb = (const float*)d_in[11];
  const float* grp_emb = (const float*)d_in[12];
  const float* time_w1 = (const float*)d_in[13];
  const float* time_b1 = (const float*)d_in[14];
  const float* time_w2 = (const float*)d_in[15];
  const float* time_b2 = (const float*)d_in[16];
  const float* comp_w = (const float*)d_in[17];
  const float* comp_b = (const float*)d_in[18];
  const float* comp_g = (const float*)d_in[19];
  const float* comp_bt = (const float*)d_in[20];
  const float* dense_w = (const float*)d_in[21];
  const float* dense_b = (const float*)d_in[22];
  const float* dense_g = (const float*)d_in[23];
  const float* dense_bt = (const float*)d_in[24];
  const float* query_w = (const float*)d_in[25];
  const float* query_b = (const float*)d_in[26];
  const float* query_g = (const float*)d_in[27];
  const float* query_bt = (const float*)d_in[28];
  const float* out_w1 = (const float*)d_in[29];
  const float* out_b1 = (const float*)d_in[30];
  const float* out_g = (const float*)d_in[31];
  const float* out_bt = (const float*)d_in[32];
  const float* out_w2 = (const float*)d_in[33];
  const float* out_b2 = (const float*)d_in[34];
  const float* out_w3 = (const float*)d_in[35];
  const float* out_b3 = (const float*)d_in[36];
  float* out = (float*)d_out;

  // Workspace — packed into the validated 4,950,016-float footprint.
  // CC replaces F/gvec/MV. H1S aliases query (dead after k_attn3);
  // H2 aliases HD (dead after k_dense_ln).
  float* ws = (float*)d_ws;
  float* E = ws;                                     // 640
  float* CC = ws + 640;                              // 5632 (end 6272, pad 8192)
  float* query = ws + 8192;                          // 262144 (end 270336)
  unsigned short* H1S = (unsigned short*)(ws + 8192);        // aliases query
  float* HD = ws + 270336;                           // 1048576 (end 1318912)
  float* H2 = HD;                                    // 524288 (aliases dead HD)
  unsigned short* OW2BT = (unsigned short*)(ws + 1318912);   // 65536 fl (end 1384448)
  unsigned short* QWBT = (unsigned short*)(ws + 1384448);    // 57344 fl (end 1441792)
  unsigned short* DWBT = (unsigned short*)(ws + 1441792);    // 65536 fl (end 1507328)
  unsigned short* DB = (unsigned short*)(ws + 1507328);      // 262144 fl (end 1769472)
  float* H1 = ws + 2099200;                          // 1048576 (end 3147776)
  unsigned short* FB = (unsigned short*)(ws + 3147776);      // 1441792 fl (end 4589568)
  unsigned short* OW1BT = (unsigned short*)(ws + 4589568);   // 360448 fl (end 4950016)

  k0_poly<<<1, 128, 0, stream>>>(time_w1, time_b1, time_w2, time_b2,
                                 comp_w, comp_b, grp_emb, comp_g, comp_bt, E, CC);
  k_convw1<<<2816, 256, 0, stream>>>(out_w1, OW1BT);
  k_convmisc<<<3520, 256, 0, stream>>>(out_w2, query_w, dense_w, dense_feat,
                                       OW2BT, QWBT, DWBT, DB);
  k_candctx<<<B_, 128, 0, stream>>>(cand_tok, ctx_tok, cand_mask, ctx_mask,
                                    tok_emb, FB);
  k_comp_pow<<<B_, 256, 0, stream>>>(hist_times, hist_grp, hist_mask, CC, FB);
  k_gemm_d<<<256, 256, 0, stream>>>(DB, DWBT, HD);
  k_dense_ln<<<B_ / 4, 256, 0, stream>>>(HD, dense_b, dense_g, dense_bt, FB);
  k_query_mfma<<<32, 256, 0, stream>>>(FB, QWBT, query_b, query_g, query_bt, query);
  k_attn3<<<B_, 256, 0, stream>>>(hist_tok, hist_pos, hist_grp, hist_mask, hist_times,
                                  tok_emb, pos_emb, grp_emb, query, E, FB);
  k_gemm1<<<256, 256, 0, stream>>>(FB, OW1BT, H1);
  k_ln1<<<B_ / 4, 256, 0, stream>>>(H1, out_b1, out_g, out_bt, H1S);
  k_gemm2<<<256, 256, 0, stream>>>(H1S, OW2BT, H2);
  k_out<<<B_ / 8, 256, 0, stream>>>(H2, out_b2, out_w3, out_b3, out);
}

// Round 11
// 329.468 us; speedup vs baseline: 1.8670x; 1.0488x over previous
//
#include <hip/hip_runtime.h>
#include <hip/hip_bf16.h>

#define B_ 2048
#define LC_ 20
#define LX_ 20
#define LH_ 200
#define D_ 128
#define H_ 512
#define DENSE_ 256

typedef __attribute__((ext_vector_type(8))) short short8v;
typedef __attribute__((ext_vector_type(4))) float floatx4;

__device__ __forceinline__ float siluf(float x) { return x / (1.f + __expf(-x)); }

__device__ __forceinline__ unsigned short f2bf(float f) {
  return __builtin_bit_cast(unsigned short, __float2bfloat16(f));
}
__device__ __forceinline__ float bf2f(unsigned short u) {
  return __bfloat162float(__builtin_bit_cast(__hip_bfloat16, u));
}

__device__ __forceinline__ float wredsum(float v) {
#pragma unroll
  for (int off = 32; off > 0; off >>= 1) v += __shfl_xor(v, off, 64);
  return v;
}

// pair index into the 15-entry upper-triangular (p<=q, 5x5) list
__device__ __forceinline__ int cidx(int a, int b) {
  if (a > b) { int t = a; a = b; b = t; }
  const int base[5] = {0, 5, 9, 12, 14};
  return base[a] + (b - a);
}

// ---------------------------------------------------------------------------
// K0 (1 block, 128 threads): E_p for attention; CC[g][p][j] degree-10 fit of
// the full comp channel map (LN moments analytic). See round-10 notes.
__global__ __launch_bounds__(128) void k0_poly(
    const float* __restrict__ w1, const float* __restrict__ b1,
    const float* __restrict__ W2, const float* __restrict__ b2,
    const float* __restrict__ comp_w, const float* __restrict__ comp_b,
    const float* __restrict__ grp_emb,
    const float* __restrict__ cg_, const float* __restrict__ cbt_,
    float* __restrict__ E, float* __restrict__ CC) {
  __shared__ float sc[5 * 128];
  __shared__ float sE[5 * 128];
  __shared__ float sF2[5 * 128];
  __shared__ float sGv[4 * 128];
  __shared__ float s48[48];
  __shared__ float sMC[20], sVC[36];
  int k = threadIdx.x;
  {
    float w = w1[k], bb = b1[k];
    float y0 = siluf(bb);
    float y1 = siluf(0.25f * w + bb);
    float y2 = siluf(0.50f * w + bb);
    float y3 = siluf(0.75f * w + bb);
    float y4 = siluf(w + bb);
    float d1 = y1 - y0;
    float d2 = y2 - 2.f * y1 + y0;
    float d3 = y3 - 3.f * y2 + 3.f * y1 - y0;
    float d4 = y4 - 4.f * y3 + 6.f * y2 - 4.f * y1 + y0;
    float c0 = y0;
    float c1 = d1 - 0.5f * d2 + d3 * (1.f / 3.f) - 0.25f * d4;
    float c2 = 0.5f * d2 - 0.5f * d3 + (11.f / 24.f) * d4;
    float c3 = d3 * (1.f / 6.f) - 0.25f * d4;
    float c4 = d4 * (1.f / 24.f);
    sc[0 * 128 + k] = c0;
    sc[1 * 128 + k] = c1 * 4.f;
    sc[2 * 128 + k] = c2 * 16.f;
    sc[3 * 128 + k] = c3 * 64.f;
    sc[4 * 128 + k] = c4 * 256.f;
  }
  __syncthreads();
  int j = k;
  float e[5] = {0, 0, 0, 0, 0};
  for (int kk = 0; kk < 128; ++kk) {
    float wv = W2[kk * 128 + j];
#pragma unroll
    for (int p = 0; p < 5; ++p) e[p] += sc[p * 128 + kk] * wv;
  }
  e[0] += b2[j];
#pragma unroll
  for (int p = 0; p < 5; ++p) { sE[p * 128 + j] = e[p]; E[p * 128 + j] = e[p]; }
  __syncthreads();
  float f[5] = {0, 0, 0, 0, 0};
  for (int kk = 0; kk < 128; ++kk) {
    float wv = comp_w[(128 + kk) * 128 + j];
#pragma unroll
    for (int p = 0; p < 5; ++p) f[p] += sE[p * 128 + kk] * wv;
  }
  f[0] += comp_b[j];
#pragma unroll
  for (int p = 0; p < 5; ++p) sF2[p * 128 + j] = f[p];
  for (int g = 0; g < 4; ++g) {
    float acc = 0.f;
    for (int kk = 0; kk < 128; ++kk) acc += grp_emb[g * 128 + kk] * comp_w[kk * 128 + j];
    sGv[g * 128 + j] = acc;
  }
  __syncthreads();
  if (k < 48) {
    const float* va;
    const float* vb = nullptr;
    int t = k;
    if (t < 5) va = &sF2[t * 128];
    else if (t < 9) va = &sGv[(t - 5) * 128];
    else if (t < 13) { va = &sGv[(t - 9) * 128]; vb = va; }
    else if (t < 33) {
      int g = (t - 13) / 5, p = (t - 13) % 5;
      va = &sGv[g * 128]; vb = &sF2[p * 128];
    } else {
      int idx = t - 33;
      int a = 0;
      if (idx >= 14) a = 4;
      else if (idx >= 12) a = 3;
      else if (idx >= 9) a = 2;
      else if (idx >= 5) a = 1;
      const int base[5] = {0, 5, 9, 12, 14};
      int bcol = a + (idx - base[a]);
      va = &sF2[a * 128]; vb = &sF2[bcol * 128];
    }
    float s = 0.f;
    if (vb) { for (int kk = 0; kk < 128; ++kk) s += va[kk] * vb[kk]; }
    else    { for (int kk = 0; kk < 128; ++kk) s += va[kk]; }
    s48[t] = s * (1.f / 128.f);
  }
  __syncthreads();
  if (k < 20) {
    int g = k / 5, p = k % 5;
    sMC[g * 5 + p] = s48[p] + (p == 0 ? s48[5 + g] : 0.f);
  }
  if (k < 36) {
    int g = k / 9, kk = k % 9;
    float v = (kk == 0 ? s48[9 + g] : 0.f);
    if (kk < 5) v += 2.f * s48[13 + g * 5 + kk];
#pragma unroll
    for (int p = 0; p < 5; ++p) {
      int q = kk - p;
      if (q >= 0 && q <= 4) v += s48[33 + cidx(p, q)];
    }
    sVC[g * 9 + kk] = v;
  }
  __syncthreads();
  const float nodes[11] = {0.f, 0.02447174185f, 0.09549150281f, 0.2061073739f,
                           0.3454915028f, 0.5f, 0.6545084972f, 0.7938926261f,
                           0.9045084972f, 0.9755282581f, 1.f};
  float cgj = cg_[j], btj = cbt_[j];
  float F0 = sF2[j], F1 = sF2[128 + j], F2v = sF2[256 + j], F3 = sF2[384 + j], F4 = sF2[512 + j];
  for (int g = 0; g < 4; ++g) {
    const float* mc = &sMC[g * 5];
    const float* vc = &sVC[g * 9];
    float gv = sGv[g * 128 + j];
    float fv[11];
#pragma unroll
    for (int n = 0; n < 11; ++n) {
      float t = nodes[n];
      float mean = (((mc[4] * t + mc[3]) * t + mc[2]) * t + mc[1]) * t + mc[0];
      float e2 = vc[8];
#pragma unroll
      for (int p = 7; p >= 0; --p) e2 = e2 * t + vc[p];
      float rstd = rsqrtf(e2 - mean * mean + 1e-5f);
      float pre = gv + ((((F4 * t + F3) * t + F2v) * t + F1) * t + F0);
      fv[n] = siluf((pre - mean) * rstd * cgj + btj);
    }
#pragma unroll
    for (int ord = 1; ord <= 10; ++ord) {
#pragma unroll
      for (int n = 10; n >= 1; --n) {
        if (n >= ord) fv[n] = (fv[n] - fv[n - 1]) / (nodes[n] - nodes[n - ord]);
      }
    }
    float c[11];
#pragma unroll
    for (int i = 0; i < 11; ++i) c[i] = 0.f;
    c[0] = fv[10];
#pragma unroll
    for (int n = 9; n >= 0; --n) {
      int deg = 9 - n;
      float x = nodes[n];
      c[deg + 1] = c[deg];
#pragma unroll
      for (int i = 10; i >= 1; --i) {
        if (i <= deg) c[i] = c[i - 1] - x * c[i];
      }
      c[0] = fv[n] - x * c[0];
    }
#pragma unroll
    for (int p = 0; p < 11; ++p) CC[(g * 11 + p) * 128 + j] = c[p];
  }
}

// ---------------------------------------------------------------------------
// out_w1 [1408x512] f32 -> OW1BT [512x1408] bf16 via LDS tile transpose.
// grid 176 (22 k-tiles x 8 n-tiles), block 256, coalesced both sides.
__global__ __launch_bounds__(256) void k_convw1t(
    const float* __restrict__ ow1, unsigned short* __restrict__ BT) {
  __shared__ float tile[64][65];
  int bk = blockIdx.x % 22;
  int bn = blockIdx.x / 22;
  int tx = threadIdx.x & 63, ty = threadIdx.x >> 6;
#pragma unroll
  for (int r = 0; r < 16; ++r) {
    int kl = ty * 16 + r;
    tile[kl][tx] = ow1[(size_t)(bk * 64 + kl) * 512 + bn * 64 + tx];
  }
  __syncthreads();
#pragma unroll
  for (int r = 0; r < 16; ++r) {
    int nl = ty * 16 + r;
    BT[(size_t)(bn * 64 + nl) * 1408 + bk * 64 + tx] = f2bf(tile[tx][nl]);
  }
}

// fused small conversions: ow2->OW2BT, qw->QWBT, dw->DWBT, df->DB. grid 3520, 256
__global__ __launch_bounds__(256) void k_convmisc(
    const float* __restrict__ ow2, const float* __restrict__ qw,
    const float* __restrict__ dw, const float* __restrict__ df,
    unsigned short* __restrict__ OW2BT, unsigned short* __restrict__ QWBT,
    unsigned short* __restrict__ DWBT, unsigned short* __restrict__ DB) {
  int idx = blockIdx.x * 256 + threadIdx.x;
  if (idx < 131072) {
    int n = idx >> 9, k = idx & 511;
    OW2BT[(size_t)n * 512 + k] = f2bf(ow2[(size_t)k * 256 + n]);
  } else if (idx < 245760) {
    int i = idx - 131072;
    int n = i / 896, k = i - n * 896;
    QWBT[(size_t)n * 896 + k] = f2bf(qw[(size_t)k * 128 + n]);
  } else if (idx < 376832) {
    int i = idx - 245760;
    int n = i >> 8, k = i & 255;
    DWBT[(size_t)n * 256 + k] = f2bf(dw[(size_t)k * 512 + n]);
  } else {
    int i = idx - 376832;
    DB[i] = f2bf(df[i]);
  }
}

// ---------------------------------------------------------------------------
// cand_s / ctx_s masked means -> FB[0:256) bf16. grid B_, block 256
// (half 0 -> cand, half 1 -> ctx, concurrent)
__global__ __launch_bounds__(256) void k_candctx(
    const int* __restrict__ ctok, const int* __restrict__ xtok,
    const int* __restrict__ cmask, const int* __restrict__ xmask,
    const float* __restrict__ tok_emb, unsigned short* __restrict__ FB) {
  int b = blockIdx.x, tid = threadIdx.x;
  int j = tid & 127, half = tid >> 7;
  float acc = 0.f, cnt = 0.f;
  if (half == 0) {
#pragma unroll
    for (int l = 0; l < LC_; ++l) {
      float mv = (float)cmask[b * LC_ + l];
      acc += mv * tok_emb[(size_t)ctok[b * LC_ + l] * 128 + j];
      cnt += mv;
    }
    FB[(size_t)b * 1408 + j] = f2bf(acc / fmaxf(cnt, 1.f));
  } else {
#pragma unroll
    for (int l = 0; l < LX_; ++l) {
      float mv = (float)xmask[b * LX_ + l];
      acc += mv * tok_emb[(size_t)xtok[b * LX_ + l] * 128 + j];
      cnt += mv;
    }
    FB[(size_t)b * 1408 + 128 + j] = f2bf(acc / fmaxf(cnt, 1.f));
  }
}

// ---------------------------------------------------------------------------
// comp summary via per-(g,p) power sums + precomputed poly CC. grid B_, 256
__global__ __launch_bounds__(256) void k_comp_pow(
    const float* __restrict__ times, const int* __restrict__ groups,
    const int* __restrict__ hmask, const float* __restrict__ CC,
    unsigned short* __restrict__ FB) {
  __shared__ float sPow[LH_ * 11];
  __shared__ int sg[LH_];
  __shared__ float sS[4 * 44];
  __shared__ float sSf[44];
  int tid = threadIdx.x, b = blockIdx.x;
  if (tid < LH_) {
    float t = times[b * LH_ + tid];
    int mk = hmask[b * LH_ + tid];
    sg[tid] = mk ? groups[b * LH_ + tid] : -1;
    float pw = 1.f;
#pragma unroll
    for (int p = 0; p < 11; ++p) { sPow[tid * 11 + p] = pw; pw *= t; }
  }
  __syncthreads();
  int lane = tid & 63, w = tid >> 6;
  if (lane < 44) {
    int g = lane / 11, p = lane - 11 * g;
    float s = 0.f;
    for (int l = w * 50; l < w * 50 + 50; ++l) {
      if (sg[l] == g) s += sPow[l * 11 + p];
    }
    sS[w * 44 + lane] = s;
  }
  __syncthreads();
  if (tid < 44) sSf[tid] = sS[tid] + sS[44 + tid] + sS[88 + tid] + sS[132 + tid];
  __syncthreads();
  if (tid < 128) {
    float cnt = sSf[0] + sSf[11] + sSf[22] + sSf[33];
    float inv = 1.f / fmaxf(cnt, 1.f);
    float acc = 0.f;
#pragma unroll 4
    for (int q = 0; q < 44; ++q) acc += sSf[q] * CC[q * 128 + tid];
    FB[(size_t)b * 1408 + 384 + tid] = f2bf(acc * inv);
  }
}

// ---------------------------------------------------------------------------
// dense GEMM via bf16 MFMA: H_D[2048x512] = DB @ DWBT^T. Tile 64x64, grid 256.
__global__ __launch_bounds__(256) void k_gemm_d(
    const unsigned short* __restrict__ A, const unsigned short* __restrict__ BT,
    float* __restrict__ HD) {
  int tid = threadIdx.x;
  int bm = blockIdx.x >> 3;
  int bn = blockIdx.x & 7;
  int w = tid >> 6, lane = tid & 63;
  int m = lane & 15, quad = lane >> 4;
  const unsigned short* ap = A + (size_t)(bm * 64 + w * 16 + m) * 256 + quad * 8;
  const unsigned short* bp0 = BT + (size_t)(bn * 64 + m) * 256 + quad * 8;
  const unsigned short* bp1 = bp0 + 16 * 256;
  const unsigned short* bp2 = bp0 + 32 * 256;
  const unsigned short* bp3 = bp0 + 48 * 256;
  floatx4 acc0 = {0.f, 0.f, 0.f, 0.f};
  floatx4 acc1 = {0.f, 0.f, 0.f, 0.f};
  floatx4 acc2 = {0.f, 0.f, 0.f, 0.f};
  floatx4 acc3 = {0.f, 0.f, 0.f, 0.f};
#pragma unroll
  for (int kc = 0; kc < 256; kc += 32) {
    short8v af = *(const short8v*)&ap[kc];
    short8v b0 = *(const short8v*)&bp0[kc];
    short8v b1 = *(const short8v*)&bp1[kc];
    short8v b2 = *(const short8v*)&bp2[kc];
    short8v b3 = *(const short8v*)&bp3[kc];
    acc0 = __builtin_amdgcn_mfma_f32_16x16x32_bf16(af, b0, acc0, 0, 0, 0);
    acc1 = __builtin_amdgcn_mfma_f32_16x16x32_bf16(af, b1, acc1, 0, 0, 0);
    acc2 = __builtin_amdgcn_mfma_f32_16x16x32_bf16(af, b2, acc2, 0, 0, 0);
    acc3 = __builtin_amdgcn_mfma_f32_16x16x32_bf16(af, b3, acc3, 0, 0, 0);
  }
  int row = bm * 64 + w * 16 + quad * 4;
  int col = bn * 64 + m;
#pragma unroll
  for (int r = 0; r < 4; ++r) {
    HD[(size_t)(row + r) * 512 + col] = acc0[r];
    HD[(size_t)(row + r) * 512 + col + 16] = acc1[r];
    HD[(size_t)(row + r) * 512 + col + 32] = acc2[r];
    HD[(size_t)(row + r) * 512 + col + 48] = acc3[r];
  }
}

// ---------------------------------------------------------------------------
// bias+LN+silu on H_D -> FB[896:1408) bf16. 4 rows/block, grid B_/4, block 256
__global__ __launch_bounds__(256) void k_dense_ln(
    const float* __restrict__ HD, const float* __restrict__ dbias,
    const float* __restrict__ dg, const float* __restrict__ dbt,
    unsigned short* __restrict__ FB) {
  __shared__ float sr1[16], sr2[16];
  int tid = threadIdx.x;
  int b0 = blockIdx.x * 4;
  int wv = tid >> 6;
  float bi0 = dbias[tid], bi1 = dbias[tid + 256];
  float a0[4], a1[4];
#pragma unroll
  for (int r = 0; r < 4; ++r) {
    a0[r] = HD[(size_t)(b0 + r) * 512 + tid] + bi0;
    a1[r] = HD[(size_t)(b0 + r) * 512 + tid + 256] + bi1;
    float s1 = wredsum(a0[r] + a1[r]);
    float s2 = wredsum(a0[r] * a0[r] + a1[r] * a1[r]);
    if ((tid & 63) == 0) { sr1[r * 4 + wv] = s1; sr2[r * 4 + wv] = s2; }
  }
  __syncthreads();
  float g0 = dg[tid], g1 = dg[tid + 256], t0 = dbt[tid], t1 = dbt[tid + 256];
#pragma unroll
  for (int r = 0; r < 4; ++r) {
    float s1 = sr1[r * 4] + sr1[r * 4 + 1] + sr1[r * 4 + 2] + sr1[r * 4 + 3];
    float s2 = sr2[r * 4] + sr2[r * 4 + 1] + sr2[r * 4 + 2] + sr2[r * 4 + 3];
    float mean = s1 / 512.f, var = s2 / 512.f - mean * mean;
    float rstd = rsqrtf(var + 1e-5f);
    FB[(size_t)(b0 + r) * 1408 + 896 + tid] = f2bf(siluf((a0[r] - mean) * rstd * g0 + t0));
    FB[(size_t)(b0 + r) * 1408 + 896 + tid + 256] = f2bf(siluf((a1[r] - mean) * rstd * g1 + t1));
  }
}

// ---------------------------------------------------------------------------
// query via bf16 MFMA (A straight from FB), fused LN+silu epilogue.
// Tile 64M x 128N, grid 32, block 256.
__global__ __launch_bounds__(256) void k_query_mfma(
    const unsigned short* __restrict__ FB, const unsigned short* __restrict__ QWBT,
    const float* __restrict__ qb, const float* __restrict__ qg,
    const float* __restrict__ qbt, float* __restrict__ query) {
  int tid = threadIdx.x;
  int w = tid >> 6, lane = tid & 63;
  int m = lane & 15, quad = lane >> 4;
  const unsigned short* ap = FB + (size_t)(blockIdx.x * 64 + w * 16 + m) * 1408 + quad * 8;
  const unsigned short* bp = QWBT + (size_t)m * 896 + quad * 8;
  floatx4 acc[8];
#pragma unroll
  for (int nt = 0; nt < 8; ++nt) acc[nt] = {0.f, 0.f, 0.f, 0.f};
#pragma unroll 4
  for (int kc = 0; kc < 28; ++kc) {
    int fo = (kc < 8) ? kc * 32 : (kc < 12 ? 384 + (kc - 8) * 32 : 896 + (kc - 12) * 32);
    short8v af = *(const short8v*)&ap[fo];
#pragma unroll
    for (int nt = 0; nt < 8; ++nt) {
      short8v bf = *(const short8v*)&bp[(size_t)nt * 16 * 896 + kc * 32];
      acc[nt] = __builtin_amdgcn_mfma_f32_16x16x32_bf16(af, bf, acc[nt], 0, 0, 0);
    }
  }
  float bj[8], gj[8], tj[8];
#pragma unroll
  for (int nt = 0; nt < 8; ++nt) {
    bj[nt] = qb[nt * 16 + m];
    gj[nt] = qg[nt * 16 + m];
    tj[nt] = qbt[nt * 16 + m];
  }
#pragma unroll
  for (int r = 0; r < 4; ++r) {
    float x[8];
    float s1 = 0.f, s2 = 0.f;
#pragma unroll
    for (int nt = 0; nt < 8; ++nt) {
      x[nt] = acc[nt][r] + bj[nt];
      s1 += x[nt];
      s2 += x[nt] * x[nt];
    }
#pragma unroll
    for (int off = 1; off < 16; off <<= 1) {
      s1 += __shfl_xor(s1, off, 64);
      s2 += __shfl_xor(s2, off, 64);
    }
    float mean = s1 * (1.f / 128.f);
    float var = s2 * (1.f / 128.f) - mean * mean;
    float rstd = rsqrtf(var + 1e-5f);
    int row = blockIdx.x * 64 + w * 16 + quad * 4 + r;
#pragma unroll
    for (int nt = 0; nt < 8; ++nt) {
      query[(size_t)row * 128 + nt * 16 + m] = siluf((x[nt] - mean) * rstd * gj[nt] + tj[nt]);
    }
  }
}

// ---------------------------------------------------------------------------
// single-pass online-softmax attention, 16-lane rows (4 rows/wave concurrent),
// dwordx4 gathers, staged poly term. grid B_, block 256.
__global__ __launch_bounds__(256) void k_attn4(
    const int* __restrict__ htok, const int* __restrict__ hpos,
    const int* __restrict__ hgrp, const int* __restrict__ hmask,
    const float* __restrict__ times,
    const float* __restrict__ tok_emb, const float* __restrict__ pos_emb,
    const float* __restrict__ grp_emb,
    const float* __restrict__ query, const float* __restrict__ E,
    unsigned short* __restrict__ FB) {
  __shared__ float sq[128];
  __shared__ float sE[5 * 128];
  __shared__ float sG[4 * 128];
  __shared__ float st[LH_];
  __shared__ float spoly[LH_];
  __shared__ int stok[LH_], spos[LH_], sgrp[LH_], smk[LH_];
  __shared__ float seq[5 * 2];
  __shared__ float s_eq[5];
  __shared__ float sA[16 * 128];
  __shared__ float sL[16];
  __shared__ float sM[16 * 5];
  int tid = threadIdx.x, b = blockIdx.x;
  int lane = tid & 63, w = tid >> 6;
  int rg = lane >> 4, li = lane & 15;
  int grp16 = w * 4 + rg;
  if (tid < 128) sq[tid] = query[b * 128 + tid];
  for (int idx = tid; idx < 5 * 128; idx += 256) sE[idx] = E[idx];
  for (int idx = tid; idx < 4 * 128; idx += 256) sG[idx] = grp_emb[idx];
  for (int l = tid; l < LH_; l += 256) {
    st[l] = times[b * LH_ + l];
    stok[l] = htok[b * LH_ + l];
    spos[l] = hpos[b * LH_ + l];
    sgrp[l] = hgrp[b * LH_ + l];
    smk[l] = hmask[b * LH_ + l];
  }
  __syncthreads();
  // eq_p = E_p . q
  if (tid < 128) {
    int wh = (tid >> 6) & 1;
#pragma unroll
    for (int p = 0; p < 5; ++p) {
      float v = sE[p * 128 + tid] * sq[tid];
      v = wredsum(v);
      if ((tid & 63) == 0) seq[p * 2 + wh] = v;
    }
  }
  __syncthreads();
  if (tid < 5) s_eq[tid] = seq[tid * 2] + seq[tid * 2 + 1];
  __syncthreads();
  if (tid < LH_) {
    float t = st[tid];
    spoly[tid] = (((s_eq[4] * t + s_eq[3]) * t + s_eq[2]) * t + s_eq[1]) * t + s_eq[0];
  }
  __syncthreads();
  const float4 qa = *(const float4*)&sq[li * 8];
  const float4 qb4 = *(const float4*)&sq[li * 8 + 4];
  const float scale = 0.08838834764831845f;  // 1/sqrt(128)
  float a0 = 0.f, a1 = 0.f, a2 = 0.f, a3 = 0.f, a4 = 0.f, a5 = 0.f, a6 = 0.f, a7 = 0.f;
  float lsum = 0.f, mom1 = 0.f, mom2 = 0.f, mom3 = 0.f, mom4 = 0.f;
  for (int l = grp16; l < LH_; l += 16) {
    if (smk[l]) {
      int tok = stok[l], pos = spos[l], g = sgrp[l];
      const float* tp_ = &tok_emb[(size_t)tok * 128 + li * 8];
      const float* pp_ = &pos_emb[pos * 128 + li * 8];
      float4 ta = *(const float4*)tp_;
      float4 tb = *(const float4*)(tp_ + 4);
      float4 pa = *(const float4*)pp_;
      float4 pb = *(const float4*)(pp_ + 4);
      const float* gp_ = &sG[g * 128 + li * 8];
      float4 ga = *(const float4*)gp_;
      float4 gb = *(const float4*)(gp_ + 4);
      float v0 = ta.x + pa.x + ga.x, v1 = ta.y + pa.y + ga.y;
      float v2 = ta.z + pa.z + ga.z, v3 = ta.w + pa.w + ga.w;
      float v4 = tb.x + pb.x + gb.x, v5 = tb.y + pb.y + gb.y;
      float v6 = tb.z + pb.z + gb.z, v7 = tb.w + pb.w + gb.w;
      float d = v0 * qa.x + v1 * qa.y + v2 * qa.z + v3 * qa.w +
                v4 * qb4.x + v5 * qb4.y + v6 * qb4.z + v7 * qb4.w;
      d += __shfl_xor(d, 1, 64);
      d += __shfl_xor(d, 2, 64);
      d += __shfl_xor(d, 4, 64);
      d += __shfl_xor(d, 8, 64);
      float e = __expf((d + spoly[l]) * scale);
      float t = st[l];
      lsum += e;
      a0 += e * v0; a1 += e * v1; a2 += e * v2; a3 += e * v3;
      a4 += e * v4; a5 += e * v5; a6 += e * v6; a7 += e * v7;
      float tp = e * t;
      mom1 += tp; tp *= t;
      mom2 += tp; tp *= t;
      mom3 += tp; tp *= t;
      mom4 += tp;
    }
  }
  float* ap2 = &sA[grp16 * 128 + li * 8];
  ap2[0] = a0; ap2[1] = a1; ap2[2] = a2; ap2[3] = a3;
  ap2[4] = a4; ap2[5] = a5; ap2[6] = a6; ap2[7] = a7;
  if (li == 0) {
    sL[grp16] = lsum;
    sM[grp16 * 5 + 1] = mom1; sM[grp16 * 5 + 2] = mom2;
    sM[grp16 * 5 + 3] = mom3; sM[grp16 * 5 + 4] = mom4;
  }
  __syncthreads();
  if (tid < 128) {
    int i = tid;
    float L = 0.f;
#pragma unroll
    for (int k = 0; k < 16; ++k) L += sL[k];
    float inv = 1.f / L;
    float v = 0.f;
#pragma unroll
    for (int k = 0; k < 16; ++k) v += sA[k * 128 + i];
    v *= inv;
    v += sE[i];
#pragma unroll
    for (int p = 1; p < 5; ++p) {
      float mp = 0.f;
#pragma unroll
      for (int k = 0; k < 16; ++k) mp += sM[k * 5 + p];
      v += mp * inv * sE[p * 128 + i];
    }
    unsigned short* row = FB + (size_t)b * 1408;
    float c = bf2f(row[i]), cm = bf2f(row[384 + i]);
    row[256 + i] = f2bf(v);
    row[512 + i] = f2bf(c * v);
    row[640 + i] = f2bf(c * cm);
    row[768 + i] = f2bf(fabsf(v - cm));
  }
}

// ---------------------------------------------------------------------------
// GEMM1 via bf16 MFMA: H1[2048x512] = FB @ OW1BT^T. Tile 64x64, grid 256, 256.
__global__ __launch_bounds__(256) void k_gemm1(
    const unsigned short* __restrict__ A, const unsigned short* __restrict__ BT,
    float* __restrict__ H1) {
  int tid = threadIdx.x;
  int bm = blockIdx.x >> 3;
  int bn = blockIdx.x & 7;
  int w = tid >> 6, lane = tid & 63;
  int m = lane & 15, quad = lane >> 4;
  const unsigned short* ap = A + (size_t)(bm * 64 + w * 16 + m) * 1408 + quad * 8;
  const unsigned short* bp0 = BT + (size_t)(bn * 64 + m) * 1408 + quad * 8;
  const unsigned short* bp1 = bp0 + 16 * 1408;
  const unsigned short* bp2 = bp0 + 32 * 1408;
  const unsigned short* bp3 = bp0 + 48 * 1408;
  floatx4 acc0 = {0.f, 0.f, 0.f, 0.f};
  floatx4 acc1 = {0.f, 0.f, 0.f, 0.f};
  floatx4 acc2 = {0.f, 0.f, 0.f, 0.f};
  floatx4 acc3 = {0.f, 0.f, 0.f, 0.f};
#pragma unroll 4
  for (int kc = 0; kc < 1408; kc += 32) {
    short8v af = *(const short8v*)&ap[kc];
    short8v b0 = *(const short8v*)&bp0[kc];
    short8v b1 = *(const short8v*)&bp1[kc];
    short8v b2 = *(const short8v*)&bp2[kc];
    short8v b3 = *(const short8v*)&bp3[kc];
    acc0 = __builtin_amdgcn_mfma_f32_16x16x32_bf16(af, b0, acc0, 0, 0, 0);
    acc1 = __builtin_amdgcn_mfma_f32_16x16x32_bf16(af, b1, acc1, 0, 0, 0);
    acc2 = __builtin_amdgcn_mfma_f32_16x16x32_bf16(af, b2, acc2, 0, 0, 0);
    acc3 = __builtin_amdgcn_mfma_f32_16x16x32_bf16(af, b3, acc3, 0, 0, 0);
  }
  int row = bm * 64 + w * 16 + quad * 4;
  int col = bn * 64 + m;
#pragma unroll
  for (int r = 0; r < 4; ++r) {
    H1[(size_t)(row + r) * 512 + col] = acc0[r];
    H1[(size_t)(row + r) * 512 + col + 16] = acc1[r];
    H1[(size_t)(row + r) * 512 + col + 32] = acc2[r];
    H1[(size_t)(row + r) * 512 + col + 48] = acc3[r];
  }
}

// ---------------------------------------------------------------------------
// LN+silu on H1 (+ob1) -> H1S bf16. 4 rows/block, grid B_/4, block 256
__global__ __launch_bounds__(256) void k_ln1(
    const float* __restrict__ H1, const float* __restrict__ ob1,
    const float* __restrict__ og, const float* __restrict__ obt,
    unsigned short* __restrict__ H1S) {
  __shared__ float sr1[16], sr2[16];
  int tid = threadIdx.x;
  int b0 = blockIdx.x * 4;
  int wv = tid >> 6;
  float bi0 = ob1[tid], bi1 = ob1[tid + 256];
  float a0[4], a1[4];
#pragma unroll
  for (int r = 0; r < 4; ++r) {
    a0[r] = H1[(size_t)(b0 + r) * 512 + tid] + bi0;
    a1[r] = H1[(size_t)(b0 + r) * 512 + tid + 256] + bi1;
    float s1 = wredsum(a0[r] + a1[r]);
    float s2 = wredsum(a0[r] * a0[r] + a1[r] * a1[r]);
    if ((tid & 63) == 0) { sr1[r * 4 + wv] = s1; sr2[r * 4 + wv] = s2; }
  }
  __syncthreads();
  float g0 = og[tid], g1 = og[tid + 256], t0 = obt[tid], t1 = obt[tid + 256];
#pragma unroll
  for (int r = 0; r < 4; ++r) {
    float s1 = sr1[r * 4] + sr1[r * 4 + 1] + sr1[r * 4 + 2] + sr1[r * 4 + 3];
    float s2 = sr2[r * 4] + sr2[r * 4 + 1] + sr2[r * 4 + 2] + sr2[r * 4 + 3];
    float mean = s1 / 512.f, var = s2 / 512.f - mean * mean;
    float rstd = rsqrtf(var + 1e-5f);
    H1S[(size_t)(b0 + r) * 512 + tid] = f2bf(siluf((a0[r] - mean) * rstd * g0 + t0));
    H1S[(size_t)(b0 + r) * 512 + tid + 256] = f2bf(siluf((a1[r] - mean) * rstd * g1 + t1));
  }
}

// ---------------------------------------------------------------------------
// GEMM2 via bf16 MFMA: H2[2048x256] = H1S @ OW2BT^T. Tile 64x32, grid 256.
__global__ __launch_bounds__(256) void k_gemm2(
    const unsigned short* __restrict__ A, const unsigned short* __restrict__ BT,
    float* __restrict__ H2) {
  int tid = threadIdx.x;
  int bm = blockIdx.x >> 3;
  int bn = blockIdx.x & 7;
  int w = tid >> 6, lane = tid & 63;
  int m = lane & 15, quad = lane >> 4;
  const unsigned short* ap = A + (size_t)(bm * 64 + w * 16 + m) * 512 + quad * 8;
  const unsigned short* bp0 = BT + (size_t)(bn * 32 + m) * 512 + quad * 8;
  const unsigned short* bp1 = bp0 + 16 * 512;
  floatx4 acc0 = {0.f, 0.f, 0.f, 0.f};
  floatx4 acc1 = {0.f, 0.f, 0.f, 0.f};
#pragma unroll
  for (int kc = 0; kc < 512; kc += 32) {
    short8v af = *(const short8v*)&ap[kc];
    short8v b0 = *(const short8v*)&bp0[kc];
    short8v b1 = *(const short8v*)&bp1[kc];
    acc0 = __builtin_amdgcn_mfma_f32_16x16x32_bf16(af, b0, acc0, 0, 0, 0);
    acc1 = __builtin_amdgcn_mfma_f32_16x16x32_bf16(af, b1, acc1, 0, 0, 0);
  }
  int row = bm * 64 + w * 16 + quad * 4;
  int col = bn * 32 + m;
#pragma unroll
  for (int r = 0; r < 4; ++r) {
    H2[(size_t)(row + r) * 256 + col] = acc0[r];
    H2[(size_t)(row + r) * 256 + col + 16] = acc1[r];
  }
}

// ---------------------------------------------------------------------------
// out[b] = sum_c silu(H2[b,c]+ob2[c])*ow3[c] + ob3. 8 rows/block, grid B_/8, 256
__global__ __launch_bounds__(256) void k_out(
    const float* __restrict__ H2, const float* __restrict__ ob2,
    const float* __restrict__ ow3, const float* __restrict__ ob3,
    float* __restrict__ out) {
  __shared__ float sdot[32];
  int tid = threadIdx.x;
  int b0 = blockIdx.x * 8;
  int wv = tid >> 6;
  float b2 = ob2[tid], w3 = ow3[tid];
#pragma unroll
  for (int r = 0; r < 8; ++r) {
    float v = siluf(H2[(size_t)(b0 + r) * 256 + tid] + b2) * w3;
    v = wredsum(v);
    if ((tid & 63) == 0) sdot[r * 4 + wv] = v;
  }
  __syncthreads();
  if (tid < 8) {
    out[b0 + tid] = sdot[tid * 4] + sdot[tid * 4 + 1] + sdot[tid * 4 + 2] + sdot[tid * 4 + 3] +
                    ob3[0];
  }
}

// ---------------------------------------------------------------------------
extern "C" void kernel_launch(void* const* d_in, const int* in_sizes, int n_in,
                              void* d_out, int out_size, void* d_ws, size_t ws_size,
                              hipStream_t stream) {
  const int* cand_tok = (const int*)d_in[0];
  const int* ctx_tok = (const int*)d_in[1];
  const int* hist_tok = (const int*)d_in[2];
  const int* hist_pos = (const int*)d_in[3];
  const int* hist_grp = (const int*)d_in[4];
  const int* cand_mask = (const int*)d_in[5];
  const int* ctx_mask = (const int*)d_in[6];
  const int* hist_mask = (const int*)d_in[7];
  const float* hist_times = (const float*)d_in[8];
  const float* dense_feat = (const float*)d_in[9];
  const float* tok_emb = (const float*)d_in[10];
  const float* pos_emb = (const float*)d_in[11];
  const float* grp_emb = (const float*)d_in[12];
  const float* time_w1 = (const float*)d_in[13];
  const float* time_b1 = (const float*)d_in[14];
  const float* time_w2 = (const float*)d_in[15];
  const float* time_b2 = (const float*)d_in[16];
  const float* comp_w = (const float*)d_in[17];
  const float* comp_b = (const float*)d_in[18];
  const float* comp_g = (const float*)d_in[19];
  const float* comp_bt = (const float*)d_in[20];
  const float* dense_w = (const float*)d_in[21];
  const float* dense_b = (const float*)d_in[22];
  const float* dense_g = (const float*)d_in[23];
  const float* dense_bt = (const float*)d_in[24];
  const float* query_w = (const float*)d_in[25];
  const float* query_b = (const float*)d_in[26];
  const float* query_g = (const float*)d_in[27];
  const float* query_bt = (const float*)d_in[28];
  const float* out_w1 = (const float*)d_in[29];
  const float* out_b1 = (const float*)d_in[30];
  const float* out_g = (const float*)d_in[31];
  const float* out_bt = (const float*)d_in[32];
  const float* out_w2 = (const float*)d_in[33];
  const float* out_b2 = (const float*)d_in[34];
  const float* out_w3 = (const float*)d_in[35];
  const float* out_b3 = (const float*)d_in[36];
  float* out = (float*)d_out;

  // Workspace — validated 4,950,016-float footprint (unchanged layout).
  float* ws = (float*)d_ws;
  float* E = ws;                                     // 640
  float* CC = ws + 640;                              // 5632 (pad to 8192)
  float* query = ws + 8192;                          // 262144
  unsigned short* H1S = (unsigned short*)(ws + 8192);        // aliases query
  float* HD = ws + 270336;                           // 1048576
  float* H2 = HD;                                    // aliases dead HD
  unsigned short* OW2BT = (unsigned short*)(ws + 1318912);   // 65536 fl
  unsigned short* QWBT = (unsigned short*)(ws + 1384448);    // 57344 fl
  unsigned short* DWBT = (unsigned short*)(ws + 1441792);    // 65536 fl
  unsigned short* DB = (unsigned short*)(ws + 1507328);      // 262144 fl
  float* H1 = ws + 2099200;                          // 1048576
  unsigned short* FB = (unsigned short*)(ws + 3147776);      // 1441792 fl
  unsigned short* OW1BT = (unsigned short*)(ws + 4589568);   // 360448 fl

  k0_poly<<<1, 128, 0, stream>>>(time_w1, time_b1, time_w2, time_b2,
                                 comp_w, comp_b, grp_emb, comp_g, comp_bt, E, CC);
  k_convw1t<<<176, 256, 0, stream>>>(out_w1, OW1BT);
  k_convmisc<<<3520, 256, 0, stream>>>(out_w2, query_w, dense_w, dense_feat,
                                       OW2BT, QWBT, DWBT, DB);
  k_candctx<<<B_, 256, 0, stream>>>(cand_tok, ctx_tok, cand_mask, ctx_mask,
                                    tok_emb, FB);
  k_comp_pow<<<B_, 256, 0, stream>>>(hist_times, hist_grp, hist_mask, CC, FB);
  k_gemm_d<<<256, 256, 0, stream>>>(DB, DWBT, HD);
  k_dense_ln<<<B_ / 4, 256, 0, stream>>>(HD, dense_b, dense_g, dense_bt, FB);
  k_query_mfma<<<32, 256, 0, stream>>>(FB, QWBT, query_b, query_g, query_bt, query);
  k_attn4<<<B_, 256, 0, stream>>>(hist_tok, hist_pos, hist_grp, hist_mask, hist_times,
                                  tok_emb, pos_emb, grp_emb, query, E, FB);
  k_gemm1<<<256, 256, 0, stream>>>(FB, OW1BT, H1);
  k_ln1<<<B_ / 4, 256, 0, stream>>>(H1, out_b1, out_g, out_bt, H1S);
  k_gemm2<<<256, 256, 0, stream>>>(H1S, OW2BT, H2);
  k_out<<<B_ / 8, 256, 0, stream>>>(H2, out_b2, out_w3, out_b3, out);
}

// Round 12
// 316.118 us; speedup vs baseline: 1.9458x; 1.0422x over previous
//
#include <hip/hip_runtime.h>
#include <hip/hip_bf16.h>

#define B_ 2048
#define LC_ 20
#define LX_ 20
#define LH_ 200
#define D_ 128
#define H_ 512
#define DENSE_ 256

typedef __attribute__((ext_vector_type(8))) short short8v;
typedef __attribute__((ext_vector_type(4))) float floatx4;

__device__ __forceinline__ float siluf(float x) { return x / (1.f + __expf(-x)); }

__device__ __forceinline__ unsigned short f2bf(float f) {
  return __builtin_bit_cast(unsigned short, __float2bfloat16(f));
}
__device__ __forceinline__ float bf2f(unsigned short u) {
  return __bfloat162float(__builtin_bit_cast(__hip_bfloat16, u));
}

__device__ __forceinline__ float wredsum(float v) {
#pragma unroll
  for (int off = 32; off > 0; off >>= 1) v += __shfl_xor(v, off, 64);
  return v;
}

// pair index into the 15-entry upper-triangular (p<=q, 5x5) list
__device__ __forceinline__ int cidx(int a, int b) {
  if (a > b) { int t = a; a = b; b = t; }
  const int base[5] = {0, 5, 9, 12, 14};
  return base[a] + (b - a);
}

// ---------------------------------------------------------------------------
// k0a: E_p = c_p @ W2 (E_0 += time_b2). grid 5 (one block per p), block 128.
__global__ __launch_bounds__(128) void k0a_E(
    const float* __restrict__ w1, const float* __restrict__ b1,
    const float* __restrict__ W2, const float* __restrict__ b2,
    float* __restrict__ E) {
  __shared__ float sc[128];
  int j = threadIdx.x, p = blockIdx.x;
  {
    float w = w1[j], bb = b1[j];
    float y0 = siluf(bb);
    float y1 = siluf(0.25f * w + bb);
    float y2 = siluf(0.50f * w + bb);
    float y3 = siluf(0.75f * w + bb);
    float y4 = siluf(w + bb);
    float d1 = y1 - y0;
    float d2 = y2 - 2.f * y1 + y0;
    float d3 = y3 - 3.f * y2 + 3.f * y1 - y0;
    float d4 = y4 - 4.f * y3 + 6.f * y2 - 4.f * y1 + y0;
    float c0 = y0;
    float c1 = d1 - 0.5f * d2 + d3 * (1.f / 3.f) - 0.25f * d4;
    float c2 = 0.5f * d2 - 0.5f * d3 + (11.f / 24.f) * d4;
    float c3 = d3 * (1.f / 6.f) - 0.25f * d4;
    float c4 = d4 * (1.f / 24.f);
    float cp;
    if (p == 0) cp = c0;
    else if (p == 1) cp = c1 * 4.f;
    else if (p == 2) cp = c2 * 16.f;
    else if (p == 3) cp = c3 * 64.f;
    else cp = c4 * 256.f;
    sc[j] = cp;
  }
  __syncthreads();
  float acc = 0.f;
#pragma unroll 8
  for (int kk = 0; kk < 128; ++kk) acc += sc[kk] * W2[kk * 128 + j];
  if (p == 0) acc += b2[j];
  E[p * 128 + j] = acc;
}

// ---------------------------------------------------------------------------
// k0b: F_p = E_p @ comp_w[128:,:] (F_0 += comp_b); gvec[g] = grp_emb[g] @ comp_w[:128,:]
// grid 9 (blocks 0-4 -> F_p, 5-8 -> gvec), block 128.
__global__ __launch_bounds__(128) void k0b_FG(
    const float* __restrict__ E, const float* __restrict__ grp_emb,
    const float* __restrict__ comp_w, const float* __restrict__ comp_b,
    float* __restrict__ F, float* __restrict__ gvec) {
  __shared__ float sv[128];
  int j = threadIdx.x, blk = blockIdx.x;
  if (blk < 5) {
    sv[j] = E[blk * 128 + j];
    __syncthreads();
    float acc = 0.f;
#pragma unroll 8
    for (int kk = 0; kk < 128; ++kk) acc += sv[kk] * comp_w[(128 + kk) * 128 + j];
    if (blk == 0) acc += comp_b[j];
    F[blk * 128 + j] = acc;
  } else {
    int g = blk - 5;
    sv[j] = grp_emb[g * 128 + j];
    __syncthreads();
    float acc = 0.f;
#pragma unroll 8
    for (int kk = 0; kk < 128; ++kk) acc += sv[kk] * comp_w[kk * 128 + j];
    gvec[g * 128 + j] = acc;
  }
}

// ---------------------------------------------------------------------------
// k0c: 48 channel-moments (wave-parallel dots) + analytic LN moment polys +
// 512 degree-10 Chebyshev fits (one per thread) -> CC. 1 block, 512 threads.
__global__ __launch_bounds__(512) void k0c_fit(
    const float* __restrict__ F, const float* __restrict__ gvec,
    const float* __restrict__ cg_, const float* __restrict__ cbt_,
    float* __restrict__ CC) {
  __shared__ float sF2[640];
  __shared__ float sGv[512];
  __shared__ float s48[48];
  __shared__ float sMC[20], sVC[36];
  int tid = threadIdx.x;
  for (int idx = tid; idx < 640; idx += 512) sF2[idx] = F[idx];
  if (tid < 512) sGv[tid] = gvec[tid];
  __syncthreads();
  int wv = tid >> 6, lane = tid & 63;
#pragma unroll
  for (int i = 0; i < 6; ++i) {
    int m = wv * 6 + i;
    if (m < 48) {
      const float* va;
      const float* vb = nullptr;
      int t = m;
      if (t < 5) va = &sF2[t * 128];
      else if (t < 9) va = &sGv[(t - 5) * 128];
      else if (t < 13) { va = &sGv[(t - 9) * 128]; vb = va; }
      else if (t < 33) {
        int g = (t - 13) / 5, p = (t - 13) % 5;
        va = &sGv[g * 128]; vb = &sF2[p * 128];
      } else {
        int idx = t - 33;
        int a = 0;
        if (idx >= 14) a = 4;
        else if (idx >= 12) a = 3;
        else if (idx >= 9) a = 2;
        else if (idx >= 5) a = 1;
        const int base[5] = {0, 5, 9, 12, 14};
        int bcol = a + (idx - base[a]);
        va = &sF2[a * 128]; vb = &sF2[bcol * 128];
      }
      float s;
      if (vb) s = va[lane] * vb[lane] + va[lane + 64] * vb[lane + 64];
      else    s = va[lane] + va[lane + 64];
      s = wredsum(s);
      if (lane == 0) s48[m] = s * (1.f / 128.f);
    }
  }
  __syncthreads();
  if (tid < 20) {
    int g = tid / 5, p = tid % 5;
    sMC[g * 5 + p] = s48[p] + (p == 0 ? s48[5 + g] : 0.f);
  }
  if (tid < 36) {
    int g = tid / 9, kk = tid % 9;
    float v = (kk == 0 ? s48[9 + g] : 0.f);
    if (kk < 5) v += 2.f * s48[13 + g * 5 + kk];
#pragma unroll
    for (int p = 0; p < 5; ++p) {
      int q = kk - p;
      if (q >= 0 && q <= 4) v += s48[33 + cidx(p, q)];
    }
    sVC[g * 9 + kk] = v;
  }
  __syncthreads();
  const float nodes[11] = {0.f, 0.02447174185f, 0.09549150281f, 0.2061073739f,
                           0.3454915028f, 0.5f, 0.6545084972f, 0.7938926261f,
                           0.9045084972f, 0.9755282581f, 1.f};
  int g = tid >> 7, j = tid & 127;
  float cgj = cg_[j], btj = cbt_[j];
  float F0 = sF2[j], F1 = sF2[128 + j], F2v = sF2[256 + j], F3 = sF2[384 + j], F4 = sF2[512 + j];
  const float* mc = &sMC[g * 5];
  const float* vc = &sVC[g * 9];
  float gv = sGv[g * 128 + j];
  float fv[11];
#pragma unroll
  for (int n = 0; n < 11; ++n) {
    float t = nodes[n];
    float mean = (((mc[4] * t + mc[3]) * t + mc[2]) * t + mc[1]) * t + mc[0];
    float e2 = vc[8];
#pragma unroll
    for (int p = 7; p >= 0; --p) e2 = e2 * t + vc[p];
    float rstd = rsqrtf(e2 - mean * mean + 1e-5f);
    float pre = gv + ((((F4 * t + F3) * t + F2v) * t + F1) * t + F0);
    fv[n] = siluf((pre - mean) * rstd * cgj + btj);
  }
#pragma unroll
  for (int ord = 1; ord <= 10; ++ord) {
#pragma unroll
    for (int n = 10; n >= 1; --n) {
      if (n >= ord) fv[n] = (fv[n] - fv[n - 1]) / (nodes[n] - nodes[n - ord]);
    }
  }
  float c[11];
#pragma unroll
  for (int i = 0; i < 11; ++i) c[i] = 0.f;
  c[0] = fv[10];
#pragma unroll
  for (int n = 9; n >= 0; --n) {
    int deg = 9 - n;
    float x = nodes[n];
    c[deg + 1] = c[deg];
#pragma unroll
    for (int i = 10; i >= 1; --i) {
      if (i <= deg) c[i] = c[i - 1] - x * c[i];
    }
    c[0] = fv[n] - x * c[0];
  }
#pragma unroll
  for (int p = 0; p < 11; ++p) CC[(g * 11 + p) * 128 + j] = c[p];
}

// ---------------------------------------------------------------------------
// out_w1 [1408x512] f32 -> OW1BT [512x1408] bf16 via LDS tile transpose.
// grid 176 (22 k-tiles x 8 n-tiles), block 256, coalesced both sides.
__global__ __launch_bounds__(256) void k_convw1t(
    const float* __restrict__ ow1, unsigned short* __restrict__ BT) {
  __shared__ float tile[64][65];
  int bk = blockIdx.x % 22;
  int bn = blockIdx.x / 22;
  int tx = threadIdx.x & 63, ty = threadIdx.x >> 6;
#pragma unroll
  for (int r = 0; r < 16; ++r) {
    int kl = ty * 16 + r;
    tile[kl][tx] = ow1[(size_t)(bk * 64 + kl) * 512 + bn * 64 + tx];
  }
  __syncthreads();
#pragma unroll
  for (int r = 0; r < 16; ++r) {
    int nl = ty * 16 + r;
    BT[(size_t)(bn * 64 + nl) * 1408 + bk * 64 + tx] = f2bf(tile[tx][nl]);
  }
}

// fused small conversions: ow2->OW2BT, qw->QWBT, dw->DWBT, df->DB. grid 3520, 256
__global__ __launch_bounds__(256) void k_convmisc(
    const float* __restrict__ ow2, const float* __restrict__ qw,
    const float* __restrict__ dw, const float* __restrict__ df,
    unsigned short* __restrict__ OW2BT, unsigned short* __restrict__ QWBT,
    unsigned short* __restrict__ DWBT, unsigned short* __restrict__ DB) {
  int idx = blockIdx.x * 256 + threadIdx.x;
  if (idx < 131072) {
    int n = idx >> 9, k = idx & 511;
    OW2BT[(size_t)n * 512 + k] = f2bf(ow2[(size_t)k * 256 + n]);
  } else if (idx < 245760) {
    int i = idx - 131072;
    int n = i / 896, k = i - n * 896;
    QWBT[(size_t)n * 896 + k] = f2bf(qw[(size_t)k * 128 + n]);
  } else if (idx < 376832) {
    int i = idx - 245760;
    int n = i >> 8, k = i & 255;
    DWBT[(size_t)n * 256 + k] = f2bf(dw[(size_t)k * 512 + n]);
  } else {
    int i = idx - 376832;
    DB[i] = f2bf(df[i]);
  }
}

// ---------------------------------------------------------------------------
// cand_s / ctx_s masked means -> FB[0:256) bf16. grid B_, block 256
__global__ __launch_bounds__(256) void k_candctx(
    const int* __restrict__ ctok, const int* __restrict__ xtok,
    const int* __restrict__ cmask, const int* __restrict__ xmask,
    const float* __restrict__ tok_emb, unsigned short* __restrict__ FB) {
  int b = blockIdx.x, tid = threadIdx.x;
  int j = tid & 127, half = tid >> 7;
  float acc = 0.f, cnt = 0.f;
  if (half == 0) {
#pragma unroll
    for (int l = 0; l < LC_; ++l) {
      float mv = (float)cmask[b * LC_ + l];
      acc += mv * tok_emb[(size_t)ctok[b * LC_ + l] * 128 + j];
      cnt += mv;
    }
    FB[(size_t)b * 1408 + j] = f2bf(acc / fmaxf(cnt, 1.f));
  } else {
#pragma unroll
    for (int l = 0; l < LX_; ++l) {
      float mv = (float)xmask[b * LX_ + l];
      acc += mv * tok_emb[(size_t)xtok[b * LX_ + l] * 128 + j];
      cnt += mv;
    }
    FB[(size_t)b * 1408 + 128 + j] = f2bf(acc / fmaxf(cnt, 1.f));
  }
}

// ---------------------------------------------------------------------------
// comp summary via per-(g,p) power sums + precomputed poly CC. grid B_, 256
__global__ __launch_bounds__(256) void k_comp_pow(
    const float* __restrict__ times, const int* __restrict__ groups,
    const int* __restrict__ hmask, const float* __restrict__ CC,
    unsigned short* __restrict__ FB) {
  __shared__ float sPow[LH_ * 11];
  __shared__ int sg[LH_];
  __shared__ float sS[4 * 44];
  __shared__ float sSf[44];
  int tid = threadIdx.x, b = blockIdx.x;
  if (tid < LH_) {
    float t = times[b * LH_ + tid];
    int mk = hmask[b * LH_ + tid];
    sg[tid] = mk ? groups[b * LH_ + tid] : -1;
    float pw = 1.f;
#pragma unroll
    for (int p = 0; p < 11; ++p) { sPow[tid * 11 + p] = pw; pw *= t; }
  }
  __syncthreads();
  int lane = tid & 63, w = tid >> 6;
  if (lane < 44) {
    int g = lane / 11, p = lane - 11 * g;
    float s = 0.f;
    for (int l = w * 50; l < w * 50 + 50; ++l) {
      if (sg[l] == g) s += sPow[l * 11 + p];
    }
    sS[w * 44 + lane] = s;
  }
  __syncthreads();
  if (tid < 44) sSf[tid] = sS[tid] + sS[44 + tid] + sS[88 + tid] + sS[132 + tid];
  __syncthreads();
  if (tid < 128) {
    float cnt = sSf[0] + sSf[11] + sSf[22] + sSf[33];
    float inv = 1.f / fmaxf(cnt, 1.f);
    float acc = 0.f;
#pragma unroll 4
    for (int q = 0; q < 44; ++q) acc += sSf[q] * CC[q * 128 + tid];
    FB[(size_t)b * 1408 + 384 + tid] = f2bf(acc * inv);
  }
}

// ---------------------------------------------------------------------------
// dense GEMM via bf16 MFMA: H_D[2048x512] = DB @ DWBT^T. Tile 64x64, grid 256.
__global__ __launch_bounds__(256) void k_gemm_d(
    const unsigned short* __restrict__ A, const unsigned short* __restrict__ BT,
    float* __restrict__ HD) {
  int tid = threadIdx.x;
  int bm = blockIdx.x >> 3;
  int bn = blockIdx.x & 7;
  int w = tid >> 6, lane = tid & 63;
  int m = lane & 15, quad = lane >> 4;
  const unsigned short* ap = A + (size_t)(bm * 64 + w * 16 + m) * 256 + quad * 8;
  const unsigned short* bp0 = BT + (size_t)(bn * 64 + m) * 256 + quad * 8;
  const unsigned short* bp1 = bp0 + 16 * 256;
  const unsigned short* bp2 = bp0 + 32 * 256;
  const unsigned short* bp3 = bp0 + 48 * 256;
  floatx4 acc0 = {0.f, 0.f, 0.f, 0.f};
  floatx4 acc1 = {0.f, 0.f, 0.f, 0.f};
  floatx4 acc2 = {0.f, 0.f, 0.f, 0.f};
  floatx4 acc3 = {0.f, 0.f, 0.f, 0.f};
#pragma unroll
  for (int kc = 0; kc < 256; kc += 32) {
    short8v af = *(const short8v*)&ap[kc];
    short8v b0 = *(const short8v*)&bp0[kc];
    short8v b1 = *(const short8v*)&bp1[kc];
    short8v b2 = *(const short8v*)&bp2[kc];
    short8v b3 = *(const short8v*)&bp3[kc];
    acc0 = __builtin_amdgcn_mfma_f32_16x16x32_bf16(af, b0, acc0, 0, 0, 0);
    acc1 = __builtin_amdgcn_mfma_f32_16x16x32_bf16(af, b1, acc1, 0, 0, 0);
    acc2 = __builtin_amdgcn_mfma_f32_16x16x32_bf16(af, b2, acc2, 0, 0, 0);
    acc3 = __builtin_amdgcn_mfma_f32_16x16x32_bf16(af, b3, acc3, 0, 0, 0);
  }
  int row = bm * 64 + w * 16 + quad * 4;
  int col = bn * 64 + m;
#pragma unroll
  for (int r = 0; r < 4; ++r) {
    HD[(size_t)(row + r) * 512 + col] = acc0[r];
    HD[(size_t)(row + r) * 512 + col + 16] = acc1[r];
    HD[(size_t)(row + r) * 512 + col + 32] = acc2[r];
    HD[(size_t)(row + r) * 512 + col + 48] = acc3[r];
  }
}

// ---------------------------------------------------------------------------
// bias+LN+silu on H_D -> FB[896:1408) bf16. 4 rows/block, grid B_/4, block 256
__global__ __launch_bounds__(256) void k_dense_ln(
    const float* __restrict__ HD, const float* __restrict__ dbias,
    const float* __restrict__ dg, const float* __restrict__ dbt,
    unsigned short* __restrict__ FB) {
  __shared__ float sr1[16], sr2[16];
  int tid = threadIdx.x;
  int b0 = blockIdx.x * 4;
  int wv = tid >> 6;
  float bi0 = dbias[tid], bi1 = dbias[tid + 256];
  float a0[4], a1[4];
#pragma unroll
  for (int r = 0; r < 4; ++r) {
    a0[r] = HD[(size_t)(b0 + r) * 512 + tid] + bi0;
    a1[r] = HD[(size_t)(b0 + r) * 512 + tid + 256] + bi1;
    float s1 = wredsum(a0[r] + a1[r]);
    float s2 = wredsum(a0[r] * a0[r] + a1[r] * a1[r]);
    if ((tid & 63) == 0) { sr1[r * 4 + wv] = s1; sr2[r * 4 + wv] = s2; }
  }
  __syncthreads();
  float g0 = dg[tid], g1 = dg[tid + 256], t0 = dbt[tid], t1 = dbt[tid + 256];
#pragma unroll
  for (int r = 0; r < 4; ++r) {
    float s1 = sr1[r * 4] + sr1[r * 4 + 1] + sr1[r * 4 + 2] + sr1[r * 4 + 3];
    float s2 = sr2[r * 4] + sr2[r * 4 + 1] + sr2[r * 4 + 2] + sr2[r * 4 + 3];
    float mean = s1 / 512.f, var = s2 / 512.f - mean * mean;
    float rstd = rsqrtf(var + 1e-5f);
    FB[(size_t)(b0 + r) * 1408 + 896 + tid] = f2bf(siluf((a0[r] - mean) * rstd * g0 + t0));
    FB[(size_t)(b0 + r) * 1408 + 896 + tid + 256] = f2bf(siluf((a1[r] - mean) * rstd * g1 + t1));
  }
}

// ---------------------------------------------------------------------------
// query via bf16 MFMA (A straight from FB), fused LN+silu epilogue.
// Tile 64M x 128N, grid 32, block 256.
__global__ __launch_bounds__(256) void k_query_mfma(
    const unsigned short* __restrict__ FB, const unsigned short* __restrict__ QWBT,
    const float* __restrict__ qb, const float* __restrict__ qg,
    const float* __restrict__ qbt, float* __restrict__ query) {
  int tid = threadIdx.x;
  int w = tid >> 6, lane = tid & 63;
  int m = lane & 15, quad = lane >> 4;
  const unsigned short* ap = FB + (size_t)(blockIdx.x * 64 + w * 16 + m) * 1408 + quad * 8;
  const unsigned short* bp = QWBT + (size_t)m * 896 + quad * 8;
  floatx4 acc[8];
#pragma unroll
  for (int nt = 0; nt < 8; ++nt) acc[nt] = {0.f, 0.f, 0.f, 0.f};
#pragma unroll 4
  for (int kc = 0; kc < 28; ++kc) {
    int fo = (kc < 8) ? kc * 32 : (kc < 12 ? 384 + (kc - 8) * 32 : 896 + (kc - 12) * 32);
    short8v af = *(const short8v*)&ap[fo];
#pragma unroll
    for (int nt = 0; nt < 8; ++nt) {
      short8v bf = *(const short8v*)&bp[(size_t)nt * 16 * 896 + kc * 32];
      acc[nt] = __builtin_amdgcn_mfma_f32_16x16x32_bf16(af, bf, acc[nt], 0, 0, 0);
    }
  }
  float bj[8], gj[8], tj[8];
#pragma unroll
  for (int nt = 0; nt < 8; ++nt) {
    bj[nt] = qb[nt * 16 + m];
    gj[nt] = qg[nt * 16 + m];
    tj[nt] = qbt[nt * 16 + m];
  }
#pragma unroll
  for (int r = 0; r < 4; ++r) {
    float x[8];
    float s1 = 0.f, s2 = 0.f;
#pragma unroll
    for (int nt = 0; nt < 8; ++nt) {
      x[nt] = acc[nt][r] + bj[nt];
      s1 += x[nt];
      s2 += x[nt] * x[nt];
    }
#pragma unroll
    for (int off = 1; off < 16; off <<= 1) {
      s1 += __shfl_xor(s1, off, 64);
      s2 += __shfl_xor(s2, off, 64);
    }
    float mean = s1 * (1.f / 128.f);
    float var = s2 * (1.f / 128.f) - mean * mean;
    float rstd = rsqrtf(var + 1e-5f);
    int row = blockIdx.x * 64 + w * 16 + quad * 4 + r;
#pragma unroll
    for (int nt = 0; nt < 8; ++nt) {
      query[(size_t)row * 128 + nt * 16 + m] = siluf((x[nt] - mean) * rstd * gj[nt] + tj[nt]);
    }
  }
}

// ---------------------------------------------------------------------------
// single-pass online-softmax attention, 16-lane rows (4 rows/wave concurrent),
// dwordx4 gathers, staged poly term. grid B_, block 256.
__global__ __launch_bounds__(256) void k_attn4(
    const int* __restrict__ htok, const int* __restrict__ hpos,
    const int* __restrict__ hgrp, const int* __restrict__ hmask,
    const float* __restrict__ times,
    const float* __restrict__ tok_emb, const float* __restrict__ pos_emb,
    const float* __restrict__ grp_emb,
    const float* __restrict__ query, const float* __restrict__ E,
    unsigned short* __restrict__ FB) {
  __shared__ float sq[128];
  __shared__ float sE[5 * 128];
  __shared__ float sG[4 * 128];
  __shared__ float st[LH_];
  __shared__ float spoly[LH_];
  __shared__ int stok[LH_], spos[LH_], sgrp[LH_], smk[LH_];
  __shared__ float seq[5 * 2];
  __shared__ float s_eq[5];
  __shared__ float sA[16 * 128];
  __shared__ float sL[16];
  __shared__ float sM[16 * 5];
  int tid = threadIdx.x, b = blockIdx.x;
  int lane = tid & 63, w = tid >> 6;
  int rg = lane >> 4, li = lane & 15;
  int grp16 = w * 4 + rg;
  if (tid < 128) sq[tid] = query[b * 128 + tid];
  for (int idx = tid; idx < 5 * 128; idx += 256) sE[idx] = E[idx];
  for (int idx = tid; idx < 4 * 128; idx += 256) sG[idx] = grp_emb[idx];
  for (int l = tid; l < LH_; l += 256) {
    st[l] = times[b * LH_ + l];
    stok[l] = htok[b * LH_ + l];
    spos[l] = hpos[b * LH_ + l];
    sgrp[l] = hgrp[b * LH_ + l];
    smk[l] = hmask[b * LH_ + l];
  }
  __syncthreads();
  if (tid < 128) {
    int wh = (tid >> 6) & 1;
#pragma unroll
    for (int p = 0; p < 5; ++p) {
      float v = sE[p * 128 + tid] * sq[tid];
      v = wredsum(v);
      if ((tid & 63) == 0) seq[p * 2 + wh] = v;
    }
  }
  __syncthreads();
  if (tid < 5) s_eq[tid] = seq[tid * 2] + seq[tid * 2 + 1];
  __syncthreads();
  if (tid < LH_) {
    float t = st[tid];
    spoly[tid] = (((s_eq[4] * t + s_eq[3]) * t + s_eq[2]) * t + s_eq[1]) * t + s_eq[0];
  }
  __syncthreads();
  const float4 qa = *(const float4*)&sq[li * 8];
  const float4 qb4 = *(const float4*)&sq[li * 8 + 4];
  const float scale = 0.08838834764831845f;  // 1/sqrt(128)
  float a0 = 0.f, a1 = 0.f, a2 = 0.f, a3 = 0.f, a4 = 0.f, a5 = 0.f, a6 = 0.f, a7 = 0.f;
  float lsum = 0.f, mom1 = 0.f, mom2 = 0.f, mom3 = 0.f, mom4 = 0.f;
  for (int l = grp16; l < LH_; l += 16) {
    if (smk[l]) {
      int tok = stok[l], pos = spos[l], g = sgrp[l];
      const float* tp_ = &tok_emb[(size_t)tok * 128 + li * 8];
      const float* pp_ = &pos_emb[pos * 128 + li * 8];
      float4 ta = *(const float4*)tp_;
      float4 tb = *(const float4*)(tp_ + 4);
      float4 pa = *(const float4*)pp_;
      float4 pb = *(const float4*)(pp_ + 4);
      const float* gp_ = &sG[g * 128 + li * 8];
      float4 ga = *(const float4*)gp_;
      float4 gb = *(const float4*)(gp_ + 4);
      float v0 = ta.x + pa.x + ga.x, v1 = ta.y + pa.y + ga.y;
      float v2 = ta.z + pa.z + ga.z, v3 = ta.w + pa.w + ga.w;
      float v4 = tb.x + pb.x + gb.x, v5 = tb.y + pb.y + gb.y;
      float v6 = tb.z + pb.z + gb.z, v7 = tb.w + pb.w + gb.w;
      float d = v0 * qa.x + v1 * qa.y + v2 * qa.z + v3 * qa.w +
                v4 * qb4.x + v5 * qb4.y + v6 * qb4.z + v7 * qb4.w;
      d += __shfl_xor(d, 1, 64);
      d += __shfl_xor(d, 2, 64);
      d += __shfl_xor(d, 4, 64);
      d += __shfl_xor(d, 8, 64);
      float e = __expf((d + spoly[l]) * scale);
      float t = st[l];
      lsum += e;
      a0 += e * v0; a1 += e * v1; a2 += e * v2; a3 += e * v3;
      a4 += e * v4; a5 += e * v5; a6 += e * v6; a7 += e * v7;
      float tp = e * t;
      mom1 += tp; tp *= t;
      mom2 += tp; tp *= t;
      mom3 += tp; tp *= t;
      mom4 += tp;
    }
  }
  float* ap2 = &sA[grp16 * 128 + li * 8];
  ap2[0] = a0; ap2[1] = a1; ap2[2] = a2; ap2[3] = a3;
  ap2[4] = a4; ap2[5] = a5; ap2[6] = a6; ap2[7] = a7;
  if (li == 0) {
    sL[grp16] = lsum;
    sM[grp16 * 5 + 1] = mom1; sM[grp16 * 5 + 2] = mom2;
    sM[grp16 * 5 + 3] = mom3; sM[grp16 * 5 + 4] = mom4;
  }
  __syncthreads();
  if (tid < 128) {
    int i = tid;
    float L = 0.f;
#pragma unroll
    for (int k = 0; k < 16; ++k) L += sL[k];
    float inv = 1.f / L;
    float v = 0.f;
#pragma unroll
    for (int k = 0; k < 16; ++k) v += sA[k * 128 + i];
    v *= inv;
    v += sE[i];
#pragma unroll
    for (int p = 1; p < 5; ++p) {
      float mp = 0.f;
#pragma unroll
      for (int k = 0; k < 16; ++k) mp += sM[k * 5 + p];
      v += mp * inv * sE[p * 128 + i];
    }
    unsigned short* row = FB + (size_t)b * 1408;
    float c = bf2f(row[i]), cm = bf2f(row[384 + i]);
    row[256 + i] = f2bf(v);
    row[512 + i] = f2bf(c * v);
    row[640 + i] = f2bf(c * cm);
    row[768 + i] = f2bf(fabsf(v - cm));
  }
}

// ---------------------------------------------------------------------------
// GEMM1 via bf16 MFMA: H1[2048x512] = FB @ OW1BT^T. Tile 64x64, grid 256, 256.
__global__ __launch_bounds__(256) void k_gemm1(
    const unsigned short* __restrict__ A, const unsigned short* __restrict__ BT,
    float* __restrict__ H1) {
  int tid = threadIdx.x;
  int bm = blockIdx.x >> 3;
  int bn = blockIdx.x & 7;
  int w = tid >> 6, lane = tid & 63;
  int m = lane & 15, quad = lane >> 4;
  const unsigned short* ap = A + (size_t)(bm * 64 + w * 16 + m) * 1408 + quad * 8;
  const unsigned short* bp0 = BT + (size_t)(bn * 64 + m) * 1408 + quad * 8;
  const unsigned short* bp1 = bp0 + 16 * 1408;
  const unsigned short* bp2 = bp0 + 32 * 1408;
  const unsigned short* bp3 = bp0 + 48 * 1408;
  floatx4 acc0 = {0.f, 0.f, 0.f, 0.f};
  floatx4 acc1 = {0.f, 0.f, 0.f, 0.f};
  floatx4 acc2 = {0.f, 0.f, 0.f, 0.f};
  floatx4 acc3 = {0.f, 0.f, 0.f, 0.f};
#pragma unroll 4
  for (int kc = 0; kc < 1408; kc += 32) {
    short8v af = *(const short8v*)&ap[kc];
    short8v b0 = *(const short8v*)&bp0[kc];
    short8v b1 = *(const short8v*)&bp1[kc];
    short8v b2 = *(const short8v*)&bp2[kc];
    short8v b3 = *(const short8v*)&bp3[kc];
    acc0 = __builtin_amdgcn_mfma_f32_16x16x32_bf16(af, b0, acc0, 0, 0, 0);
    acc1 = __builtin_amdgcn_mfma_f32_16x16x32_bf16(af, b1, acc1, 0, 0, 0);
    acc2 = __builtin_amdgcn_mfma_f32_16x16x32_bf16(af, b2, acc2, 0, 0, 0);
    acc3 = __builtin_amdgcn_mfma_f32_16x16x32_bf16(af, b3, acc3, 0, 0, 0);
  }
  int row = bm * 64 + w * 16 + quad * 4;
  int col = bn * 64 + m;
#pragma unroll
  for (int r = 0; r < 4; ++r) {
    H1[(size_t)(row + r) * 512 + col] = acc0[r];
    H1[(size_t)(row + r) * 512 + col + 16] = acc1[r];
    H1[(size_t)(row + r) * 512 + col + 32] = acc2[r];
    H1[(size_t)(row + r) * 512 + col + 48] = acc3[r];
  }
}

// ---------------------------------------------------------------------------
// LN+silu on H1 (+ob1) -> H1S bf16. 4 rows/block, grid B_/4, block 256
__global__ __launch_bounds__(256) void k_ln1(
    const float* __restrict__ H1, const float* __restrict__ ob1,
    const float* __restrict__ og, const float* __restrict__ obt,
    unsigned short* __restrict__ H1S) {
  __shared__ float sr1[16], sr2[16];
  int tid = threadIdx.x;
  int b0 = blockIdx.x * 4;
  int wv = tid >> 6;
  float bi0 = ob1[tid], bi1 = ob1[tid + 256];
  float a0[4], a1[4];
#pragma unroll
  for (int r = 0; r < 4; ++r) {
    a0[r] = H1[(size_t)(b0 + r) * 512 + tid] + bi0;
    a1[r] = H1[(size_t)(b0 + r) * 512 + tid + 256] + bi1;
    float s1 = wredsum(a0[r] + a1[r]);
    float s2 = wredsum(a0[r] * a0[r] + a1[r] * a1[r]);
    if ((tid & 63) == 0) { sr1[r * 4 + wv] = s1; sr2[r * 4 + wv] = s2; }
  }
  __syncthreads();
  float g0 = og[tid], g1 = og[tid + 256], t0 = obt[tid], t1 = obt[tid + 256];
#pragma unroll
  for (int r = 0; r < 4; ++r) {
    float s1 = sr1[r * 4] + sr1[r * 4 + 1] + sr1[r * 4 + 2] + sr1[r * 4 + 3];
    float s2 = sr2[r * 4] + sr2[r * 4 + 1] + sr2[r * 4 + 2] + sr2[r * 4 + 3];
    float mean = s1 / 512.f, var = s2 / 512.f - mean * mean;
    float rstd = rsqrtf(var + 1e-5f);
    H1S[(size_t)(b0 + r) * 512 + tid] = f2bf(siluf((a0[r] - mean) * rstd * g0 + t0));
    H1S[(size_t)(b0 + r) * 512 + tid + 256] = f2bf(siluf((a1[r] - mean) * rstd * g1 + t1));
  }
}

// ---------------------------------------------------------------------------
// GEMM2 via bf16 MFMA: H2[2048x256] = H1S @ OW2BT^T. Tile 64x32, grid 256.
__global__ __launch_bounds__(256) void k_gemm2(
    const unsigned short* __restrict__ A, const unsigned short* __restrict__ BT,
    float* __restrict__ H2) {
  int tid = threadIdx.x;
  int bm = blockIdx.x >> 3;
  int bn = blockIdx.x & 7;
  int w = tid >> 6, lane = tid & 63;
  int m = lane & 15, quad = lane >> 4;
  const unsigned short* ap = A + (size_t)(bm * 64 + w * 16 + m) * 512 + quad * 8;
  const unsigned short* bp0 = BT + (size_t)(bn * 32 + m) * 512 + quad * 8;
  const unsigned short* bp1 = bp0 + 16 * 512;
  floatx4 acc0 = {0.f, 0.f, 0.f, 0.f};
  floatx4 acc1 = {0.f, 0.f, 0.f, 0.f};
#pragma unroll
  for (int kc = 0; kc < 512; kc += 32) {
    short8v af = *(const short8v*)&ap[kc];
    short8v b0 = *(const short8v*)&bp0[kc];
    short8v b1 = *(const short8v*)&bp1[kc];
    acc0 = __builtin_amdgcn_mfma_f32_16x16x32_bf16(af, b0, acc0, 0, 0, 0);
    acc1 = __builtin_amdgcn_mfma_f32_16x16x32_bf16(af, b1, acc1, 0, 0, 0);
  }
  int row = bm * 64 + w * 16 + quad * 4;
  int col = bn * 32 + m;
#pragma unroll
  for (int r = 0; r < 4; ++r) {
    H2[(size_t)(row + r) * 256 + col] = acc0[r];
    H2[(size_t)(row + r) * 256 + col + 16] = acc1[r];
  }
}

// ---------------------------------------------------------------------------
// out[b] = sum_c silu(H2[b,c]+ob2[c])*ow3[c] + ob3. 8 rows/block, grid B_/8, 256
__global__ __launch_bounds__(256) void k_out(
    const float* __restrict__ H2, const float* __restrict__ ob2,
    const float* __restrict__ ow3, const float* __restrict__ ob3,
    float* __restrict__ out) {
  __shared__ float sdot[32];
  int tid = threadIdx.x;
  int b0 = blockIdx.x * 8;
  int wv = tid >> 6;
  float b2 = ob2[tid], w3 = ow3[tid];
#pragma unroll
  for (int r = 0; r < 8; ++r) {
    float v = siluf(H2[(size_t)(b0 + r) * 256 + tid] + b2) * w3;
    v = wredsum(v);
    if ((tid & 63) == 0) sdot[r * 4 + wv] = v;
  }
  __syncthreads();
  if (tid < 8) {
    out[b0 + tid] = sdot[tid * 4] + sdot[tid * 4 + 1] + sdot[tid * 4 + 2] + sdot[tid * 4 + 3] +
                    ob3[0];
  }
}

// ---------------------------------------------------------------------------
extern "C" void kernel_launch(void* const* d_in, const int* in_sizes, int n_in,
                              void* d_out, int out_size, void* d_ws, size_t ws_size,
                              hipStream_t stream) {
  const int* cand_tok = (const int*)d_in[0];
  const int* ctx_tok = (const int*)d_in[1];
  const int* hist_tok = (const int*)d_in[2];
  const int* hist_pos = (const int*)d_in[3];
  const int* hist_grp = (const int*)d_in[4];
  const int* cand_mask = (const int*)d_in[5];
  const int* ctx_mask = (const int*)d_in[6];
  const int* hist_mask = (const int*)d_in[7];
  const float* hist_times = (const float*)d_in[8];
  const float* dense_feat = (const float*)d_in[9];
  const float* tok_emb = (const float*)d_in[10];
  const float* pos_emb = (const float*)d_in[11];
  const float* grp_emb = (const float*)d_in[12];
  const float* time_w1 = (const float*)d_in[13];
  const float* time_b1 = (const float*)d_in[14];
  const float* time_w2 = (const float*)d_in[15];
  const float* time_b2 = (const float*)d_in[16];
  const float* comp_w = (const float*)d_in[17];
  const float* comp_b = (const float*)d_in[18];
  const float* comp_g = (const float*)d_in[19];
  const float* comp_bt = (const float*)d_in[20];
  const float* dense_w = (const float*)d_in[21];
  const float* dense_b = (const float*)d_in[22];
  const float* dense_g = (const float*)d_in[23];
  const float* dense_bt = (const float*)d_in[24];
  const float* query_w = (const float*)d_in[25];
  const float* query_b = (const float*)d_in[26];
  const float* query_g = (const float*)d_in[27];
  const float* query_bt = (const float*)d_in[28];
  const float* out_w1 = (const float*)d_in[29];
  const float* out_b1 = (const float*)d_in[30];
  const float* out_g = (const float*)d_in[31];
  const float* out_bt = (const float*)d_in[32];
  const float* out_w2 = (const float*)d_in[33];
  const float* out_b2 = (const float*)d_in[34];
  const float* out_w3 = (const float*)d_in[35];
  const float* out_b3 = (const float*)d_in[36];
  float* out = (float*)d_out;

  // Workspace — validated 4,950,016-float footprint. F/gvec scratch live in
  // the pad region between CC and query.
  float* ws = (float*)d_ws;
  float* E = ws;                                     // 640
  float* CC = ws + 640;                              // 5632 (ends 6272)
  float* Fs = ws + 6272;                             // 640 (ends 6912)
  float* gvecs = ws + 6912;                          // 512 (ends 7424, pad 8192)
  float* query = ws + 8192;                          // 262144
  unsigned short* H1S = (unsigned short*)(ws + 8192);        // aliases query
  float* HD = ws + 270336;                           // 1048576
  float* H2 = HD;                                    // aliases dead HD
  unsigned short* OW2BT = (unsigned short*)(ws + 1318912);   // 65536 fl
  unsigned short* QWBT = (unsigned short*)(ws + 1384448);    // 57344 fl
  unsigned short* DWBT = (unsigned short*)(ws + 1441792);    // 65536 fl
  unsigned short* DB = (unsigned short*)(ws + 1507328);      // 262144 fl
  float* H1 = ws + 2099200;                          // 1048576
  unsigned short* FB = (unsigned short*)(ws + 3147776);      // 1441792 fl
  unsigned short* OW1BT = (unsigned short*)(ws + 4589568);   // 360448 fl

  k0a_E<<<5, 128, 0, stream>>>(time_w1, time_b1, time_w2, time_b2, E);
  k0b_FG<<<9, 128, 0, stream>>>(E, grp_emb, comp_w, comp_b, Fs, gvecs);
  k0c_fit<<<1, 512, 0, stream>>>(Fs, gvecs, comp_g, comp_bt, CC);
  k_convw1t<<<176, 256, 0, stream>>>(out_w1, OW1BT);
  k_convmisc<<<3520, 256, 0, stream>>>(out_w2, query_w, dense_w, dense_feat,
                                       OW2BT, QWBT, DWBT, DB);
  k_candctx<<<B_, 256, 0, stream>>>(cand_tok, ctx_tok, cand_mask, ctx_mask,
                                    tok_emb, FB);
  k_comp_pow<<<B_, 256, 0, stream>>>(hist_times, hist_grp, hist_mask, CC, FB);
  k_gemm_d<<<256, 256, 0, stream>>>(DB, DWBT, HD);
  k_dense_ln<<<B_ / 4, 256, 0, stream>>>(HD, dense_b, dense_g, dense_bt, FB);
  k_query_mfma<<<32, 256, 0, stream>>>(FB, QWBT, query_b, query_g, query_bt, query);
  k_attn4<<<B_, 256, 0, stream>>>(hist_tok, hist_pos, hist_grp, hist_mask, hist_times,
                                  tok_emb, pos_emb, grp_emb, query, E, FB);
  k_gemm1<<<256, 256, 0, stream>>>(FB, OW1BT, H1);
  k_ln1<<<B_ / 4, 256, 0, stream>>>(H1, out_b1, out_g, out_bt, H1S);
  k_gemm2<<<256, 256, 0, stream>>>(H1S, OW2BT, H2);
  k_out<<<B_ / 8, 256, 0, stream>>>(H2, out_b2, out_w3, out_b3, out);
}